// Round 1
// baseline (1444.803 us; speedup 1.0000x reference)
//
#include <hip/hip_runtime.h>
#include <climits>
#include <cmath>

#define NB 8192
#define EPSQ 1e-8f

// ---- ws layout (byte offsets), total use = 83,456 B ----
#define WS_F(ws)    ((float*)(ws))                 // scalars: 0 s0,1 sx1,2 sw1,3 sb1,4 sy1,5 sr1,6 sx2,7 sw2,8 sb2,9 sy2,10 sr2,11 sx3,12 swf,13 sb3,14 sy3
#define WS_I(ws)    ((int*)((char*)(ws)+128))      // 0 maxabs_x bits, 1 maxabsI1, 2 maxI1, 3 maxabsI2, 4 maxI2, 5 maxabsI3
#define WS_Q2T(ws)  ((int*)((char*)(ws)+256))      // [16]
#define WS_Q3T(ws)  ((int*)((char*)(ws)+320))      // [16]
#define WS_B1L(ws)  ((int*)((char*)(ws)+384))      // [16]
#define WS_B2L(ws)  ((int*)((char*)(ws)+448))      // [32]
#define WS_BFL(ws)  ((int*)((char*)(ws)+576))      // [16]
#define WS_M1F(ws)  ((float*)((char*)(ws)+640))    // [16*9]
#define WS_M2F(ws)  ((float*)((char*)(ws)+2048))   // [9][16][32] = 4608
#define WS_MFF(ws)  ((float*)((char*)(ws)+20480))  // [10][1568] = 15680

__device__ __forceinline__ float clampf(float v, float lo, float hi){ return fminf(fmaxf(v, lo), hi); }

__device__ __forceinline__ float wave_max_f(float v){
#pragma unroll
  for (int off=32; off; off>>=1) v = fmaxf(v, __shfl_down(v, off, 64));
  return v;
}
__device__ __forceinline__ int wave_max_i(int v){
#pragma unroll
  for (int off=32; off; off>>=1) v = max(v, __shfl_down(v, off, 64));
  return v;
}

// block(256) reduce of (amax>=0, smax signed) then atomics
__device__ __forceinline__ void reduce2_atomic(int amax, int smax, int* gA, int* gS){
  amax = wave_max_i(amax); smax = wave_max_i(smax);
  __shared__ int sA[4], sS[4];
  int w = threadIdx.x>>6, l = threadIdx.x&63;
  if (l==0){ sA[w]=amax; sS[w]=smax; }
  __syncthreads();
  if (threadIdx.x==0){
#pragma unroll
    for (int i=1;i<4;i++){ amax=max(amax,sA[i]); smax=max(smax,sS[i]); }
    atomicMax(gA, amax); atomicMax(gS, smax);
  }
}

__global__ void k_init(char* ws){
  int* I = WS_I(ws);
  if (threadIdx.x==0){ I[0]=0; I[1]=0; I[2]=INT_MIN; I[3]=0; I[4]=INT_MIN; I[5]=0; }
}

__global__ void k_absx(const float* __restrict__ x, char* ws){
  const float4* x4 = (const float4*)x;
  const int n4 = NB*784/4;
  float m = 0.f;
  for (int i = blockIdx.x*blockDim.x + threadIdx.x; i < n4; i += gridDim.x*blockDim.x){
    float4 v = x4[i];
    m = fmaxf(m, fmaxf(fmaxf(fabsf(v.x),fabsf(v.y)), fmaxf(fabsf(v.z),fabsf(v.w))));
  }
  m = wave_max_f(m);
  __shared__ float sm[4];
  int w = threadIdx.x>>6;
  if ((threadIdx.x&63)==0) sm[w]=m;
  __syncthreads();
  if (threadIdx.x==0){
    m = fmaxf(fmaxf(sm[0],sm[1]), fmaxf(sm[2],sm[3]));
    atomicMax((unsigned*)WS_I(ws), __float_as_uint(m));
  }
}

__global__ void k_wq(const float* __restrict__ w1, const float* __restrict__ b1,
                     const float* __restrict__ w2, const float* __restrict__ wf,
                     char* ws){
  __shared__ float red[256];
  float* F = WS_F(ws);
  int* I = WS_I(ws);
  int t = threadIdx.x;
  auto bmaxabs = [&](const float* p, int n)->float{
    float m=0.f; for (int i=t;i<n;i+=256) m=fmaxf(m,fabsf(p[i]));
    red[t]=m; __syncthreads();
    for (int s=128;s;s>>=1){ if (t<s) red[t]=fmaxf(red[t],red[t+s]); __syncthreads(); }
    float r=red[0]; __syncthreads(); return r;
  };
  float mw1 = bmaxabs(w1,144);
  float mw2 = bmaxabs(w2,4608);
  float mwf = bmaxabs(wf,15680);
  float mx  = __uint_as_float((unsigned)I[0]);
  float s0  = fmaxf(mx/127.f, EPSQ);
  float sx1 = fmaxf((127.f*s0)/127.f, EPSQ);   // max|h0| = fl(127*s0) (argmax maps to level 127)
  float sw1 = fmaxf(mw1/7.f, EPSQ);
  float sw2 = fmaxf(mw2/7.f, EPSQ);
  float swf = fmaxf(mwf/7.f, EPSQ);
  float sb1 = sx1*sw1;
  if (t==0){ F[0]=s0; F[1]=sx1; F[2]=sw1; F[3]=sb1; F[7]=sw2; F[12]=swf; }
  float* m1f = WS_M1F(ws);
  for (int i=t;i<144;i+=256) m1f[i] = clampf(rintf(w1[i]/sw1), -7.f, 7.f);
  if (t<16) WS_B1L(ws)[t] = (int)rintf(b1[t]/sb1);
  float* m2f = WS_M2F(ws);
  for (int i=t;i<4608;i+=256){
    int oc = i/144, r = i-oc*144, c = r/9, tp = r-c*9;   // w2 OIHW flat
    m2f[(tp*16+c)*32+oc] = clampf(rintf(w2[i]/sw2), -7.f, 7.f);
  }
  float* mff = WS_MFF(ws);
  for (int i=t;i<15680;i+=256) mff[i] = clampf(rintf(wf[i]/swf), -7.f, 7.f);
}

__global__ void k_s1(const float* __restrict__ b2, char* ws){
  float* F=WS_F(ws); int* I=WS_I(ws);
  __shared__ float sh[4];
  int t=threadIdx.x;
  if (t==0){
    float sb1=F[3];
    float sy1 = fmaxf((sb1*(float)I[1])/127.f, EPSQ);
    float mp  = sb1*(float)I[2];
    float P1  = clampf(rintf(mp/sy1), 0.f, 127.f);        // max positive int8 level (post-relu)
    float sr1 = fmaxf((sy1*P1)/15.f, EPSQ);
    float N1  = clampf(rintf((sy1*P1)/sr1), 0.f, 15.f);   // max uint4 level
    float sx2 = fmaxf((N1*sr1)/127.f, EPSQ);
    float sb2 = sx2*F[7];
    F[4]=sy1; F[5]=sr1; F[6]=sx2; F[8]=sb2;
    sh[0]=sr1; sh[1]=sx2; sh[2]=sb2;
  }
  __syncthreads();
  float sr1=sh[0], sx2=sh[1], sb2=sh[2];
  if (t<16) WS_Q2T(ws)[t] = (int)clampf(rintf(((float)t*sr1)/sx2), -128.f, 127.f);
  if (t<32) WS_B2L(ws)[t] = (int)rintf(b2[t]/sb2);
}

__global__ void k_s2(const float* __restrict__ bf, char* ws){
  float* F=WS_F(ws); int* I=WS_I(ws);
  __shared__ float sh[4];
  int t=threadIdx.x;
  if (t==0){
    float sb2=F[8];
    float sy2 = fmaxf((sb2*(float)I[3])/127.f, EPSQ);
    float mp  = sb2*(float)I[4];
    float P2  = clampf(rintf(mp/sy2), 0.f, 127.f);
    float sr2 = fmaxf((sy2*P2)/15.f, EPSQ);
    float N2  = clampf(rintf((sy2*P2)/sr2), 0.f, 15.f);
    float sx3 = fmaxf((N2*sr2)/127.f, EPSQ);
    float sb3 = sx3*F[12];
    F[9]=sy2; F[10]=sr2; F[11]=sx3; F[13]=sb3;
    sh[0]=sr2; sh[1]=sx3; sh[2]=sb3;
  }
  __syncthreads();
  float sr2=sh[0], sx3=sh[1], sb3=sh[2];
  if (t<16) WS_Q3T(ws)[t] = (int)clampf(rintf(((float)t*sr2)/sx3), -128.f, 127.f);
  if (t<16) WS_BFL(ws)[t] = (t<10) ? (int)rintf(bf[t]/sb3) : 0;
}

__global__ void k_s3(char* ws){
  float* F=WS_F(ws); int* I=WS_I(ws);
  if (threadIdx.x==0) F[14] = fmaxf((F[13]*(float)I[5])/127.f, EPSQ);
}

// MODE 0: conv1 int-reduce. MODE 1: conv1 requant+pool1+conv2 int-reduce.
// MODE 2: conv1 chain + conv2 requant + pool2 + fc -> I3 (in d_out as int) + maxabs reduce.
template<int MODE>
__global__ __launch_bounds__(256) void k_fused(const float* __restrict__ x, char* ws, int* i3out){
  constexpr int ARENA = (MODE==0) ? 3840 : 37632;
  __shared__ __align__(16) char arena[ARENA];
  float* k0f   = (float*)arena;                          // 784 (phase A)
  float* m1f_s = (float*)(arena+3136);                   // 144
  float* b1f   = (float*)(arena+3712);                   // 16   (ends 3776)
  unsigned char* n1buf = (unsigned char*)(arena+12544);  // 12544 (ends 25088)
  float* q2f   = (float*)arena;                          // 3136 floats (phase B+, overlays k0f/m1f)
  float* m2f_s = (float*)(arena+12544);                  // 4608 floats (overlays n1buf, ends 30976)
  float* b2f   = (float*)(arena+30976);                  // 32 (ends 31104)
  unsigned char* n2buf = (unsigned char*)(arena+31104);  // 6272 (ends 37376)
  float* q3f   = (float*)arena;                          // 1568 floats (phase D, overlays q2f)
  float* redf  = (float*)(arena+37376);                  // 40 floats

  const int tid = threadIdx.x;
  const int img = blockIdx.x;
  const float* F = WS_F(ws);
  const float s0 = F[0];

  const float* xi = x + img*784;
  for (int i=tid; i<784; i+=256) k0f[i] = clampf(rintf(xi[i]/s0), -128.f, 127.f);
  for (int i=tid; i<144; i+=256) m1f_s[i] = WS_M1F(ws)[i];
  if (tid<16) b1f[tid] = (float)WS_B1L(ws)[tid];

  float sb1=0.f, sy1=0.f, sr1=0.f;
  __shared__ int q2s[16];
  if constexpr (MODE>=1){
    sb1=F[3]; sy1=F[4]; sr1=F[5];
    if (tid<16) q2s[tid] = WS_Q2T(ws)[tid];
  }
  __syncthreads();

  // ---- conv1 (integer-exact via fp32 FMA) ----
  int amax=0, smax=INT_MIN;
  for (int i=tid; i<12544; i+=256){
    int oc = i/784; int pos = i-oc*784; int oy=pos/28; int ox=pos-oy*28;
    float acc = b1f[oc];
    const float* wr = m1f_s + oc*9;
#pragma unroll
    for (int dy=-1; dy<=1; dy++){
      int iy=oy+dy;
      if ((unsigned)iy<28u){
#pragma unroll
        for (int dx=-1; dx<=1; dx++){
          int ix=ox+dx;
          if ((unsigned)ix<28u) acc = fmaf(k0f[iy*28+ix], wr[(dy+1)*3+(dx+1)], acc);
        }
      }
    }
    if constexpr (MODE==0){
      int v=(int)acc; amax=max(amax,abs(v)); smax=max(smax,v);
    } else {
      float y  = sb1*acc;
      float k1 = clampf(rintf(y/sy1), -128.f, 127.f);
      float n1 = (k1>0.f) ? clampf(rintf((sy1*k1)/sr1), 0.f, 15.f) : 0.f;
      n1buf[i] = (unsigned char)n1;
    }
  }
  if constexpr (MODE==0){
    reduce2_atomic(amax, smax, &WS_I(ws)[1], &WS_I(ws)[2]);
    return;
  } else {
  __syncthreads();
  // ---- pool1 + uint4->int8 requant table -> q2f ----
  for (int i=tid; i<3136; i+=256){
    int c=i/196, s=i-c*196, py=s/14, px=s-py*14;
    int b = c*784 + (py*2)*28 + px*2;
    int n = max(max((int)n1buf[b],(int)n1buf[b+1]), max((int)n1buf[b+28],(int)n1buf[b+29]));
    q2f[i] = (float)q2s[n];
  }
  __syncthreads();
  for (int i=tid; i<4608; i+=256) m2f_s[i] = WS_M2F(ws)[i];
  if (tid<32) b2f[tid] = (float)WS_B2L(ws)[tid];
  __shared__ int q3s[16]; __shared__ int bfs[16];
  if constexpr (MODE==2){
    if (tid<16) q3s[tid]=WS_Q3T(ws)[tid];
    if (tid<16) bfs[tid]=WS_BFL(ws)[tid];
  }
  __syncthreads();

  // ---- conv2: thread = position, acc over all 32 oc ----
  float acc2[32];
  const bool act = tid<196;
  int py=0,px=0;
  if (act){ py = tid/14; px = tid-py*14; }
#pragma unroll
  for (int oc=0;oc<32;oc++) acc2[oc] = act ? b2f[oc] : 0.f;
  if (act){
#pragma unroll
    for (int t9=0;t9<9;t9++){
      int dy=t9/3-1, dx=t9-(t9/3)*3-1;
      int iy=py+dy, ix=px+dx;
      if ((unsigned)iy<14u && (unsigned)ix<14u){
        int ip = iy*14+ix;
        for (int c=0;c<16;c++){
          float a = q2f[c*196+ip];
          const float* mr = m2f_s + (t9*16+c)*32;
#pragma unroll
          for (int oc=0;oc<32;oc++) acc2[oc] = fmaf(a, mr[oc], acc2[oc]);
        }
      }
    }
  }

  if constexpr (MODE==1){
    int amax2=0, smax2=INT_MIN;
    if (act){
#pragma unroll
      for (int oc=0;oc<32;oc++){ int v=(int)acc2[oc]; amax2=max(amax2,abs(v)); smax2=max(smax2,v); }
    }
    reduce2_atomic(amax2, smax2, &WS_I(ws)[3], &WS_I(ws)[4]);
    return;
  } else if constexpr (MODE==2){
    const float sb2=F[8], sy2=F[9], sr2=F[10];
    if (act){
#pragma unroll
      for (int oc=0;oc<32;oc++){
        float y2 = sb2*acc2[oc];
        float k2 = clampf(rintf(y2/sy2), -128.f, 127.f);
        float n2 = (k2>0.f) ? clampf(rintf((sy2*k2)/sr2), 0.f, 15.f) : 0.f;
        n2buf[oc*196+tid] = (unsigned char)n2;
      }
    }
    __syncthreads();
    // ---- pool2 + q3 table ----
    for (int i=tid;i<1568;i+=256){
      int c=i/49, s=i-c*49, p2y=s/7, p2x=s-p2y*7;
      int b = c*196 + p2y*2*14 + p2x*2;
      int n = max(max((int)n2buf[b],(int)n2buf[b+1]), max((int)n2buf[b+14],(int)n2buf[b+15]));
      q3f[i] = (float)q3s[n];
    }
    __syncthreads();
    // ---- fc (integer-exact fp32) ----
    const float* mff = WS_MFF(ws);
    float a10[10];
#pragma unroll
    for (int o=0;o<10;o++) a10[o]=0.f;
    for (int k=tid;k<1568;k+=256){
      float qa = q3f[k];
#pragma unroll
      for (int o=0;o<10;o++) a10[o] = fmaf(qa, mff[o*1568+k], a10[o]);
    }
#pragma unroll
    for (int o=0;o<10;o++){
#pragma unroll
      for (int off=32; off; off>>=1) a10[o] += __shfl_down(a10[o], off, 64);
    }
    int w = tid>>6, l = tid&63;
    if (l==0){
#pragma unroll
      for (int o=0;o<10;o++) redf[w*10+o] = a10[o];
    }
    __syncthreads();
    if (tid<10){
      float s = redf[tid] + redf[10+tid] + redf[20+tid] + redf[30+tid];
      int I3v = (int)s + bfs[tid];
      i3out[img*10+tid] = I3v;
      redf[tid] = (float)abs(I3v);
    }
    __syncthreads();
    if (tid==0){
      int m=0;
#pragma unroll
      for (int o=0;o<10;o++) m = max(m, (int)redf[o]);
      atomicMax(&WS_I(ws)[5], m);
    }
  }
  }
}

__global__ void k_out(char* ws, float* __restrict__ out){
  float* F=WS_F(ws);
  float sb3=F[13], sy3=F[14];
  int i = blockIdx.x*blockDim.x + threadIdx.x;
  if (i < NB*10){
    int iv = ((const int*)out)[i];      // I3 stored in d_out by k_fused<2>
    float y = sb3*(float)iv;
    float q = clampf(rintf(y/sy3), -128.f, 127.f);
    out[i] = q*sy3;
  }
}

extern "C" void kernel_launch(void* const* d_in, const int* in_sizes, int n_in,
                              void* d_out, int out_size, void* d_ws, size_t ws_size,
                              hipStream_t stream){
  const float* x  = (const float*)d_in[0];
  const float* w1 = (const float*)d_in[1];
  const float* b1 = (const float*)d_in[2];
  const float* w2 = (const float*)d_in[3];
  const float* b2 = (const float*)d_in[4];
  const float* wf = (const float*)d_in[5];
  const float* bf = (const float*)d_in[6];
  char* ws = (char*)d_ws;
  float* out = (float*)d_out;
  int* i3 = (int*)d_out;

  k_init<<<dim3(1), dim3(64), 0, stream>>>(ws);
  k_absx<<<dim3(2048), dim3(256), 0, stream>>>(x, ws);
  k_wq<<<dim3(1), dim3(256), 0, stream>>>(w1, b1, w2, wf, ws);
  k_fused<0><<<dim3(NB), dim3(256), 0, stream>>>(x, ws, i3);
  k_s1<<<dim3(1), dim3(64), 0, stream>>>(b2, ws);
  k_fused<1><<<dim3(NB), dim3(256), 0, stream>>>(x, ws, i3);
  k_s2<<<dim3(1), dim3(64), 0, stream>>>(bf, ws);
  k_fused<2><<<dim3(NB), dim3(256), 0, stream>>>(x, ws, i3);
  k_s3<<<dim3(1), dim3(1), 0, stream>>>(ws);
  k_out<<<dim3((NB*10+255)/256), dim3(256), 0, stream>>>(ws, out);
}

// Round 2
// 646.785 us; speedup vs baseline: 2.2338x; 2.2338x over previous
//
#include <hip/hip_runtime.h>
#include <climits>

#define NB 8192
#define EPSQ 1e-8f

using i32x4  = __attribute__((ext_vector_type(4)))  int;
using i32x16 = __attribute__((ext_vector_type(16))) int;

// ---- ws layout (byte offsets) ----
// scalars F: 0 s0,1 sx1,2 sw1,3 sb1,4 sy1,5 sr1,6 sx2,7 sw2,8 sb2,9 sy2,10 sr2,11 sx3,12 swf,13 sb3,14 sy3
#define WS_F(ws)     ((float*)(ws))
#define WS_I(ws)     ((int*)((char*)(ws)+128))      // 0 maxabs_x bits,1 maxabsI1,2 maxI1,3 maxabsI2,4 maxI2,5 maxabsI3
#define WS_B1L(ws)   ((int*)((char*)(ws)+384))      // [16]
#define WS_B2L(ws)   ((int*)((char*)(ws)+448))      // [32]
#define WS_BFL(ws)   ((int*)((char*)(ws)+576))      // [16]
#define WS_M1F(ws)   ((float*)((char*)(ws)+640))    // [144]
#define WS_B2FR(ws)  ((char*)(ws)+2048)             // [5][64][16] = 5120 packed i8 B-fragments
#define WS_Q2TAB(ws) ((signed char*)((char*)(ws)+7168))  // [256] k1 level -> q2 int8 level
#define WS_Q3TAB(ws) ((signed char*)((char*)(ws)+7424))  // [256] k2 level -> q3 int8 level
#define WS_MFF(ws)   ((float*)((char*)(ws)+20480))  // [10][1568] float fc weight levels
#define WS_Q2G_OFF   131072                          // [NB][196][16] i8 pooled conv1 levels (25.7MB)

__device__ __forceinline__ float clampf(float v, float lo, float hi){ return fminf(fmaxf(v, lo), hi); }

__device__ __forceinline__ float wave_max_f(float v){
#pragma unroll
  for (int off=32; off; off>>=1) v = fmaxf(v, __shfl_down(v, off, 64));
  return v;
}
__device__ __forceinline__ int wave_max_i(int v){
#pragma unroll
  for (int off=32; off; off>>=1) v = max(v, __shfl_down(v, off, 64));
  return v;
}

__device__ __forceinline__ void reduce2_atomic(int amax, int smax, int* gA, int* gS){
  amax = wave_max_i(amax); smax = wave_max_i(smax);
  __shared__ int sA[4], sS[4];
  int w = threadIdx.x>>6, l = threadIdx.x&63;
  if (l==0){ sA[w]=amax; sS[w]=smax; }
  __syncthreads();
  if (threadIdx.x==0){
#pragma unroll
    for (int i=1;i<4;i++){ amax=max(amax,sA[i]); smax=max(smax,sS[i]); }
    atomicMax(gA, amax); atomicMax(gS, smax);
  }
}

__global__ void k_init(char* ws){
  int* I = WS_I(ws);
  if (threadIdx.x==0){ I[0]=0; I[1]=0; I[2]=INT_MIN; I[3]=0; I[4]=INT_MIN; I[5]=0; }
}

__global__ void k_absx(const float* __restrict__ x, char* ws){
  const float4* x4 = (const float4*)x;
  const int n4 = NB*784/4;
  float m = 0.f;
  for (int i = blockIdx.x*blockDim.x + threadIdx.x; i < n4; i += gridDim.x*blockDim.x){
    float4 v = x4[i];
    m = fmaxf(m, fmaxf(fmaxf(fabsf(v.x),fabsf(v.y)), fmaxf(fabsf(v.z),fabsf(v.w))));
  }
  m = wave_max_f(m);
  __shared__ float sm[4];
  int w = threadIdx.x>>6;
  if ((threadIdx.x&63)==0) sm[w]=m;
  __syncthreads();
  if (threadIdx.x==0){
    m = fmaxf(fmaxf(sm[0],sm[1]), fmaxf(sm[2],sm[3]));
    atomicMax((unsigned*)WS_I(ws), __float_as_uint(m));
  }
}

__global__ void k_wq(const float* __restrict__ w1, const float* __restrict__ b1,
                     const float* __restrict__ w2, const float* __restrict__ wf,
                     char* ws){
  __shared__ float red[256];
  float* F = WS_F(ws);
  int* I = WS_I(ws);
  int t = threadIdx.x;
  auto bmaxabs = [&](const float* p, int n)->float{
    float m=0.f; for (int i=t;i<n;i+=256) m=fmaxf(m,fabsf(p[i]));
    red[t]=m; __syncthreads();
    for (int s=128;s;s>>=1){ if (t<s) red[t]=fmaxf(red[t],red[t+s]); __syncthreads(); }
    float r=red[0]; __syncthreads(); return r;
  };
  float mw1 = bmaxabs(w1,144);
  float mw2 = bmaxabs(w2,4608);
  float mwf = bmaxabs(wf,15680);
  float mx  = __uint_as_float((unsigned)I[0]);
  float s0  = fmaxf(mx/127.f, EPSQ);
  float sx1 = fmaxf((127.f*s0)/127.f, EPSQ);   // max|h0| maps to level 127
  float sw1 = fmaxf(mw1/7.f, EPSQ);
  float sw2 = fmaxf(mw2/7.f, EPSQ);
  float swf = fmaxf(mwf/7.f, EPSQ);
  float sb1 = sx1*sw1;
  if (t==0){ F[0]=s0; F[1]=sx1; F[2]=sw1; F[3]=sb1; F[7]=sw2; F[12]=swf; }
  float* m1f = WS_M1F(ws);
  for (int i=t;i<144;i+=256) m1f[i] = clampf(rintf(w1[i]/sw1), -7.f, 7.f);
  if (t<16) WS_B1L(ws)[t] = (int)rintf(b1[t]/sb1);
  // packed B-fragments for mfma_i32_32x32x32_i8: chunk c covers k=[32c,32c+32);
  // lane l: col oc=l&31, k=(l>>5)*16+j  ->  tap = 2c+(l>>5), channel = j
  for (int i=t;i<5120;i+=256){
    int chunk=i>>10, r=i&1023, ln=r>>4, j=r&15;
    int tap=2*chunk+(ln>>5), oc=ln&31;
    signed char v=0;
    if (tap<9) v=(signed char)clampf(rintf(w2[oc*144 + j*9 + tap]/sw2), -7.f, 7.f);
    WS_B2FR(ws)[i]=v;
  }
  float* mff = WS_MFF(ws);
  for (int i=t;i<15680;i+=256) mff[i] = clampf(rintf(wf[i]/swf), -7.f, 7.f);
}

__global__ void k_s1(const float* __restrict__ b2, char* ws){
  float* F=WS_F(ws); int* I=WS_I(ws);
  __shared__ float sh[4];
  int t=threadIdx.x;
  if (t==0){
    float sb1=F[3];
    float sy1 = fmaxf((sb1*(float)I[1])/127.f, EPSQ);
    float mp  = sb1*(float)I[2];
    float P1  = clampf(rintf(mp/sy1), 0.f, 127.f);
    float sr1 = fmaxf((sy1*P1)/15.f, EPSQ);
    float N1  = clampf(rintf((sy1*P1)/sr1), 0.f, 15.f);
    float sx2 = fmaxf((N1*sr1)/127.f, EPSQ);
    float sb2 = sx2*F[7];
    F[4]=sy1; F[5]=sr1; F[6]=sx2; F[8]=sb2;
    sh[0]=sy1; sh[1]=sr1; sh[2]=sx2; sh[3]=sb2;
  }
  __syncthreads();
  float sy1=sh[0], sr1=sh[1], sx2=sh[2], sb2=sh[3];
  // k1 (int8 conv1 level) -> q2 (int8 conv2-input level); monotone so pool commutes
  int k = t-128;
  float n = (k>0) ? clampf(rintf((sy1*(float)k)/sr1), 0.f, 15.f) : 0.f;
  WS_Q2TAB(ws)[t] = (signed char)clampf(rintf((n*sr1)/sx2), -128.f, 127.f);
  if (t<32) WS_B2L(ws)[t] = (int)rintf(b2[t]/sb2);
}

__global__ void k_s2(const float* __restrict__ bf, char* ws){
  float* F=WS_F(ws); int* I=WS_I(ws);
  __shared__ float sh[4];
  int t=threadIdx.x;
  if (t==0){
    float sb2=F[8];
    float sy2 = fmaxf((sb2*(float)I[3])/127.f, EPSQ);
    float mp  = sb2*(float)I[4];
    float P2  = clampf(rintf(mp/sy2), 0.f, 127.f);
    float sr2 = fmaxf((sy2*P2)/15.f, EPSQ);
    float N2  = clampf(rintf((sy2*P2)/sr2), 0.f, 15.f);
    float sx3 = fmaxf((N2*sr2)/127.f, EPSQ);
    float sb3 = sx3*F[12];
    F[9]=sy2; F[10]=sr2; F[11]=sx3; F[13]=sb3;
    sh[0]=sy2; sh[1]=sr2; sh[2]=sx3; sh[3]=sb3;
  }
  __syncthreads();
  float sy2=sh[0], sr2=sh[1], sx3=sh[2], sb3=sh[3];
  int k = t-128;
  float n = (k>0) ? clampf(rintf((sy2*(float)k)/sr2), 0.f, 15.f) : 0.f;
  WS_Q3TAB(ws)[t] = (signed char)clampf(rintf((n*sr2)/sx3), -128.f, 127.f);
  if (t<16) WS_BFL(ws)[t] = (t<10) ? (int)rintf(bf[t]/sb3) : 0;
}

__global__ void k_s3(char* ws){
  float* F=WS_F(ws); int* I=WS_I(ws);
  if (threadIdx.x==0) F[14] = fmaxf((F[13]*(float)I[5])/127.f, EPSQ);
}

// MODE 0: conv1 int-reduce.  MODE 1: conv1+pool1 (store q2 levels), conv2 MFMA int-reduce.
// MODE 2: (load or recompute q2) conv2 MFMA requant + pool2 + fc -> I3 in d_out + maxabs.
template<int MODE, bool SKIP>
__global__ __launch_bounds__(256) void k_fused(const float* __restrict__ x, char* __restrict__ ws,
                                               char* __restrict__ q2g, int* __restrict__ i3out){
  constexpr bool C1 = (MODE<2) || (!SKIP);
  constexpr int OFF_K0=0, OFF_M1=3600, OFF_B1=4176, OFF_N1=4240;
  constexpr int OFF_Q2L = C1 ? 16784 : 0;      // [196][16] i8, 16B aligned
  constexpr int OFF_B2I = OFF_Q2L+3136;        // int[32]
  constexpr int OFF_Q2T = OFF_B2I+128;         // i8[256]
  constexpr int OFF_N2  = OFF_Q2T+256;         // i8[32][196]
  constexpr int OFF_Q3T = OFF_N2+6272;         // i8[256]
  constexpr int OFF_BFS = OFF_Q3T+256;         // int[16]
  constexpr int OFF_Q3F = OFF_BFS+64;          // float[1568]
  constexpr int OFF_RED = OFF_Q3F+6272;        // float[40]
  constexpr int ARENA = (MODE==0) ? 4240 : ((MODE==1) ? OFF_N2 : OFF_RED+160);
  __shared__ __align__(16) char arena[ARENA];

  const int tid=threadIdx.x, img=blockIdx.x;
  const int lane=tid&63, wid=tid>>6;
  const float* F=WS_F(ws);

  signed char* q2l = (signed char*)(arena+OFF_Q2L);
  int* b2li = (int*)(arena+OFF_B2I);

  if constexpr (C1){
    float* k0p=(float*)(arena+OFF_K0);         // zero-padded 30x30
    float* m1f_s=(float*)(arena+OFF_M1);
    float* b1f=(float*)(arena+OFF_B1);
    signed char* n1buf=(signed char*)(arena+OFF_N1);  // k1 levels [16][784]
    const float s0=F[0];
    const float* xi=x+img*784;
    for (int i=tid;i<900;i+=256){
      int r=i/30, c=i-r*30;
      float v=0.f;
      if (r>=1 && r<=28 && c>=1 && c<=28) v=clampf(rintf(xi[(r-1)*28+(c-1)]/s0),-128.f,127.f);
      k0p[i]=v;
    }
    for (int i=tid;i<144;i+=256) m1f_s[i]=WS_M1F(ws)[i];
    if (tid<16) b1f[tid]=(float)WS_B1L(ws)[tid];
    if constexpr (MODE>=1){
      ((signed char*)(arena+OFF_Q2T))[tid]=WS_Q2TAB(ws)[tid];
      if (tid<32) b2li[tid]=WS_B2L(ws)[tid];
    }
    if constexpr (MODE==2){
      ((signed char*)(arena+OFF_Q3T))[tid]=WS_Q3TAB(ws)[tid];
      if (tid<16) ((int*)(arena+OFF_BFS))[tid]=WS_BFL(ws)[tid];
    }
    __syncthreads();

    float sb1=0.f, sy1=0.f;
    if constexpr (MODE>=1){ sb1=F[3]; sy1=F[4]; }
    int amax=0, smax=INT_MIN;
    for (int i=tid;i<12544;i+=256){
      int oc=i/784, pos=i-oc*784, oy=pos/28, ox=pos-oy*28;
      const float* wr=m1f_s+oc*9;
      const float* kp=k0p+oy*30+ox;
      float acc=b1f[oc];
      acc=fmaf(kp[0],wr[0],acc); acc=fmaf(kp[1],wr[1],acc); acc=fmaf(kp[2],wr[2],acc);
      acc=fmaf(kp[30],wr[3],acc); acc=fmaf(kp[31],wr[4],acc); acc=fmaf(kp[32],wr[5],acc);
      acc=fmaf(kp[60],wr[6],acc); acc=fmaf(kp[61],wr[7],acc); acc=fmaf(kp[62],wr[8],acc);
      if constexpr (MODE==0){
        int v=(int)acc; amax=max(amax,v<0?-v:v); smax=max(smax,v);
      } else {
        n1buf[i]=(signed char)clampf(rintf((sb1*acc)/sy1),-128.f,127.f);
      }
    }
    if constexpr (MODE==0){
      reduce2_atomic(amax,smax,&WS_I(ws)[1],&WS_I(ws)[2]);
      return;
    }
    __syncthreads();
    // pool1 on k1 levels (monotone) -> q2 int8 levels, channel-last [196][16]
    {
      signed char* q2t_s=(signed char*)(arena+OFF_Q2T);
      for (int i=tid;i<3136;i+=256){
        int s=i>>4, c=i&15, py=s/14, px=s-py*14;
        int b=c*784+py*56+px*2;
        int m=max(max((int)n1buf[b],(int)n1buf[b+1]),max((int)n1buf[b+28],(int)n1buf[b+29]));
        q2l[i]=q2t_s[m+128];
      }
    }
    __syncthreads();
    if constexpr (MODE==1){
      if (q2g){
        for (int i=tid;i<196;i+=256) ((i32x4*)(q2g+(size_t)img*3136))[i]=((const i32x4*)q2l)[i];
      }
    }
  } else {
    for (int i=tid;i<196;i+=256) ((i32x4*)q2l)[i]=((const i32x4*)(q2g+(size_t)img*3136))[i];
    if (tid<32) b2li[tid]=WS_B2L(ws)[tid];
    ((signed char*)(arena+OFF_Q3T))[tid]=WS_Q3TAB(ws)[tid];
    if (tid<16) ((int*)(arena+OFF_BFS))[tid]=WS_BFL(ws)[tid];
    __syncthreads();
  }

  // ---- conv2 as [196x144]x[144x32] i8 GEMM via mfma_i32_32x32x32_i8 ----
  i32x4 bfr[5];
  {
    const i32x4* bg=(const i32x4*)WS_B2FR(ws);
#pragma unroll
    for (int c=0;c<5;c++) bfr[c]=bg[c*64+lane];
  }
  const int col=lane&31, h=lane>>5;
  const int bias=b2li[col];
  int amax2=0, smax2=INT_MIN;
  float sb2=0.f, sy2=0.f;
  signed char* n2buf=nullptr;
  if constexpr (MODE==2){ sb2=F[8]; sy2=F[9]; n2buf=(signed char*)(arena+OFF_N2); }

  for (int mt=wid; mt<7; mt+=4){
    const int p=mt*32+col;
    const bool pv=p<196;
    const int oy=p/14, ox=p-oy*14;
    i32x16 acc;
#pragma unroll
    for (int r=0;r<16;r++) acc[r]=bias;
#pragma unroll
    for (int c=0;c<5;c++){
      const int tap=2*c+h;
      i32x4 a={0,0,0,0};
      if (pv && tap<9){
        const int iy=oy+tap/3-1, ix=ox+tap-(tap/3)*3-1;
        if ((unsigned)iy<14u && (unsigned)ix<14u) a=*(const i32x4*)(q2l+(iy*14+ix)*16);
      }
      acc=__builtin_amdgcn_mfma_i32_32x32x32_i8(a,bfr[c],acc,0,0,0);
    }
#pragma unroll
    for (int r=0;r<16;r++){
      const int row=(r&3)+8*(r>>2)+4*h;
      const int pp=mt*32+row;
      if (pp<196){
        const int v=acc[r];
        if constexpr (MODE==1){ amax2=max(amax2,v<0?-v:v); smax2=max(smax2,v); }
        else if constexpr (MODE==2){
          n2buf[col*196+pp]=(signed char)clampf(rintf((sb2*(float)v)/sy2),-128.f,127.f);
        }
      }
    }
  }
  if constexpr (MODE==1){
    reduce2_atomic(amax2,smax2,&WS_I(ws)[3],&WS_I(ws)[4]);
    return;
  }
  if constexpr (MODE==2){
    __syncthreads();
    signed char* q3t_s=(signed char*)(arena+OFF_Q3T);
    float* q3f=(float*)(arena+OFF_Q3F);
    for (int i=tid;i<1568;i+=256){
      int cch=i/49, s=i-cch*49, qy=s/7, qx=s-qy*7;
      int b=cch*196+qy*28+qx*2;
      int m=max(max((int)n2buf[b],(int)n2buf[b+1]),max((int)n2buf[b+14],(int)n2buf[b+15]));
      q3f[i]=(float)q3t_s[m+128];
    }
    __syncthreads();
    const float* mff=WS_MFF(ws);
    float a10[10];
#pragma unroll
    for (int o=0;o<10;o++) a10[o]=0.f;
    for (int k=tid;k<1568;k+=256){
      float qa=q3f[k];
#pragma unroll
      for (int o=0;o<10;o++) a10[o]=fmaf(qa,mff[o*1568+k],a10[o]);
    }
#pragma unroll
    for (int o=0;o<10;o++){
#pragma unroll
      for (int off=32;off;off>>=1) a10[o]+=__shfl_down(a10[o],off,64);
    }
    float* redf=(float*)(arena+OFF_RED);
    int* bfs=(int*)(arena+OFF_BFS);
    if (lane==0){
#pragma unroll
      for (int o=0;o<10;o++) redf[wid*10+o]=a10[o];
    }
    __syncthreads();
    if (tid<10){
      float s=redf[tid]+redf[10+tid]+redf[20+tid]+redf[30+tid];
      int I3v=(int)s+bfs[tid];
      i3out[img*10+tid]=I3v;
      redf[tid]=(float)(I3v<0?-I3v:I3v);
    }
    __syncthreads();
    if (tid==0){
      int m=0;
#pragma unroll
      for (int o=0;o<10;o++) m=max(m,(int)redf[o]);
      atomicMax(&WS_I(ws)[5],m);
    }
  }
}

__global__ void k_out(char* ws, float* __restrict__ out){
  float* F=WS_F(ws);
  float sb3=F[13], sy3=F[14];
  int i = blockIdx.x*blockDim.x + threadIdx.x;
  if (i < NB*10){
    int iv = ((const int*)out)[i];
    float y = sb3*(float)iv;
    float q = clampf(rintf(y/sy3), -128.f, 127.f);
    out[i] = q*sy3;
  }
}

extern "C" void kernel_launch(void* const* d_in, const int* in_sizes, int n_in,
                              void* d_out, int out_size, void* d_ws, size_t ws_size,
                              hipStream_t stream){
  const float* x  = (const float*)d_in[0];
  const float* w1 = (const float*)d_in[1];
  const float* b1 = (const float*)d_in[2];
  const float* w2 = (const float*)d_in[3];
  const float* b2 = (const float*)d_in[4];
  const float* wf = (const float*)d_in[5];
  const float* bf = (const float*)d_in[6];
  char* ws = (char*)d_ws;
  float* out = (float*)d_out;
  int* i3 = (int*)d_out;

  const bool big = ws_size >= (size_t)WS_Q2G_OFF + (size_t)NB*3136;
  char* q2g = big ? (ws + WS_Q2G_OFF) : nullptr;

  k_init<<<dim3(1), dim3(64), 0, stream>>>(ws);
  k_absx<<<dim3(2048), dim3(256), 0, stream>>>(x, ws);
  k_wq<<<dim3(1), dim3(256), 0, stream>>>(w1, b1, w2, wf, ws);
  k_fused<0,false><<<dim3(NB), dim3(256), 0, stream>>>(x, ws, nullptr, i3);
  k_s1<<<dim3(1), dim3(256), 0, stream>>>(b2, ws);
  k_fused<1,false><<<dim3(NB), dim3(256), 0, stream>>>(x, ws, q2g, i3);
  k_s2<<<dim3(1), dim3(256), 0, stream>>>(bf, ws);
  if (big) k_fused<2,true ><<<dim3(NB), dim3(256), 0, stream>>>(x, ws, q2g, i3);
  else     k_fused<2,false><<<dim3(NB), dim3(256), 0, stream>>>(x, ws, nullptr, i3);
  k_s3<<<dim3(1), dim3(1), 0, stream>>>(ws);
  k_out<<<dim3((NB*10+255)/256), dim3(256), 0, stream>>>(ws, out);
}

// Round 3
// 586.253 us; speedup vs baseline: 2.4645x; 1.1033x over previous
//
#include <hip/hip_runtime.h>
#include <climits>

#define NB 8192
#define EPSQ 1e-8f

using i32x4  = __attribute__((ext_vector_type(4)))  int;
using i32x16 = __attribute__((ext_vector_type(16))) int;

// ---- ws layout (byte offsets) ----
// scalars F: 0 s0,1 sx1,2 sw1,3 sb1,4 sy1,5 sr1,6 sx2,7 sw2,8 sb2,9 sy2,10 sr2,11 sx3,12 swf,13 sb3,14 sy3
#define WS_F(ws)     ((float*)(ws))
#define WS_I(ws)     ((int*)((char*)(ws)+128))      // 0 maxabs_x bits,1 maxabsI1,2 maxI1,3 maxabsI2,4 maxI2,5 maxabsI3
#define WS_B1L(ws)   ((int*)((char*)(ws)+384))      // [16]
#define WS_B2L(ws)   ((int*)((char*)(ws)+448))      // [32]
#define WS_BFL(ws)   ((int*)((char*)(ws)+576))      // [16]
#define WS_M1F(ws)   ((float*)((char*)(ws)+640))    // [144]
#define WS_B2FR(ws)  ((char*)(ws)+2048)             // [5][64][16] = 5120 packed i8 B-fragments (conv2)
#define WS_Q2TAB(ws) ((signed char*)((char*)(ws)+7168))  // [256] k1 level -> q2 int8 level
#define WS_Q3TAB(ws) ((signed char*)((char*)(ws)+7424))  // [256] k2 level -> q3 int8 level
#define WS_B1FR(ws)  ((char*)(ws)+7680)             // [64][16] = 1024 packed i8 B-fragments (conv1)
#define WS_MFF(ws)   ((float*)((char*)(ws)+20480))  // [10][1568] float fc weight levels
#define WS_BIG_OFF   131072                          // tier A: int16 pooled I1 [NB][196][16] (51.4MB)
                                                     // tier B: q2g i8 [NB][196][16] (25.7MB)

__device__ __forceinline__ float clampf(float v, float lo, float hi){ return fminf(fmaxf(v, lo), hi); }

__device__ __forceinline__ float wave_max_f(float v){
#pragma unroll
  for (int off=32; off; off>>=1) v = fmaxf(v, __shfl_down(v, off, 64));
  return v;
}
__device__ __forceinline__ int wave_max_i(int v){
#pragma unroll
  for (int off=32; off; off>>=1) v = max(v, __shfl_down(v, off, 64));
  return v;
}

__device__ __forceinline__ void reduce2_atomic(int amax, int smax, int* gA, int* gS){
  amax = wave_max_i(amax); smax = wave_max_i(smax);
  __shared__ int sA[4], sS[4];
  int w = threadIdx.x>>6, l = threadIdx.x&63;
  if (l==0){ sA[w]=amax; sS[w]=smax; }
  __syncthreads();
  if (threadIdx.x==0){
#pragma unroll
    for (int i=1;i<4;i++){ amax=max(amax,sA[i]); smax=max(smax,sS[i]); }
    atomicMax(gA, amax); atomicMax(gS, smax);
  }
}

__global__ void k_init(char* ws){
  int* I = WS_I(ws);
  if (threadIdx.x==0){ I[0]=0; I[1]=0; I[2]=INT_MIN; I[3]=0; I[4]=INT_MIN; I[5]=0; }
}

__global__ void k_absx(const float* __restrict__ x, char* ws){
  const float4* x4 = (const float4*)x;
  const int n4 = NB*784/4;
  float m = 0.f;
  for (int i = blockIdx.x*blockDim.x + threadIdx.x; i < n4; i += gridDim.x*blockDim.x){
    float4 v = x4[i];
    m = fmaxf(m, fmaxf(fmaxf(fabsf(v.x),fabsf(v.y)), fmaxf(fabsf(v.z),fabsf(v.w))));
  }
  m = wave_max_f(m);
  __shared__ float sm[4];
  int w = threadIdx.x>>6;
  if ((threadIdx.x&63)==0) sm[w]=m;
  __syncthreads();
  if (threadIdx.x==0){
    m = fmaxf(fmaxf(sm[0],sm[1]), fmaxf(sm[2],sm[3]));
    atomicMax((unsigned*)WS_I(ws), __float_as_uint(m));
  }
}

__global__ void k_wq(const float* __restrict__ w1, const float* __restrict__ b1,
                     const float* __restrict__ w2, const float* __restrict__ wf,
                     char* ws){
  __shared__ float red[256];
  float* F = WS_F(ws);
  int* I = WS_I(ws);
  int t = threadIdx.x;
  auto bmaxabs = [&](const float* p, int n)->float{
    float m=0.f; for (int i=t;i<n;i+=256) m=fmaxf(m,fabsf(p[i]));
    red[t]=m; __syncthreads();
    for (int s=128;s;s>>=1){ if (t<s) red[t]=fmaxf(red[t],red[t+s]); __syncthreads(); }
    float r=red[0]; __syncthreads(); return r;
  };
  float mw1 = bmaxabs(w1,144);
  float mw2 = bmaxabs(w2,4608);
  float mwf = bmaxabs(wf,15680);
  float mx  = __uint_as_float((unsigned)I[0]);
  float s0  = fmaxf(mx/127.f, EPSQ);
  float sx1 = fmaxf((127.f*s0)/127.f, EPSQ);   // max|h0| maps to level 127
  float sw1 = fmaxf(mw1/7.f, EPSQ);
  float sw2 = fmaxf(mw2/7.f, EPSQ);
  float swf = fmaxf(mwf/7.f, EPSQ);
  float sb1 = sx1*sw1;
  if (t==0){ F[0]=s0; F[1]=sx1; F[2]=sw1; F[3]=sb1; F[7]=sw2; F[12]=swf; }
  float* m1f = WS_M1F(ws);
  for (int i=t;i<144;i+=256) m1f[i] = clampf(rintf(w1[i]/sw1), -7.f, 7.f);
  if (t<16) WS_B1L(ws)[t] = (int)rintf(b1[t]/sb1);
  // conv2 B-fragments for mfma_i32_32x32x32_i8: chunk c: lane l -> col oc=l&31, k=(l>>5)*16+j
  for (int i=t;i<5120;i+=256){
    int chunk=i>>10, r=i&1023, ln=r>>4, j=r&15;
    int tap=2*chunk+(ln>>5), oc=ln&31;
    signed char v=0;
    if (tap<9) v=(signed char)clampf(rintf(w2[oc*144 + j*9 + tap]/sw2), -7.f, 7.f);
    WS_B2FR(ws)[i]=v;
  }
  // conv1 B-fragments: single K-chunk; k = tap 0..8 (else 0), col = oc (0..15, else 0)
  for (int i=t;i<1024;i+=256){
    int ln=i>>4, j=i&15;
    int k=(ln>>5)*16+j, oc=ln&31;
    signed char v=0;
    if (k<9 && oc<16) v=(signed char)clampf(rintf(w1[oc*9+k]/sw1), -7.f, 7.f);
    WS_B1FR(ws)[i]=v;
  }
  float* mff = WS_MFF(ws);
  for (int i=t;i<15680;i+=256) mff[i] = clampf(rintf(wf[i]/swf), -7.f, 7.f);
}

__global__ void k_s1(const float* __restrict__ b2, char* ws){
  float* F=WS_F(ws); int* I=WS_I(ws);
  __shared__ float sh[4];
  int t=threadIdx.x;
  if (t==0){
    float sb1=F[3];
    float sy1 = fmaxf((sb1*(float)I[1])/127.f, EPSQ);
    float mp  = sb1*(float)I[2];
    float P1  = clampf(rintf(mp/sy1), 0.f, 127.f);
    float sr1 = fmaxf((sy1*P1)/15.f, EPSQ);
    float N1  = clampf(rintf((sy1*P1)/sr1), 0.f, 15.f);
    float sx2 = fmaxf((N1*sr1)/127.f, EPSQ);
    float sb2 = sx2*F[7];
    F[4]=sy1; F[5]=sr1; F[6]=sx2; F[8]=sb2;
    sh[0]=sy1; sh[1]=sr1; sh[2]=sx2; sh[3]=sb2;
  }
  __syncthreads();
  float sy1=sh[0], sr1=sh[1], sx2=sh[2], sb2=sh[3];
  // k1 (int8 conv1 level) -> q2 (int8 conv2-input level); monotone so pool commutes
  int k = t-128;
  float n = (k>0) ? clampf(rintf((sy1*(float)k)/sr1), 0.f, 15.f) : 0.f;
  WS_Q2TAB(ws)[t] = (signed char)clampf(rintf((n*sr1)/sx2), -128.f, 127.f);
  if (t<32) WS_B2L(ws)[t] = (int)rintf(b2[t]/sb2);
}

__global__ void k_s2(const float* __restrict__ bf, char* ws){
  float* F=WS_F(ws); int* I=WS_I(ws);
  __shared__ float sh[4];
  int t=threadIdx.x;
  if (t==0){
    float sb2=F[8];
    float sy2 = fmaxf((sb2*(float)I[3])/127.f, EPSQ);
    float mp  = sb2*(float)I[4];
    float P2  = clampf(rintf(mp/sy2), 0.f, 127.f);
    float sr2 = fmaxf((sy2*P2)/15.f, EPSQ);
    float N2  = clampf(rintf((sy2*P2)/sr2), 0.f, 15.f);
    float sx3 = fmaxf((N2*sr2)/127.f, EPSQ);
    float sb3 = sx3*F[12];
    F[9]=sy2; F[10]=sr2; F[11]=sx3; F[13]=sb3;
    sh[0]=sy2; sh[1]=sr2; sh[2]=sx3; sh[3]=sb3;
  }
  __syncthreads();
  float sy2=sh[0], sr2=sh[1], sx3=sh[2], sb3=sh[3];
  int k = t-128;
  float n = (k>0) ? clampf(rintf((sy2*(float)k)/sr2), 0.f, 15.f) : 0.f;
  WS_Q3TAB(ws)[t] = (signed char)clampf(rintf((n*sr2)/sx3), -128.f, 127.f);
  if (t<16) WS_BFL(ws)[t] = (t<10) ? (int)rintf(bf[t]/sb3) : 0;
}

__global__ void k_s3(char* ws){
  float* F=WS_F(ws); int* I=WS_I(ws);
  if (threadIdx.x==0) F[14] = fmaxf((F[13]*(float)I[5])/127.f, EPSQ);
}

// ==================== Tier A: conv1 via i8 MFMA, once ====================
// quantize x -> padded 30x(32) i8 -> im2col A[800][16] -> 25x mfma_i32_32x32x32_i8
// -> amax/smax reduce + pooled-max-I1 (int16) store to global.
__global__ __launch_bounds__(256) void k_c1(const float* __restrict__ x, char* __restrict__ ws,
                                            short* __restrict__ i1p){
  constexpr int OFF_K0=0, OFF_A=960, OFF_I1=13760, OFF_B1=38848;
  __shared__ __align__(16) char arena[38912];
  signed char* k0b = (signed char*)(arena+OFF_K0);   // [30][32] padded image, zero border
  signed char* Abuf= (signed char*)(arena+OFF_A);    // [800][16] im2col
  short*       I1s = (short*)(arena+OFF_I1);         // [784][16]
  int*         b1i = (int*)(arena+OFF_B1);

  const int tid=threadIdx.x, img=blockIdx.x;
  const int lane=tid&63, wid=tid>>6;
  const float s0 = WS_F(ws)[0];

  if (tid<16) b1i[tid]=WS_B1L(ws)[tid];
  // zero padded image + im2col tail rows
  for (int i=tid;i<240;i+=256) ((int*)k0b)[i]=0;
  for (int i=tid;i<3200;i+=256) ((int*)Abuf)[i]=0;
  __syncthreads();
  // quantize input into padded interior
  const float* xi = x + img*784;
  for (int i=tid;i<784;i+=256){
    int r=i/28, c=i-r*28;
    float v = clampf(rintf(xi[i]/s0), -128.f, 127.f);
    k0b[(r+1)*32 + (c+1)] = (signed char)v;
  }
  __syncthreads();
  // build im2col rows: row p -> 9 window bytes + 7 zero pad, one b128 write
  for (int p=tid;p<784;p+=256){
    int oy=p/28, ox=p-oy*28;
    int base = oy*32+ox;
    int al = base & ~3, sh = (base&3)*8;
    unsigned l0a=*(const unsigned*)(k0b+al),    l1a=*(const unsigned*)(k0b+al+4);
    unsigned l0b=*(const unsigned*)(k0b+al+32), l1b=*(const unsigned*)(k0b+al+36);
    unsigned l0c=*(const unsigned*)(k0b+al+64), l1c=*(const unsigned*)(k0b+al+68);
    unsigned u0=(unsigned)(((((unsigned long long)l1a)<<32)|l0a)>>sh);
    unsigned u1=(unsigned)(((((unsigned long long)l1b)<<32)|l0b)>>sh);
    unsigned u2=(unsigned)(((((unsigned long long)l1c)<<32)|l0c)>>sh);
    i32x4 row;
    row[0]=(int)((u0&0xFFFFFFu)|(u1<<24));
    row[1]=(int)(((u1>>8)&0xFFFFu)|((u2&0xFFFFu)<<16));
    row[2]=(int)((u2>>16)&0xFFu);
    row[3]=0;
    *(i32x4*)(Abuf + p*16) = row;
  }
  __syncthreads();
  // MFMA: 25 M-tiles of 32 positions x 32 cols (16 oc used), K=32 (9 taps used)
  const i32x4 bfr = ((const i32x4*)WS_B1FR(ws))[lane];
  const int col=lane&31, h=lane>>5;
  const int bias=(col<16)? b1i[col] : 0;
  int amax=0, smax=INT_MIN;
  for (int mt=wid; mt<25; mt+=4){
    i32x4 a={0,0,0,0};
    if (h==0) a = *(const i32x4*)(Abuf + (mt*32+col)*16);
    i32x16 acc;
#pragma unroll
    for (int r=0;r<16;r++) acc[r]=bias;
    acc=__builtin_amdgcn_mfma_i32_32x32x32_i8(a,bfr,acc,0,0,0);
#pragma unroll
    for (int r=0;r<16;r++){
      int row=(r&3)+8*(r>>2)+4*h;
      int p=mt*32+row;
      if (p<784 && col<16){
        int v=acc[r];
        amax=max(amax,v<0?-v:v); smax=max(smax,v);
        I1s[p*16+col]=(short)v;
      }
    }
  }
  __syncthreads();
  // pool1 max on raw I1 (all later maps monotone) -> global int16 [196][16]
  for (int i=tid;i<3136;i+=256){
    int pp=i>>4, c=i&15, py=pp/14, px=pp-py*14;
    int p0=py*56+px*2;
    int m=max(max((int)I1s[p0*16+c],(int)I1s[(p0+1)*16+c]),
              max((int)I1s[(p0+28)*16+c],(int)I1s[(p0+29)*16+c]));
    i1p[(size_t)img*3136 + i]=(short)m;
  }
  reduce2_atomic(amax,smax,&WS_I(ws)[1],&WS_I(ws)[2]);
}

// Tier A second/third pass: pooled I1 -> k1 -> q2 levels -> conv2 MFMA.
// FIN=0: reduce I2 amax/smax.  FIN=1: requant+pool2+fc -> I3 + maxabs.
template<bool FIN>
__global__ __launch_bounds__(256) void k_c2(char* __restrict__ ws, const short* __restrict__ i1p,
                                            int* __restrict__ i3out){
  constexpr int OFF_Q2L=0, OFF_B2I=3136, OFF_Q2T=3264, OFF_N2=3520,
                OFF_Q3T=9792, OFF_BFS=10048, OFF_Q3F=10112, OFF_RED=16384;
  constexpr int ARENA = FIN ? 16544 : 3520;
  __shared__ __align__(16) char arena[ARENA];
  signed char* q2l=(signed char*)(arena+OFF_Q2L);
  int* b2li=(int*)(arena+OFF_B2I);
  signed char* q2t=(signed char*)(arena+OFF_Q2T);

  const int tid=threadIdx.x, img=blockIdx.x;
  const int lane=tid&63, wid=tid>>6;
  const float* F=WS_F(ws);
  const float sb1=F[3], sy1=F[4];

  q2t[tid]=WS_Q2TAB(ws)[tid];
  if (tid<32) b2li[tid]=WS_B2L(ws)[tid];
  if constexpr (FIN){
    ((signed char*)(arena+OFF_Q3T))[tid]=WS_Q3TAB(ws)[tid];
    if (tid<16) ((int*)(arena+OFF_BFS))[tid]=WS_BFL(ws)[tid];
  }
  __syncthreads();
  for (int i=tid;i<3136;i+=256){
    int m=(int)i1p[(size_t)img*3136+i];
    float k1=clampf(rintf((sb1*(float)m)/sy1),-128.f,127.f);
    q2l[i]=q2t[(int)k1+128];
  }
  __syncthreads();

  // conv2 as [196x144]x[144x32] i8 GEMM
  i32x4 bfr[5];
  {
    const i32x4* bg=(const i32x4*)WS_B2FR(ws);
#pragma unroll
    for (int c=0;c<5;c++) bfr[c]=bg[c*64+lane];
  }
  const int col=lane&31, h=lane>>5;
  const int bias=b2li[col];
  int amax2=0, smax2=INT_MIN;
  float sb2=0.f, sy2=0.f;
  signed char* n2buf=nullptr;
  if constexpr (FIN){ sb2=F[8]; sy2=F[9]; n2buf=(signed char*)(arena+OFF_N2); }

  for (int mt=wid; mt<7; mt+=4){
    const int p=mt*32+col;
    const bool pv=p<196;
    const int oy=p/14, ox=p-oy*14;
    i32x16 acc;
#pragma unroll
    for (int r=0;r<16;r++) acc[r]=bias;
#pragma unroll
    for (int c=0;c<5;c++){
      const int tap=2*c+h;
      i32x4 a={0,0,0,0};
      if (pv && tap<9){
        const int iy=oy+tap/3-1, ix=ox+tap-(tap/3)*3-1;
        if ((unsigned)iy<14u && (unsigned)ix<14u) a=*(const i32x4*)(q2l+(iy*14+ix)*16);
      }
      acc=__builtin_amdgcn_mfma_i32_32x32x32_i8(a,bfr[c],acc,0,0,0);
    }
#pragma unroll
    for (int r=0;r<16;r++){
      const int row=(r&3)+8*(r>>2)+4*h;
      const int pp=mt*32+row;
      if (pp<196){
        const int v=acc[r];
        if constexpr (!FIN){ amax2=max(amax2,v<0?-v:v); smax2=max(smax2,v); }
        else {
          n2buf[col*196+pp]=(signed char)clampf(rintf((sb2*(float)v)/sy2),-128.f,127.f);
        }
      }
    }
  }
  if constexpr (!FIN){
    reduce2_atomic(amax2,smax2,&WS_I(ws)[3],&WS_I(ws)[4]);
    return;
  } else {
    __syncthreads();
    signed char* q3t_s=(signed char*)(arena+OFF_Q3T);
    float* q3f=(float*)(arena+OFF_Q3F);
    for (int i=tid;i<1568;i+=256){
      int cch=i/49, s=i-cch*49, qy=s/7, qx=s-qy*7;
      int b=cch*196+qy*28+qx*2;
      int m=max(max((int)n2buf[b],(int)n2buf[b+1]),max((int)n2buf[b+14],(int)n2buf[b+15]));
      q3f[i]=(float)q3t_s[m+128];
    }
    __syncthreads();
    const float* mff=WS_MFF(ws);
    float a10[10];
#pragma unroll
    for (int o=0;o<10;o++) a10[o]=0.f;
    for (int k=tid;k<1568;k+=256){
      float qa=q3f[k];
#pragma unroll
      for (int o=0;o<10;o++) a10[o]=fmaf(qa,mff[o*1568+k],a10[o]);
    }
#pragma unroll
    for (int o=0;o<10;o++){
#pragma unroll
      for (int off=32;off;off>>=1) a10[o]+=__shfl_down(a10[o],off,64);
    }
    float* redf=(float*)(arena+OFF_RED);
    int* bfs=(int*)(arena+OFF_BFS);
    if (lane==0){
#pragma unroll
      for (int o=0;o<10;o++) redf[wid*10+o]=a10[o];
    }
    __syncthreads();
    if (tid<10){
      float s=redf[tid]+redf[10+tid]+redf[20+tid]+redf[30+tid];
      int I3v=(int)s+bfs[tid];
      i3out[img*10+tid]=I3v;
      redf[tid]=(float)(I3v<0?-I3v:I3v);
    }
    __syncthreads();
    if (tid==0){
      int m=0;
#pragma unroll
      for (int o=0;o<10;o++) m=max(m,(int)redf[o]);
      atomicMax(&WS_I(ws)[5],m);
    }
  }
}

// ==================== Tier B/C fallback: verified R2 path ====================
template<int MODE, bool SKIP>
__global__ __launch_bounds__(256) void k_fused(const float* __restrict__ x, char* __restrict__ ws,
                                               char* __restrict__ q2g, int* __restrict__ i3out){
  constexpr bool C1 = (MODE<2) || (!SKIP);
  constexpr int OFF_K0=0, OFF_M1=3600, OFF_B1=4176, OFF_N1=4240;
  constexpr int OFF_Q2L = C1 ? 16784 : 0;
  constexpr int OFF_B2I = OFF_Q2L+3136;
  constexpr int OFF_Q2T = OFF_B2I+128;
  constexpr int OFF_N2  = OFF_Q2T+256;
  constexpr int OFF_Q3T = OFF_N2+6272;
  constexpr int OFF_BFS = OFF_Q3T+256;
  constexpr int OFF_Q3F = OFF_BFS+64;
  constexpr int OFF_RED = OFF_Q3F+6272;
  constexpr int ARENA = (MODE==0) ? 4240 : ((MODE==1) ? OFF_N2 : OFF_RED+160);
  __shared__ __align__(16) char arena[ARENA];

  const int tid=threadIdx.x, img=blockIdx.x;
  const int lane=tid&63, wid=tid>>6;
  const float* F=WS_F(ws);

  signed char* q2l = (signed char*)(arena+OFF_Q2L);
  int* b2li = (int*)(arena+OFF_B2I);

  if constexpr (C1){
    float* k0p=(float*)(arena+OFF_K0);
    float* m1f_s=(float*)(arena+OFF_M1);
    float* b1f=(float*)(arena+OFF_B1);
    signed char* n1buf=(signed char*)(arena+OFF_N1);
    const float s0=F[0];
    const float* xi=x+img*784;
    for (int i=tid;i<900;i+=256){
      int r=i/30, c=i-r*30;
      float v=0.f;
      if (r>=1 && r<=28 && c>=1 && c<=28) v=clampf(rintf(xi[(r-1)*28+(c-1)]/s0),-128.f,127.f);
      k0p[i]=v;
    }
    for (int i=tid;i<144;i+=256) m1f_s[i]=WS_M1F(ws)[i];
    if (tid<16) b1f[tid]=(float)WS_B1L(ws)[tid];
    if constexpr (MODE>=1){
      ((signed char*)(arena+OFF_Q2T))[tid]=WS_Q2TAB(ws)[tid];
      if (tid<32) b2li[tid]=WS_B2L(ws)[tid];
    }
    if constexpr (MODE==2){
      ((signed char*)(arena+OFF_Q3T))[tid]=WS_Q3TAB(ws)[tid];
      if (tid<16) ((int*)(arena+OFF_BFS))[tid]=WS_BFL(ws)[tid];
    }
    __syncthreads();

    float sb1=0.f, sy1=0.f;
    if constexpr (MODE>=1){ sb1=F[3]; sy1=F[4]; }
    int amax=0, smax=INT_MIN;
    for (int i=tid;i<12544;i+=256){
      int oc=i/784, pos=i-oc*784, oy=pos/28, ox=pos-oy*28;
      const float* wr=m1f_s+oc*9;
      const float* kp=k0p+oy*30+ox;
      float acc=b1f[oc];
      acc=fmaf(kp[0],wr[0],acc); acc=fmaf(kp[1],wr[1],acc); acc=fmaf(kp[2],wr[2],acc);
      acc=fmaf(kp[30],wr[3],acc); acc=fmaf(kp[31],wr[4],acc); acc=fmaf(kp[32],wr[5],acc);
      acc=fmaf(kp[60],wr[6],acc); acc=fmaf(kp[61],wr[7],acc); acc=fmaf(kp[62],wr[8],acc);
      if constexpr (MODE==0){
        int v=(int)acc; amax=max(amax,v<0?-v:v); smax=max(smax,v);
      } else {
        n1buf[i]=(signed char)clampf(rintf((sb1*acc)/sy1),-128.f,127.f);
      }
    }
    if constexpr (MODE==0){
      reduce2_atomic(amax,smax,&WS_I(ws)[1],&WS_I(ws)[2]);
      return;
    }
    __syncthreads();
    {
      signed char* q2t_s=(signed char*)(arena+OFF_Q2T);
      for (int i=tid;i<3136;i+=256){
        int s=i>>4, c=i&15, py=s/14, px=s-py*14;
        int b=c*784+py*56+px*2;
        int m=max(max((int)n1buf[b],(int)n1buf[b+1]),max((int)n1buf[b+28],(int)n1buf[b+29]));
        q2l[i]=q2t_s[m+128];
      }
    }
    __syncthreads();
    if constexpr (MODE==1){
      if (q2g){
        for (int i=tid;i<196;i+=256) ((i32x4*)(q2g+(size_t)img*3136))[i]=((const i32x4*)q2l)[i];
      }
    }
  } else {
    for (int i=tid;i<196;i+=256) ((i32x4*)q2l)[i]=((const i32x4*)(q2g+(size_t)img*3136))[i];
    if (tid<32) b2li[tid]=WS_B2L(ws)[tid];
    ((signed char*)(arena+OFF_Q3T))[tid]=WS_Q3TAB(ws)[tid];
    if (tid<16) ((int*)(arena+OFF_BFS))[tid]=WS_BFL(ws)[tid];
    __syncthreads();
  }

  i32x4 bfr[5];
  {
    const i32x4* bg=(const i32x4*)WS_B2FR(ws);
#pragma unroll
    for (int c=0;c<5;c++) bfr[c]=bg[c*64+lane];
  }
  const int col=lane&31, h=lane>>5;
  const int bias=b2li[col];
  int amax2=0, smax2=INT_MIN;
  float sb2=0.f, sy2=0.f;
  signed char* n2buf=nullptr;
  if constexpr (MODE==2){ sb2=F[8]; sy2=F[9]; n2buf=(signed char*)(arena+OFF_N2); }

  for (int mt=wid; mt<7; mt+=4){
    const int p=mt*32+col;
    const bool pv=p<196;
    const int oy=p/14, ox=p-oy*14;
    i32x16 acc;
#pragma unroll
    for (int r=0;r<16;r++) acc[r]=bias;
#pragma unroll
    for (int c=0;c<5;c++){
      const int tap=2*c+h;
      i32x4 a={0,0,0,0};
      if (pv && tap<9){
        const int iy=oy+tap/3-1, ix=ox+tap-(tap/3)*3-1;
        if ((unsigned)iy<14u && (unsigned)ix<14u) a=*(const i32x4*)(q2l+(iy*14+ix)*16);
      }
      acc=__builtin_amdgcn_mfma_i32_32x32x32_i8(a,bfr[c],acc,0,0,0);
    }
#pragma unroll
    for (int r=0;r<16;r++){
      const int row=(r&3)+8*(r>>2)+4*h;
      const int pp=mt*32+row;
      if (pp<196){
        const int v=acc[r];
        if constexpr (MODE==1){ amax2=max(amax2,v<0?-v:v); smax2=max(smax2,v); }
        else if constexpr (MODE==2){
          n2buf[col*196+pp]=(signed char)clampf(rintf((sb2*(float)v)/sy2),-128.f,127.f);
        }
      }
    }
  }
  if constexpr (MODE==1){
    reduce2_atomic(amax2,smax2,&WS_I(ws)[3],&WS_I(ws)[4]);
    return;
  }
  if constexpr (MODE==2){
    __syncthreads();
    signed char* q3t_s=(signed char*)(arena+OFF_Q3T);
    float* q3f=(float*)(arena+OFF_Q3F);
    for (int i=tid;i<1568;i+=256){
      int cch=i/49, s=i-cch*49, qy=s/7, qx=s-qy*7;
      int b=cch*196+qy*28+qx*2;
      int m=max(max((int)n2buf[b],(int)n2buf[b+1]),max((int)n2buf[b+14],(int)n2buf[b+15]));
      q3f[i]=(float)q3t_s[m+128];
    }
    __syncthreads();
    const float* mff=WS_MFF(ws);
    float a10[10];
#pragma unroll
    for (int o=0;o<10;o++) a10[o]=0.f;
    for (int k=tid;k<1568;k+=256){
      float qa=q3f[k];
#pragma unroll
      for (int o=0;o<10;o++) a10[o]=fmaf(qa,mff[o*1568+k],a10[o]);
    }
#pragma unroll
    for (int o=0;o<10;o++){
#pragma unroll
      for (int off=32;off;off>>=1) a10[o]+=__shfl_down(a10[o],off,64);
    }
    float* redf=(float*)(arena+OFF_RED);
    int* bfs=(int*)(arena+OFF_BFS);
    if (lane==0){
#pragma unroll
      for (int o=0;o<10;o++) redf[wid*10+o]=a10[o];
    }
    __syncthreads();
    if (tid<10){
      float s=redf[tid]+redf[10+tid]+redf[20+tid]+redf[30+tid];
      int I3v=(int)s+bfs[tid];
      i3out[img*10+tid]=I3v;
      redf[tid]=(float)(I3v<0?-I3v:I3v);
    }
    __syncthreads();
    if (tid==0){
      int m=0;
#pragma unroll
      for (int o=0;o<10;o++) m=max(m,(int)redf[o]);
      atomicMax(&WS_I(ws)[5],m);
    }
  }
}

__global__ void k_out(char* ws, float* __restrict__ out){
  float* F=WS_F(ws);
  float sb3=F[13], sy3=F[14];
  int i = blockIdx.x*blockDim.x + threadIdx.x;
  if (i < NB*10){
    int iv = ((const int*)out)[i];
    float y = sb3*(float)iv;
    float q = clampf(rintf(y/sy3), -128.f, 127.f);
    out[i] = q*sy3;
  }
}

extern "C" void kernel_launch(void* const* d_in, const int* in_sizes, int n_in,
                              void* d_out, int out_size, void* d_ws, size_t ws_size,
                              hipStream_t stream){
  const float* x  = (const float*)d_in[0];
  const float* w1 = (const float*)d_in[1];
  const float* b1 = (const float*)d_in[2];
  const float* w2 = (const float*)d_in[3];
  const float* b2 = (const float*)d_in[4];
  const float* wf = (const float*)d_in[5];
  const float* bf = (const float*)d_in[6];
  char* ws = (char*)d_ws;
  float* out = (float*)d_out;
  int* i3 = (int*)d_out;

  const size_t needA = (size_t)WS_BIG_OFF + (size_t)NB*3136*2;  // ~51.5MB
  const size_t needB = (size_t)WS_BIG_OFF + (size_t)NB*3136;    // ~26MB

  k_init<<<dim3(1), dim3(64), 0, stream>>>(ws);
  k_absx<<<dim3(2048), dim3(256), 0, stream>>>(x, ws);
  k_wq<<<dim3(1), dim3(256), 0, stream>>>(w1, b1, w2, wf, ws);

  if (ws_size >= needA){
    short* i1p = (short*)(ws + WS_BIG_OFF);
    k_c1<<<dim3(NB), dim3(256), 0, stream>>>(x, ws, i1p);
    k_s1<<<dim3(1), dim3(256), 0, stream>>>(b2, ws);
    k_c2<false><<<dim3(NB), dim3(256), 0, stream>>>(ws, i1p, i3);
    k_s2<<<dim3(1), dim3(256), 0, stream>>>(bf, ws);
    k_c2<true ><<<dim3(NB), dim3(256), 0, stream>>>(ws, i1p, i3);
  } else {
    const bool big = ws_size >= needB;
    char* q2g = big ? (ws + WS_BIG_OFF) : nullptr;
    k_fused<0,false><<<dim3(NB), dim3(256), 0, stream>>>(x, ws, nullptr, i3);
    k_s1<<<dim3(1), dim3(256), 0, stream>>>(b2, ws);
    k_fused<1,false><<<dim3(NB), dim3(256), 0, stream>>>(x, ws, q2g, i3);
    k_s2<<<dim3(1), dim3(256), 0, stream>>>(bf, ws);
    if (big) k_fused<2,true ><<<dim3(NB), dim3(256), 0, stream>>>(x, ws, q2g, i3);
    else     k_fused<2,false><<<dim3(NB), dim3(256), 0, stream>>>(x, ws, nullptr, i3);
  }
  k_s3<<<dim3(1), dim3(1), 0, stream>>>(ws);
  k_out<<<dim3((NB*10+255)/256), dim3(256), 0, stream>>>(ws, out);
}

// Round 4
// 354.855 us; speedup vs baseline: 4.0715x; 1.6521x over previous
//
#include <hip/hip_runtime.h>
#include <climits>

#define NB 8192
#define EPSQ 1e-8f

using i32x4  = __attribute__((ext_vector_type(4)))  int;
using i32x16 = __attribute__((ext_vector_type(16))) int;

// ---- ws layout (byte offsets) ----
// scalars F: 0 s0,1 sx1,2 sw1,3 sb1,4 sy1,5 sr1,6 sx2,7 sw2,8 sb2,9 sy2,10 sr2,11 sx3,12 swf,13 sb3,14 sy3
#define WS_F(ws)     ((float*)(ws))
#define WS_I(ws)     ((int*)((char*)(ws)+128))      // 0 maxabs_x bits,1 maxabsI1,2 maxI1,3 maxabsI2,4 maxI2,5 maxabsI3
#define WS_B1L(ws)   ((int*)((char*)(ws)+384))      // [16]
#define WS_B2L(ws)   ((int*)((char*)(ws)+448))      // [32]
#define WS_BFL(ws)   ((int*)((char*)(ws)+576))      // [16]
#define WS_M1F(ws)   ((float*)((char*)(ws)+640))    // [144]
#define WS_B2FR(ws)  ((char*)(ws)+2048)             // [5][64][16] conv2 i8 B-fragments
#define WS_Q2TAB(ws) ((signed char*)((char*)(ws)+7168))  // [256] k1 level -> q2 int8 level
#define WS_Q3TAB(ws) ((signed char*)((char*)(ws)+7424))  // [256] k2 level -> q3 int8 level
#define WS_B1FR(ws)  ((char*)(ws)+7680)             // [64][16] conv1 i8 B-fragments (fallback)
#define WS_MFF(ws)   ((float*)((char*)(ws)+20480))  // [10][1568] float fc levels (fallback)
#define WS_WFP(ws)   ((char*)(ws)+83200)            // [49][64][16] fc i8 B-fragments (50176 B)
#define WS_BIG_OFF   139264

__device__ __forceinline__ float clampf(float v, float lo, float hi){ return fminf(fmaxf(v, lo), hi); }

__device__ __forceinline__ float wave_max_f(float v){
#pragma unroll
  for (int off=32; off; off>>=1) v = fmaxf(v, __shfl_down(v, off, 64));
  return v;
}
__device__ __forceinline__ int wave_max_i(int v){
#pragma unroll
  for (int off=32; off; off>>=1) v = max(v, __shfl_down(v, off, 64));
  return v;
}

__device__ __forceinline__ void reduce2_atomic(int amax, int smax, int* gA, int* gS){
  amax = wave_max_i(amax); smax = wave_max_i(smax);
  __shared__ int sA[4], sS[4];
  int w = threadIdx.x>>6, l = threadIdx.x&63;
  if (l==0){ sA[w]=amax; sS[w]=smax; }
  __syncthreads();
  if (threadIdx.x==0){
#pragma unroll
    for (int i=1;i<4;i++){ amax=max(amax,sA[i]); smax=max(smax,sS[i]); }
    atomicMax(gA, amax); atomicMax(gS, smax);
  }
}

__global__ void k_init(char* ws){
  int* I = WS_I(ws);
  if (threadIdx.x==0){ I[0]=0; I[1]=0; I[2]=INT_MIN; I[3]=0; I[4]=INT_MIN; I[5]=0; }
}

__global__ void k_absx(const float* __restrict__ x, char* ws){
  const float4* x4 = (const float4*)x;
  const int n4 = NB*784/4;
  float m = 0.f;
  for (int i = blockIdx.x*blockDim.x + threadIdx.x; i < n4; i += gridDim.x*blockDim.x){
    float4 v = x4[i];
    m = fmaxf(m, fmaxf(fmaxf(fabsf(v.x),fabsf(v.y)), fmaxf(fabsf(v.z),fabsf(v.w))));
  }
  m = wave_max_f(m);
  __shared__ float sm[4];
  int w = threadIdx.x>>6;
  if ((threadIdx.x&63)==0) sm[w]=m;
  __syncthreads();
  if (threadIdx.x==0){
    m = fmaxf(fmaxf(sm[0],sm[1]), fmaxf(sm[2],sm[3]));
    atomicMax((unsigned*)WS_I(ws), __float_as_uint(m));
  }
}

__global__ void k_wq(const float* __restrict__ w1, const float* __restrict__ b1,
                     const float* __restrict__ w2, const float* __restrict__ wf,
                     char* ws){
  __shared__ float red[256];
  float* F = WS_F(ws);
  int* I = WS_I(ws);
  int t = threadIdx.x;
  auto bmaxabs = [&](const float* p, int n)->float{
    float m=0.f; for (int i=t;i<n;i+=256) m=fmaxf(m,fabsf(p[i]));
    red[t]=m; __syncthreads();
    for (int s=128;s;s>>=1){ if (t<s) red[t]=fmaxf(red[t],red[t+s]); __syncthreads(); }
    float r=red[0]; __syncthreads(); return r;
  };
  float mw1 = bmaxabs(w1,144);
  float mw2 = bmaxabs(w2,4608);
  float mwf = bmaxabs(wf,15680);
  float mx  = __uint_as_float((unsigned)I[0]);
  float s0  = fmaxf(mx/127.f, EPSQ);
  float sx1 = fmaxf((127.f*s0)/127.f, EPSQ);
  float sw1 = fmaxf(mw1/7.f, EPSQ);
  float sw2 = fmaxf(mw2/7.f, EPSQ);
  float swf = fmaxf(mwf/7.f, EPSQ);
  float sb1 = sx1*sw1;
  if (t==0){ F[0]=s0; F[1]=sx1; F[2]=sw1; F[3]=sb1; F[7]=sw2; F[12]=swf; }
  float* m1f = WS_M1F(ws);
  for (int i=t;i<144;i+=256) m1f[i] = clampf(rintf(w1[i]/sw1), -7.f, 7.f);
  if (t<16) WS_B1L(ws)[t] = (int)rintf(b1[t]/sb1);
  // conv2 B-fragments: chunk c, lane l -> col oc=l&31, k=(l>>5)*16+j; tap=2c+(l>>5), ch=j
  for (int i=t;i<5120;i+=256){
    int chunk=i>>10, r=i&1023, ln=r>>4, j=r&15;
    int tap=2*chunk+(ln>>5), oc=ln&31;
    signed char v=0;
    if (tap<9) v=(signed char)clampf(rintf(w2[oc*144 + j*9 + tap]/sw2), -7.f, 7.f);
    WS_B2FR(ws)[i]=v;
  }
  // conv1 B-fragments (fallback k_c1)
  for (int i=t;i<1024;i+=256){
    int ln=i>>4, j=i&15;
    int k=(ln>>5)*16+j, oc=ln&31;
    signed char v=0;
    if (k<9 && oc<16) v=(signed char)clampf(rintf(w1[oc*9+k]/sw1), -7.f, 7.f);
    WS_B1FR(ws)[i]=v;
  }
  float* mff = WS_MFF(ws);
  for (int i=t;i<15680;i+=256) mff[i] = clampf(rintf(wf[i]/swf), -7.f, 7.f);
  // fc B-fragments: chunk c, lane l: col oc=l&31, k=c*32+(l>>5)*16+j; feature f=ch*49+cell, k=cell*32+ch
  for (int i=t;i<50176;i+=256){
    int chunk=i>>10, r2=i&1023, ln=r2>>4, j=r2&15;
    int oc=ln&31, k=chunk*32+(ln>>5)*16+j;
    int cell=k>>5, ch=k&31;
    signed char v=0;
    if (oc<10) v=(signed char)clampf(rintf(wf[oc*1568 + ch*49 + cell]/swf), -7.f, 7.f);
    ((signed char*)WS_WFP(ws))[i]=v;
  }
}

__global__ void k_s1(const float* __restrict__ b2, char* ws){
  float* F=WS_F(ws); int* I=WS_I(ws);
  __shared__ float sh[4];
  int t=threadIdx.x;
  if (t==0){
    float sb1=F[3];
    float sy1 = fmaxf((sb1*(float)I[1])/127.f, EPSQ);
    float mp  = sb1*(float)I[2];
    float P1  = clampf(rintf(mp/sy1), 0.f, 127.f);
    float sr1 = fmaxf((sy1*P1)/15.f, EPSQ);
    float N1  = clampf(rintf((sy1*P1)/sr1), 0.f, 15.f);
    float sx2 = fmaxf((N1*sr1)/127.f, EPSQ);
    float sb2 = sx2*F[7];
    F[4]=sy1; F[5]=sr1; F[6]=sx2; F[8]=sb2;
    sh[0]=sy1; sh[1]=sr1; sh[2]=sx2; sh[3]=sb2;
  }
  __syncthreads();
  float sy1=sh[0], sr1=sh[1], sx2=sh[2], sb2=sh[3];
  int k = t-128;
  float n = (k>0) ? clampf(rintf((sy1*(float)k)/sr1), 0.f, 15.f) : 0.f;
  WS_Q2TAB(ws)[t] = (signed char)clampf(rintf((n*sr1)/sx2), -128.f, 127.f);
  if (t<32) WS_B2L(ws)[t] = (int)rintf(b2[t]/sb2);
}

__global__ void k_s2(const float* __restrict__ bf, char* ws){
  float* F=WS_F(ws); int* I=WS_I(ws);
  __shared__ float sh[4];
  int t=threadIdx.x;
  if (t==0){
    float sb2=F[8];
    float sy2 = fmaxf((sb2*(float)I[3])/127.f, EPSQ);
    float mp  = sb2*(float)I[4];
    float P2  = clampf(rintf(mp/sy2), 0.f, 127.f);
    float sr2 = fmaxf((sy2*P2)/15.f, EPSQ);
    float N2  = clampf(rintf((sy2*P2)/sr2), 0.f, 15.f);
    float sx3 = fmaxf((N2*sr2)/127.f, EPSQ);
    float sb3 = sx3*F[12];
    F[9]=sy2; F[10]=sr2; F[11]=sx3; F[13]=sb3;
    sh[0]=sy2; sh[1]=sr2; sh[2]=sx3; sh[3]=sb3;
  }
  __syncthreads();
  float sy2=sh[0], sr2=sh[1], sx3=sh[2], sb3=sh[3];
  int k = t-128;
  float n = (k>0) ? clampf(rintf((sy2*(float)k)/sr2), 0.f, 15.f) : 0.f;
  WS_Q3TAB(ws)[t] = (signed char)clampf(rintf((n*sr2)/sx3), -128.f, 127.f);
  if (t<16) WS_BFL(ws)[t] = (t<10) ? (int)rintf(bf[t]/sb3) : 0;
}

__global__ void k_s3(char* ws){
  float* F=WS_F(ws); int* I=WS_I(ws);
  if (threadIdx.x==0) F[14] = fmaxf((F[13]*(float)I[5])/127.f, EPSQ);
}

// ================= NEW PATH =================
// P2a: quantize x -> padded i8 [NB][30][32], zero borders. 1 thread = 1 u32 word.
__global__ void k_qx(const float* __restrict__ x, const char* __restrict__ ws,
                     signed char* __restrict__ qx){
  const float s0 = ((const float*)ws)[0];
  int id = blockIdx.x*256 + threadIdx.x;          // < NB*240
  int img = id/240, w = id - img*240;
  int r = w>>3, c4 = (w&7)<<2;
  const float* xi = x + img*784;
  unsigned out = 0;
#pragma unroll
  for (int j=0;j<4;j++){
    int c = c4+j;
    bool valid = (r>=1) && (r<=28) && (c>=1) && (c<=28);
    int q = 0;
    if (valid){
      float xv = xi[(r-1)*28 + (c-1)];
      q = (int)clampf(rintf(xv/s0), -128.f, 127.f);
    }
    out |= ((unsigned)(unsigned char)(signed char)q) << (8*j);
  }
  ((unsigned*)qx)[id] = out;
}

// P2b: conv1 + pool1 + amax/smax(I1). 1 thread = 1 (img, pooled-cell); exact: NB*196 = blocks*256.
__global__ __launch_bounds__(256) void k_conv1(const signed char* __restrict__ qx,
                                               char* __restrict__ ws,
                                               short* __restrict__ i1p){
  __shared__ float wsm[144];
  __shared__ float wbias[16];
  int t = threadIdx.x;
  if (t<144) wsm[t] = WS_M1F(ws)[t];
  if (t<16) wbias[t] = (float)WS_B1L(ws)[t];
  __syncthreads();
  int id = blockIdx.x*256 + t;
  int img = id/196, cell = id - img*196;
  int py = cell/14, px = cell - py*14;
  const signed char* qb = qx + img*960 + (2*py)*32;
  int pc0 = 2*px;
  int al = pc0 & ~3, sh = (pc0&3)*8;
  float in[4][4];
#pragma unroll
  for (int rr=0; rr<4; rr++){
    unsigned lo = *(const unsigned*)(qb + rr*32 + al);
    unsigned hi = *(const unsigned*)(qb + rr*32 + al + 4);
    unsigned wrd = (unsigned)(((((unsigned long long)hi)<<32)|lo) >> sh);
#pragma unroll
    for (int cc=0; cc<4; cc++)
      in[rr][cc] = (float)(signed char)((wrd >> (8*cc)) & 0xFFu);
  }
  int amax=0, smax=INT_MIN;
  short outv[16];
#pragma unroll
  for (int oc=0; oc<16; oc++){
    const float* wv = wsm + oc*9;
    float b = wbias[oc];
    float a00=b, a01=b, a10=b, a11=b;
#pragma unroll
    for (int dy=0; dy<3; dy++){
#pragma unroll
      for (int dx=0; dx<3; dx++){
        float wt = wv[dy*3+dx];
        a00 = fmaf(in[dy  ][dx  ], wt, a00);
        a01 = fmaf(in[dy  ][dx+1], wt, a01);
        a10 = fmaf(in[dy+1][dx  ], wt, a10);
        a11 = fmaf(in[dy+1][dx+1], wt, a11);
      }
    }
    int v00=(int)a00, v01=(int)a01, v10=(int)a10, v11=(int)a11;
    int mx = max(max(v00,v01), max(v10,v11));
    int ax = max(max(v00<0?-v00:v00, v01<0?-v01:v01), max(v10<0?-v10:v10, v11<0?-v11:v11));
    amax = max(amax, ax);
    smax = max(smax, mx);
    outv[oc] = (short)mx;
  }
  int4* dst = (int4*)(i1p + (size_t)id*16);
  dst[0] = *(const int4*)&outv[0];
  dst[1] = *(const int4*)&outv[8];
  reduce2_atomic(amax, smax, &WS_I(ws)[1], &WS_I(ws)[2]);
}

// P3: conv2 MFMA (wave = image, no block barriers in main flow) + amax/smax(I2)
// + pool2 (ds_max on raw I2, monotone-commute) -> pooled-I2 int32 written IN-PLACE over i1p.
__global__ __launch_bounds__(256) void k_conv2r(char* __restrict__ ws,
                                                short* __restrict__ i1p,
                                                int* __restrict__ p2g){
  constexpr int WSLICE = 4096 + 6272;
  __shared__ __align__(16) char arena[4*WSLICE];
  const int t=threadIdx.x, lane=t&63, wid=t>>6;
  const int img = blockIdx.x*4 + wid;
  char* wbase = arena + wid*WSLICE;
  signed char* q2p = (signed char*)wbase;            // [16][16][16ch] padded, zero borders
  int* poolw = (int*)(wbase + 4096);                 // [49][32]
  const float* F = WS_F(ws);
  const float sb1=F[3], sy1=F[4];
  const signed char* q2t = WS_Q2TAB(ws);

  // zero q2p (512 u64), init pool to INT_MIN
#pragma unroll
  for (int k=0;k<8;k++) ((unsigned long long*)q2p)[lane + 64*k] = 0ULL;
#pragma unroll
  for (int k=0;k<24;k++) poolw[lane + 64*k] = INT_MIN;
  if (lane<32) poolw[1536+lane] = INT_MIN;

  // requant pooled-I1 -> q2 levels into padded interior
  const unsigned* src = (const unsigned*)(i1p + (size_t)img*3136);
  for (int k=0;k<25;k++){
    int idx = lane + 64*k;
    if (idx >= 1568) break;
    unsigned wv = src[idx];
    int e0 = idx*2;
    int cellc = e0 >> 4, ch = e0 & 15;
    int pyc = cellc/14, pxc = cellc - pyc*14;
    int m0 = (int)(short)(wv & 0xFFFFu);
    int m1 = (int)(short)(wv >> 16);
    float k10 = clampf(rintf((sb1*(float)m0)/sy1), -128.f, 127.f);
    float k11 = clampf(rintf((sb1*(float)m1)/sy1), -128.f, 127.f);
    int b0 = (int)(unsigned char)q2t[(int)k10+128];
    int b1 = (int)(unsigned char)q2t[(int)k11+128];
    *(unsigned short*)(q2p + ((pyc+1)*16 + (pxc+1))*16 + ch) = (unsigned short)(b0 | (b1<<8));
  }

  i32x4 bfr[5];
  const i32x4* bg = (const i32x4*)WS_B2FR(ws);
#pragma unroll
  for (int c=0;c<5;c++) bfr[c] = bg[c*64+lane];
  const int col = lane&31, h = lane>>5;
  const int bias = WS_B2L(ws)[col];
  int amax2=0, smax2=INT_MIN;
  const int TOFF[9] = {0,1,2,16,17,18,32,33,34};

#pragma unroll
  for (int mt=0; mt<7; mt++){
    int p = mt*32 + col;
    bool pv = p < 196;
    int oy = p/14, ox = p - oy*14;
    int E0 = oy*16 + ox;
    i32x16 acc;
#pragma unroll
    for (int r=0;r<16;r++) acc[r] = bias;
#pragma unroll
    for (int c=0;c<5;c++){
      int toff = h ? ((2*c+1<9)? TOFF[2*c+1] : -1) : TOFF[2*c];
      bool ok = pv && (toff>=0);
      int entry = ok ? (E0 + toff) : 0;     // entry 0 = zero border cell
      i32x4 a = *(const i32x4*)(q2p + entry*16);
      acc = __builtin_amdgcn_mfma_i32_32x32x32_i8(a, bfr[c], acc, 0,0,0);
    }
#pragma unroll
    for (int r=0;r<16;r++){
      int row = (r&3) + 8*(r>>2) + 4*h;
      int pp = mt*32 + row;
      if (pp < 196){
        int v = acc[r];
        amax2 = max(amax2, v<0?-v:v);
        smax2 = max(smax2, v);
        int qy = pp/14, qx2 = pp - qy*14;
        int cc = (qy>>1)*7 + (qx2>>1);
        atomicMax(&poolw[cc*32 + col], v);
      }
    }
  }
  reduce2_atomic(amax2, smax2, &WS_I(ws)[3], &WS_I(ws)[4]);
  // pooled store (in-place over i1p; all reads of src completed above)
  int* dst = p2g + (size_t)img*1568;
#pragma unroll
  for (int k=0;k<24;k++){ int idx = lane+64*k; dst[idx] = poolw[idx]; }
  if (lane<32) dst[1536+lane] = poolw[1536+lane];
}

// P4: pooled-I2 -> q3 int8 levels (pure stream, 4 elems/thread)
__global__ void k_rq2(const char* __restrict__ ws, const int* __restrict__ p2g,
                      signed char* __restrict__ q3g){
  const float* F = (const float*)ws;
  const float sb2 = F[8], sy2 = F[9];
  const signed char* q3t = WS_Q3TAB(ws);
  int id = blockIdx.x*256 + threadIdx.x;
  i32x4 m4 = ((const i32x4*)p2g)[id];
  unsigned out=0;
#pragma unroll
  for (int j=0;j<4;j++){
    float k2 = clampf(rintf((sb2*(float)m4[j])/sy2), -128.f, 127.f);
    out |= ((unsigned)(unsigned char)q3t[(int)k2+128]) << (8*j);
  }
  ((unsigned*)q3g)[id] = out;
}

// P5: fc as i8 MFMA GEMM M=8192 N=10(pad32) K=1568 + I3 store + amax(I3)
__global__ __launch_bounds__(256) void k_fc(char* __restrict__ ws,
                                            const signed char* __restrict__ q3g,
                                            int* __restrict__ i3out){
  int t=threadIdx.x, lane=t&63, wid=t>>6;
  int mt = blockIdx.x*4 + wid;                 // 0..255
  const int col=lane&31, h=lane>>5;
  const signed char* A0 = q3g + (size_t)(mt*32 + col)*1568 + 16*h;
  const i32x4* wfp = (const i32x4*)WS_WFP(ws);
  int bias = (col<10) ? WS_BFL(ws)[col] : 0;
  i32x16 acc;
#pragma unroll
  for (int r=0;r<16;r++) acc[r]=bias;
  for (int c=0;c<49;c++){
    i32x4 a = *(const i32x4*)(A0 + c*32);
    i32x4 b = wfp[c*64 + lane];
    acc = __builtin_amdgcn_mfma_i32_32x32x32_i8(a, b, acc, 0,0,0);
  }
  int am=0;
#pragma unroll
  for (int r=0;r<16;r++){
    int row=(r&3)+8*(r>>2)+4*h;
    int img = mt*32+row;
    if (col<10){
      int v = acc[r];
      i3out[img*10+col] = v;
      am = max(am, v<0?-v:v);
    }
  }
  am = wave_max_i(am);
  __shared__ int sA[4];
  if (lane==0) sA[wid]=am;
  __syncthreads();
  if (t==0) atomicMax(&WS_I(ws)[5], max(max(sA[0],sA[1]),max(sA[2],sA[3])));
}

// ================= FALLBACK (verified R3 tier-A) =================
__global__ __launch_bounds__(256) void k_c1(const float* __restrict__ x, char* __restrict__ ws,
                                            short* __restrict__ i1p){
  constexpr int OFF_K0=0, OFF_A=960, OFF_I1=13760, OFF_B1=38848;
  __shared__ __align__(16) char arena[38912];
  signed char* k0b = (signed char*)(arena+OFF_K0);
  signed char* Abuf= (signed char*)(arena+OFF_A);
  short*       I1s = (short*)(arena+OFF_I1);
  int*         b1i = (int*)(arena+OFF_B1);

  const int tid=threadIdx.x, img=blockIdx.x;
  const int lane=tid&63, wid=tid>>6;
  const float s0 = WS_F(ws)[0];

  if (tid<16) b1i[tid]=WS_B1L(ws)[tid];
  for (int i=tid;i<240;i+=256) ((int*)k0b)[i]=0;
  for (int i=tid;i<3200;i+=256) ((int*)Abuf)[i]=0;
  __syncthreads();
  const float* xi = x + img*784;
  for (int i=tid;i<784;i+=256){
    int r=i/28, c=i-r*28;
    float v = clampf(rintf(xi[i]/s0), -128.f, 127.f);
    k0b[(r+1)*32 + (c+1)] = (signed char)v;
  }
  __syncthreads();
  for (int p=tid;p<784;p+=256){
    int oy=p/28, ox=p-oy*28;
    int base = oy*32+ox;
    int al = base & ~3, sh = (base&3)*8;
    unsigned l0a=*(const unsigned*)(k0b+al),    l1a=*(const unsigned*)(k0b+al+4);
    unsigned l0b=*(const unsigned*)(k0b+al+32), l1b=*(const unsigned*)(k0b+al+36);
    unsigned l0c=*(const unsigned*)(k0b+al+64), l1c=*(const unsigned*)(k0b+al+68);
    unsigned u0=(unsigned)(((((unsigned long long)l1a)<<32)|l0a)>>sh);
    unsigned u1=(unsigned)(((((unsigned long long)l1b)<<32)|l0b)>>sh);
    unsigned u2=(unsigned)(((((unsigned long long)l1c)<<32)|l0c)>>sh);
    i32x4 row;
    row[0]=(int)((u0&0xFFFFFFu)|(u1<<24));
    row[1]=(int)(((u1>>8)&0xFFFFu)|((u2&0xFFFFu)<<16));
    row[2]=(int)((u2>>16)&0xFFu);
    row[3]=0;
    *(i32x4*)(Abuf + p*16) = row;
  }
  __syncthreads();
  const i32x4 bfr = ((const i32x4*)WS_B1FR(ws))[lane];
  const int col=lane&31, h=lane>>5;
  const int bias=(col<16)? b1i[col] : 0;
  int amax=0, smax=INT_MIN;
  for (int mt=wid; mt<25; mt+=4){
    i32x4 a={0,0,0,0};
    if (h==0) a = *(const i32x4*)(Abuf + (mt*32+col)*16);
    i32x16 acc;
#pragma unroll
    for (int r=0;r<16;r++) acc[r]=bias;
    acc=__builtin_amdgcn_mfma_i32_32x32x32_i8(a,bfr,acc,0,0,0);
#pragma unroll
    for (int r=0;r<16;r++){
      int row=(r&3)+8*(r>>2)+4*h;
      int p=mt*32+row;
      if (p<784 && col<16){
        int v=acc[r];
        amax=max(amax,v<0?-v:v); smax=max(smax,v);
        I1s[p*16+col]=(short)v;
      }
    }
  }
  __syncthreads();
  for (int i=tid;i<3136;i+=256){
    int pp=i>>4, c=i&15, py=pp/14, px=pp-py*14;
    int p0=py*56+px*2;
    int m=max(max((int)I1s[p0*16+c],(int)I1s[(p0+1)*16+c]),
              max((int)I1s[(p0+28)*16+c],(int)I1s[(p0+29)*16+c]));
    i1p[(size_t)img*3136 + i]=(short)m;
  }
  reduce2_atomic(amax,smax,&WS_I(ws)[1],&WS_I(ws)[2]);
}

template<bool FIN>
__global__ __launch_bounds__(256) void k_c2(char* __restrict__ ws, const short* __restrict__ i1p,
                                            int* __restrict__ i3out){
  constexpr int OFF_Q2L=0, OFF_B2I=3136, OFF_Q2T=3264, OFF_N2=3520,
                OFF_Q3T=9792, OFF_BFS=10048, OFF_Q3F=10112, OFF_RED=16384;
  constexpr int ARENA = FIN ? 16544 : 3520;
  __shared__ __align__(16) char arena[ARENA];
  signed char* q2l=(signed char*)(arena+OFF_Q2L);
  int* b2li=(int*)(arena+OFF_B2I);
  signed char* q2t=(signed char*)(arena+OFF_Q2T);

  const int tid=threadIdx.x, img=blockIdx.x;
  const int lane=tid&63, wid=tid>>6;
  const float* F=WS_F(ws);
  const float sb1=F[3], sy1=F[4];

  q2t[tid]=WS_Q2TAB(ws)[tid];
  if (tid<32) b2li[tid]=WS_B2L(ws)[tid];
  if constexpr (FIN){
    ((signed char*)(arena+OFF_Q3T))[tid]=WS_Q3TAB(ws)[tid];
    if (tid<16) ((int*)(arena+OFF_BFS))[tid]=WS_BFL(ws)[tid];
  }
  __syncthreads();
  for (int i=tid;i<3136;i+=256){
    int m=(int)i1p[(size_t)img*3136+i];
    float k1=clampf(rintf((sb1*(float)m)/sy1),-128.f,127.f);
    q2l[i]=q2t[(int)k1+128];
  }
  __syncthreads();

  i32x4 bfr[5];
  {
    const i32x4* bg=(const i32x4*)WS_B2FR(ws);
#pragma unroll
    for (int c=0;c<5;c++) bfr[c]=bg[c*64+lane];
  }
  const int col=lane&31, h=lane>>5;
  const int bias=b2li[col];
  int amax2=0, smax2=INT_MIN;
  float sb2=0.f, sy2=0.f;
  signed char* n2buf=nullptr;
  if constexpr (FIN){ sb2=F[8]; sy2=F[9]; n2buf=(signed char*)(arena+OFF_N2); }

  for (int mt=wid; mt<7; mt+=4){
    const int p=mt*32+col;
    const bool pv=p<196;
    const int oy=p/14, ox=p-oy*14;
    i32x16 acc;
#pragma unroll
    for (int r=0;r<16;r++) acc[r]=bias;
#pragma unroll
    for (int c=0;c<5;c++){
      const int tap=2*c+h;
      i32x4 a={0,0,0,0};
      if (pv && tap<9){
        const int iy=oy+tap/3-1, ix=ox+tap-(tap/3)*3-1;
        if ((unsigned)iy<14u && (unsigned)ix<14u) a=*(const i32x4*)(q2l+(iy*14+ix)*16);
      }
      acc=__builtin_amdgcn_mfma_i32_32x32x32_i8(a,bfr[c],acc,0,0,0);
    }
#pragma unroll
    for (int r=0;r<16;r++){
      const int row=(r&3)+8*(r>>2)+4*h;
      const int pp=mt*32+row;
      if (pp<196){
        const int v=acc[r];
        if constexpr (!FIN){ amax2=max(amax2,v<0?-v:v); smax2=max(smax2,v); }
        else {
          n2buf[col*196+pp]=(signed char)clampf(rintf((sb2*(float)v)/sy2),-128.f,127.f);
        }
      }
    }
  }
  if constexpr (!FIN){
    reduce2_atomic(amax2,smax2,&WS_I(ws)[3],&WS_I(ws)[4]);
    return;
  } else {
    __syncthreads();
    signed char* q3t_s=(signed char*)(arena+OFF_Q3T);
    float* q3f=(float*)(arena+OFF_Q3F);
    for (int i=tid;i<1568;i+=256){
      int cch=i/49, s=i-cch*49, qy=s/7, qx=s-qy*7;
      int b=cch*196+qy*28+qx*2;
      int m=max(max((int)n2buf[b],(int)n2buf[b+1]),max((int)n2buf[b+14],(int)n2buf[b+15]));
      q3f[i]=(float)q3t_s[m+128];
    }
    __syncthreads();
    const float* mff=WS_MFF(ws);
    float a10[10];
#pragma unroll
    for (int o=0;o<10;o++) a10[o]=0.f;
    for (int k=tid;k<1568;k+=256){
      float qa=q3f[k];
#pragma unroll
      for (int o=0;o<10;o++) a10[o]=fmaf(qa,mff[o*1568+k],a10[o]);
    }
#pragma unroll
    for (int o=0;o<10;o++){
#pragma unroll
      for (int off=32;off;off>>=1) a10[o]+=__shfl_down(a10[o],off,64);
    }
    float* redf=(float*)(arena+OFF_RED);
    int* bfs=(int*)(arena+OFF_BFS);
    if (lane==0){
#pragma unroll
      for (int o=0;o<10;o++) redf[wid*10+o]=a10[o];
    }
    __syncthreads();
    if (tid<10){
      float s=redf[tid]+redf[10+tid]+redf[20+tid]+redf[30+tid];
      int I3v=(int)s+bfs[tid];
      i3out[img*10+tid]=I3v;
      redf[tid]=(float)(I3v<0?-I3v:I3v);
    }
    __syncthreads();
    if (tid==0){
      int m=0;
#pragma unroll
      for (int o=0;o<10;o++) m=max(m,(int)redf[o]);
      atomicMax(&WS_I(ws)[5],m);
    }
  }
}

__global__ void k_out(char* ws, float* __restrict__ out){
  float* F=WS_F(ws);
  float sb3=F[13], sy3=F[14];
  int i = blockIdx.x*blockDim.x + threadIdx.x;
  if (i < NB*10){
    int iv = ((const int*)out)[i];
    float y = sb3*(float)iv;
    float q = clampf(rintf(y/sy3), -128.f, 127.f);
    out[i] = q*sy3;
  }
}

extern "C" void kernel_launch(void* const* d_in, const int* in_sizes, int n_in,
                              void* d_out, int out_size, void* d_ws, size_t ws_size,
                              hipStream_t stream){
  const float* x  = (const float*)d_in[0];
  const float* w1 = (const float*)d_in[1];
  const float* b1 = (const float*)d_in[2];
  const float* w2 = (const float*)d_in[3];
  const float* b2 = (const float*)d_in[4];
  const float* wf = (const float*)d_in[5];
  const float* bf = (const float*)d_in[6];
  char* ws = (char*)d_ws;
  float* out = (float*)d_out;
  int* i3 = (int*)d_out;

  const size_t QX_SZ  = (size_t)NB*960;        //  7,864,320
  const size_t I1_SZ  = (size_t)NB*6272;       // 51,380,224 (i1p int16 / pooled-I2 int32 in place)
  const size_t Q3_SZ  = (size_t)NB*1568;       // 12,845,056
  const size_t needFull = (size_t)WS_BIG_OFF + QX_SZ + I1_SZ + Q3_SZ;
  const size_t needA    = (size_t)WS_BIG_OFF + I1_SZ;

  k_init<<<dim3(1), dim3(64), 0, stream>>>(ws);
  k_absx<<<dim3(2048), dim3(256), 0, stream>>>(x, ws);
  k_wq<<<dim3(1), dim3(256), 0, stream>>>(w1, b1, w2, wf, ws);

  if (ws_size >= needFull){
    signed char* qx  = (signed char*)(ws + WS_BIG_OFF);
    short*       i1p = (short*)(ws + WS_BIG_OFF + QX_SZ);
    int*         p2g = (int*)i1p;
    signed char* q3g = (signed char*)(ws + WS_BIG_OFF + QX_SZ + I1_SZ);
    k_qx   <<<dim3(NB*240/256), dim3(256), 0, stream>>>(x, ws, qx);
    k_conv1<<<dim3(NB*196/256), dim3(256), 0, stream>>>(qx, ws, i1p);
    k_s1   <<<dim3(1), dim3(256), 0, stream>>>(b2, ws);
    k_conv2r<<<dim3(NB/4), dim3(256), 0, stream>>>(ws, i1p, p2g);
    k_s2   <<<dim3(1), dim3(256), 0, stream>>>(bf, ws);
    k_rq2  <<<dim3(NB*1568/1024), dim3(256), 0, stream>>>(ws, p2g, q3g);
    k_fc   <<<dim3(64), dim3(256), 0, stream>>>(ws, q3g, i3);
  } else {
    short* i1p = (short*)(ws + WS_BIG_OFF);
    k_c1<<<dim3(NB), dim3(256), 0, stream>>>(x, ws, i1p);
    k_s1<<<dim3(1), dim3(256), 0, stream>>>(b2, ws);
    k_c2<false><<<dim3(NB), dim3(256), 0, stream>>>(ws, i1p, i3);
    k_s2<<<dim3(1), dim3(256), 0, stream>>>(bf, ws);
    k_c2<true ><<<dim3(NB), dim3(256), 0, stream>>>(ws, i1p, i3);
  }
  k_s3<<<dim3(1), dim3(1), 0, stream>>>(ws);
  k_out<<<dim3((NB*10+255)/256), dim3(256), 0, stream>>>(ws, out);
}

// Round 5
// 354.150 us; speedup vs baseline: 4.0796x; 1.0020x over previous
//
#include <hip/hip_runtime.h>
#include <climits>

#define NB 8192
#define EPSQ 1e-8f

using i32x4  = __attribute__((ext_vector_type(4)))  int;
using i32x16 = __attribute__((ext_vector_type(16))) int;

// ---- ws layout (byte offsets) ----
// scalars F: 0 s0,1 sx1,2 sw1,3 sb1,4 sy1,5 sr1,6 sx2,7 sw2,8 sb2,9 sy2,10 sr2,11 sx3,12 swf,13 sb3,14 sy3
#define WS_F(ws)     ((float*)(ws))
#define WS_I(ws)     ((int*)((char*)(ws)+128))      // 0 maxabs_x bits,1 maxabsI1,2 maxI1,3 maxabsI2,4 maxI2,5 maxabsI3
#define WS_B1L(ws)   ((int*)((char*)(ws)+384))      // [16]
#define WS_B2L(ws)   ((int*)((char*)(ws)+448))      // [32]
#define WS_BFL(ws)   ((int*)((char*)(ws)+576))      // [16]
#define WS_M1F(ws)   ((float*)((char*)(ws)+640))    // [144]
#define WS_B1F(ws)   ((float*)((char*)(ws)+1280))   // [16] float bias levels (conv1)
#define WS_B2FR(ws)  ((char*)(ws)+2048)             // [5][64][16] conv2 i8 B-fragments
#define WS_Q2TAB(ws) ((signed char*)((char*)(ws)+7168))  // [256] k1 level -> q2 int8 level
#define WS_Q3TAB(ws) ((signed char*)((char*)(ws)+7424))  // [256] k2 level -> q3 int8 level
#define WS_B1FR(ws)  ((char*)(ws)+7680)             // [64][16] conv1 i8 B-fragments (fallback)
#define WS_MFF(ws)   ((float*)((char*)(ws)+20480))  // [10][1568] float fc levels (fallback)
#define WS_WFP(ws)   ((char*)(ws)+83200)            // [49][64][16] fc i8 B-fragments (50176 B)
#define WS_BIG_OFF   139264

__device__ __forceinline__ float clampf(float v, float lo, float hi){ return fminf(fmaxf(v, lo), hi); }

__device__ __forceinline__ float wave_max_f(float v){
#pragma unroll
  for (int off=32; off; off>>=1) v = fmaxf(v, __shfl_down(v, off, 64));
  return v;
}
__device__ __forceinline__ int wave_max_i(int v){
#pragma unroll
  for (int off=32; off; off>>=1) v = max(v, __shfl_down(v, off, 64));
  return v;
}

__device__ __forceinline__ void reduce2_atomic(int amax, int smax, int* gA, int* gS){
  amax = wave_max_i(amax); smax = wave_max_i(smax);
  __shared__ int sA[4], sS[4];
  int w = threadIdx.x>>6, l = threadIdx.x&63;
  if (l==0){ sA[w]=amax; sS[w]=smax; }
  __syncthreads();
  if (threadIdx.x==0){
#pragma unroll
    for (int i=1;i<4;i++){ amax=max(amax,sA[i]); smax=max(smax,sS[i]); }
    atomicMax(gA, amax); atomicMax(gS, smax);
  }
}

__global__ void k_init(char* ws){
  int* I = WS_I(ws);
  if (threadIdx.x==0){ I[0]=0; I[1]=0; I[2]=INT_MIN; I[3]=0; I[4]=INT_MIN; I[5]=0; }
}

__global__ void k_absx(const float* __restrict__ x, char* ws){
  const float4* x4 = (const float4*)x;
  const int n4 = NB*784/4;
  float m = 0.f;
  for (int i = blockIdx.x*blockDim.x + threadIdx.x; i < n4; i += gridDim.x*blockDim.x){
    float4 v = x4[i];
    m = fmaxf(m, fmaxf(fmaxf(fabsf(v.x),fabsf(v.y)), fmaxf(fabsf(v.z),fabsf(v.w))));
  }
  m = wave_max_f(m);
  __shared__ float sm[4];
  int w = threadIdx.x>>6;
  if ((threadIdx.x&63)==0) sm[w]=m;
  __syncthreads();
  if (threadIdx.x==0){
    m = fmaxf(fmaxf(sm[0],sm[1]), fmaxf(sm[2],sm[3]));
    atomicMax((unsigned*)WS_I(ws), __float_as_uint(m));
  }
}

__global__ void k_wq(const float* __restrict__ w1, const float* __restrict__ b1,
                     const float* __restrict__ w2, const float* __restrict__ wf,
                     char* ws){
  __shared__ float red[256];
  float* F = WS_F(ws);
  int* I = WS_I(ws);
  int t = threadIdx.x;
  auto bmaxabs = [&](const float* p, int n)->float{
    float m=0.f; for (int i=t;i<n;i+=256) m=fmaxf(m,fabsf(p[i]));
    red[t]=m; __syncthreads();
    for (int s=128;s;s>>=1){ if (t<s) red[t]=fmaxf(red[t],red[t+s]); __syncthreads(); }
    float r=red[0]; __syncthreads(); return r;
  };
  float mw1 = bmaxabs(w1,144);
  float mw2 = bmaxabs(w2,4608);
  float mwf = bmaxabs(wf,15680);
  float mx  = __uint_as_float((unsigned)I[0]);
  float s0  = fmaxf(mx/127.f, EPSQ);
  float sx1 = fmaxf((127.f*s0)/127.f, EPSQ);
  float sw1 = fmaxf(mw1/7.f, EPSQ);
  float sw2 = fmaxf(mw2/7.f, EPSQ);
  float swf = fmaxf(mwf/7.f, EPSQ);
  float sb1 = sx1*sw1;
  if (t==0){ F[0]=s0; F[1]=sx1; F[2]=sw1; F[3]=sb1; F[7]=sw2; F[12]=swf; }
  float* m1f = WS_M1F(ws);
  for (int i=t;i<144;i+=256) m1f[i] = clampf(rintf(w1[i]/sw1), -7.f, 7.f);
  if (t<16){
    int bl = (int)rintf(b1[t]/sb1);
    WS_B1L(ws)[t] = bl;
    WS_B1F(ws)[t] = (float)bl;
  }
  // conv2 B-fragments: chunk c, lane l -> col oc=l&31, k=(l>>5)*16+j; tap=2c+(l>>5), ch=j
  for (int i=t;i<5120;i+=256){
    int chunk=i>>10, r=i&1023, ln=r>>4, j=r&15;
    int tap=2*chunk+(ln>>5), oc=ln&31;
    signed char v=0;
    if (tap<9) v=(signed char)clampf(rintf(w2[oc*144 + j*9 + tap]/sw2), -7.f, 7.f);
    WS_B2FR(ws)[i]=v;
  }
  // conv1 B-fragments (fallback k_c1)
  for (int i=t;i<1024;i+=256){
    int ln=i>>4, j=i&15;
    int k=(ln>>5)*16+j, oc=ln&31;
    signed char v=0;
    if (k<9 && oc<16) v=(signed char)clampf(rintf(w1[oc*9+k]/sw1), -7.f, 7.f);
    WS_B1FR(ws)[i]=v;
  }
  float* mff = WS_MFF(ws);
  for (int i=t;i<15680;i+=256) mff[i] = clampf(rintf(wf[i]/swf), -7.f, 7.f);
  // fc B-fragments: chunk c, lane l: col oc=l&31, k=c*32+(l>>5)*16+j; feature f=ch*49+cell, k=cell*32+ch
  for (int i=t;i<50176;i+=256){
    int chunk=i>>10, r2=i&1023, ln=r2>>4, j=r2&15;
    int oc=ln&31, k=chunk*32+(ln>>5)*16+j;
    int cell=k>>5, ch=k&31;
    signed char v=0;
    if (oc<10) v=(signed char)clampf(rintf(wf[oc*1568 + ch*49 + cell]/swf), -7.f, 7.f);
    ((signed char*)WS_WFP(ws))[i]=v;
  }
}

__global__ void k_s1(const float* __restrict__ b2, char* ws){
  float* F=WS_F(ws); int* I=WS_I(ws);
  __shared__ float sh[4];
  int t=threadIdx.x;
  if (t==0){
    float sb1=F[3];
    float sy1 = fmaxf((sb1*(float)I[1])/127.f, EPSQ);
    float mp  = sb1*(float)I[2];
    float P1  = clampf(rintf(mp/sy1), 0.f, 127.f);
    float sr1 = fmaxf((sy1*P1)/15.f, EPSQ);
    float N1  = clampf(rintf((sy1*P1)/sr1), 0.f, 15.f);
    float sx2 = fmaxf((N1*sr1)/127.f, EPSQ);
    float sb2 = sx2*F[7];
    F[4]=sy1; F[5]=sr1; F[6]=sx2; F[8]=sb2;
    sh[0]=sy1; sh[1]=sr1; sh[2]=sx2; sh[3]=sb2;
  }
  __syncthreads();
  float sy1=sh[0], sr1=sh[1], sx2=sh[2], sb2=sh[3];
  int k = t-128;
  float n = (k>0) ? clampf(rintf((sy1*(float)k)/sr1), 0.f, 15.f) : 0.f;
  WS_Q2TAB(ws)[t] = (signed char)clampf(rintf((n*sr1)/sx2), -128.f, 127.f);
  if (t<32) WS_B2L(ws)[t] = (int)rintf(b2[t]/sb2);
}

__global__ void k_s2(const float* __restrict__ bf, char* ws){
  float* F=WS_F(ws); int* I=WS_I(ws);
  __shared__ float sh[4];
  int t=threadIdx.x;
  if (t==0){
    float sb2=F[8];
    float sy2 = fmaxf((sb2*(float)I[3])/127.f, EPSQ);
    float mp  = sb2*(float)I[4];
    float P2  = clampf(rintf(mp/sy2), 0.f, 127.f);
    float sr2 = fmaxf((sy2*P2)/15.f, EPSQ);
    float N2  = clampf(rintf((sy2*P2)/sr2), 0.f, 15.f);
    float sx3 = fmaxf((N2*sr2)/127.f, EPSQ);
    float sb3 = sx3*F[12];
    F[9]=sy2; F[10]=sr2; F[11]=sx3; F[13]=sb3;
    sh[0]=sy2; sh[1]=sr2; sh[2]=sx3; sh[3]=sb3;
  }
  __syncthreads();
  float sy2=sh[0], sr2=sh[1], sx3=sh[2], sb3=sh[3];
  int k = t-128;
  float n = (k>0) ? clampf(rintf((sy2*(float)k)/sr2), 0.f, 15.f) : 0.f;
  WS_Q3TAB(ws)[t] = (signed char)clampf(rintf((n*sr2)/sx3), -128.f, 127.f);
  if (t<16) WS_BFL(ws)[t] = (t<10) ? (int)rintf(bf[t]/sb3) : 0;
}

__global__ void k_s3(char* ws){
  float* F=WS_F(ws); int* I=WS_I(ws);
  if (threadIdx.x==0) F[14] = fmaxf((F[13]*(float)I[5])/127.f, EPSQ);
}

// ================= NEW PATH =================
// P2a: quantize x -> padded i8 [NB][30][32], zero borders. 1 thread = 1 u32 word.
__global__ void k_qx(const float* __restrict__ x, const char* __restrict__ ws,
                     signed char* __restrict__ qx){
  const float s0 = ((const float*)ws)[0];
  int id = blockIdx.x*256 + threadIdx.x;          // < NB*240
  int img = id/240, w = id - img*240;
  int r = w>>3, c4 = (w&7)<<2;
  const float* xi = x + img*784;
  unsigned out = 0;
#pragma unroll
  for (int j=0;j<4;j++){
    int c = c4+j;
    bool valid = (r>=1) && (r<=28) && (c>=1) && (c<=28);
    int q = 0;
    if (valid){
      float xv = xi[(r-1)*28 + (c-1)];
      q = (int)clampf(rintf(xv/s0), -128.f, 127.f);
    }
    out |= ((unsigned)(unsigned char)(signed char)q) << (8*j);
  }
  ((unsigned*)qx)[id] = out;
}

// P2b: conv1 + pool1 + amax/smax(I1). 1 thread = 1 (img, pooled-cell).
// Weights/bias read directly from ws with uniform constant indices -> s_load
// (scalar cache), no LDS staging, no barrier before the reduce.
__global__ __launch_bounds__(256) void k_conv1(const signed char* __restrict__ qx,
                                               char* __restrict__ ws,
                                               short* __restrict__ i1p){
  const int t = threadIdx.x;
  const int id = blockIdx.x*256 + t;
  const int img = id/196, cell = id - img*196;
  const int py = cell/14, px = cell - py*14;
  const signed char* qb = qx + img*960 + (2*py)*32;
  const int pc0 = 2*px;
  const int al = pc0 & ~3, sh = (pc0&3)*8;
  float in[4][4];
#pragma unroll
  for (int rr=0; rr<4; rr++){
    unsigned lo = *(const unsigned*)(qb + rr*32 + al);
    unsigned hi = *(const unsigned*)(qb + rr*32 + al + 4);
    unsigned wrd = (unsigned)(((((unsigned long long)hi)<<32)|lo) >> sh);
#pragma unroll
    for (int cc=0; cc<4; cc++)
      in[rr][cc] = (float)(signed char)((wrd >> (8*cc)) & 0xFFu);
  }
  const float* __restrict__ m1f = WS_M1F(ws);   // uniform -> SGPR
  const float* __restrict__ b1f = WS_B1F(ws);   // uniform -> SGPR
  int amax=0, smax=INT_MIN;
  short outv[16];
#pragma unroll
  for (int oc=0; oc<16; oc++){
    float b = b1f[oc];
    float a00=b, a01=b, a10=b, a11=b;
#pragma unroll
    for (int dy=0; dy<3; dy++){
#pragma unroll
      for (int dx=0; dx<3; dx++){
        float wt = m1f[oc*9+dy*3+dx];
        a00 = fmaf(in[dy  ][dx  ], wt, a00);
        a01 = fmaf(in[dy  ][dx+1], wt, a01);
        a10 = fmaf(in[dy+1][dx  ], wt, a10);
        a11 = fmaf(in[dy+1][dx+1], wt, a11);
      }
    }
    int v00=(int)a00, v01=(int)a01, v10=(int)a10, v11=(int)a11;
    int mx = max(max(v00,v01), max(v10,v11));
    int ax = max(max(v00<0?-v00:v00, v01<0?-v01:v01), max(v10<0?-v10:v10, v11<0?-v11:v11));
    amax = max(amax, ax);
    smax = max(smax, mx);
    outv[oc] = (short)mx;
  }
  int4* dst = (int4*)(i1p + (size_t)id*16);
  dst[0] = *(const int4*)&outv[0];
  dst[1] = *(const int4*)&outv[8];
  reduce2_atomic(amax, smax, &WS_I(ws)[1], &WS_I(ws)[2]);
}

// P3: conv2 MFMA (wave = image) + amax/smax(I2) + pool2 -> pooled-I2 int32 in-place over i1p.
__global__ __launch_bounds__(256) void k_conv2r(char* __restrict__ ws,
                                                short* __restrict__ i1p,
                                                int* __restrict__ p2g){
  constexpr int WSLICE = 4096 + 6272;
  __shared__ __align__(16) char arena[4*WSLICE];
  const int t=threadIdx.x, lane=t&63, wid=t>>6;
  const int img = blockIdx.x*4 + wid;
  char* wbase = arena + wid*WSLICE;
  signed char* q2p = (signed char*)wbase;            // [16][16][16ch] padded, zero borders
  int* poolw = (int*)(wbase + 4096);                 // [49][32]
  const float* F = WS_F(ws);
  const float sb1=F[3], sy1=F[4];
  const signed char* q2t = WS_Q2TAB(ws);

#pragma unroll
  for (int k=0;k<8;k++) ((unsigned long long*)q2p)[lane + 64*k] = 0ULL;
#pragma unroll
  for (int k=0;k<24;k++) poolw[lane + 64*k] = INT_MIN;
  if (lane<32) poolw[1536+lane] = INT_MIN;

  const unsigned* src = (const unsigned*)(i1p + (size_t)img*3136);
  for (int k=0;k<25;k++){
    int idx = lane + 64*k;
    if (idx >= 1568) break;
    unsigned wv = src[idx];
    int e0 = idx*2;
    int cellc = e0 >> 4, ch = e0 & 15;
    int pyc = cellc/14, pxc = cellc - pyc*14;
    int m0 = (int)(short)(wv & 0xFFFFu);
    int m1 = (int)(short)(wv >> 16);
    float k10 = clampf(rintf((sb1*(float)m0)/sy1), -128.f, 127.f);
    float k11 = clampf(rintf((sb1*(float)m1)/sy1), -128.f, 127.f);
    int b0 = (int)(unsigned char)q2t[(int)k10+128];
    int b1 = (int)(unsigned char)q2t[(int)k11+128];
    *(unsigned short*)(q2p + ((pyc+1)*16 + (pxc+1))*16 + ch) = (unsigned short)(b0 | (b1<<8));
  }

  i32x4 bfr[5];
  const i32x4* bg = (const i32x4*)WS_B2FR(ws);
#pragma unroll
  for (int c=0;c<5;c++) bfr[c] = bg[c*64+lane];
  const int col = lane&31, h = lane>>5;
  const int bias = WS_B2L(ws)[col];
  int amax2=0, smax2=INT_MIN;
  const int TOFF[9] = {0,1,2,16,17,18,32,33,34};

#pragma unroll
  for (int mt=0; mt<7; mt++){
    int p = mt*32 + col;
    bool pv = p < 196;
    int oy = p/14, ox = p - oy*14;
    int E0 = oy*16 + ox;
    i32x16 acc;
#pragma unroll
    for (int r=0;r<16;r++) acc[r] = bias;
#pragma unroll
    for (int c=0;c<5;c++){
      int toff = h ? ((2*c+1<9)? TOFF[2*c+1] : -1) : TOFF[2*c];
      bool ok = pv && (toff>=0);
      int entry = ok ? (E0 + toff) : 0;
      i32x4 a = *(const i32x4*)(q2p + entry*16);
      acc = __builtin_amdgcn_mfma_i32_32x32x32_i8(a, bfr[c], acc, 0,0,0);
    }
#pragma unroll
    for (int r=0;r<16;r++){
      int row = (r&3) + 8*(r>>2) + 4*h;
      int pp = mt*32 + row;
      if (pp < 196){
        int v = acc[r];
        amax2 = max(amax2, v<0?-v:v);
        smax2 = max(smax2, v);
        int qy = pp/14, qx2 = pp - qy*14;
        int cc = (qy>>1)*7 + (qx2>>1);
        atomicMax(&poolw[cc*32 + col], v);
      }
    }
  }
  reduce2_atomic(amax2, smax2, &WS_I(ws)[3], &WS_I(ws)[4]);
  int* dst = p2g + (size_t)img*1568;
#pragma unroll
  for (int k=0;k<24;k++){ int idx = lane+64*k; dst[idx] = poolw[idx]; }
  if (lane<32) dst[1536+lane] = poolw[1536+lane];
}

// P4: pooled-I2 -> q3 int8 levels (pure stream)
__global__ void k_rq2(const char* __restrict__ ws, const int* __restrict__ p2g,
                      signed char* __restrict__ q3g){
  const float* F = (const float*)ws;
  const float sb2 = F[8], sy2 = F[9];
  const signed char* q3t = WS_Q3TAB(ws);
  int id = blockIdx.x*256 + threadIdx.x;
  i32x4 m4 = ((const i32x4*)p2g)[id];
  unsigned out=0;
#pragma unroll
  for (int j=0;j<4;j++){
    float k2 = clampf(rintf((sb2*(float)m4[j])/sy2), -128.f, 127.f);
    out |= ((unsigned)(unsigned char)q3t[(int)k2+128]) << (8*j);
  }
  ((unsigned*)q3g)[id] = out;
}

// P5: fc as i8 MFMA GEMM, 256 blocks, K split across 4 waves, LDS combine.
__global__ __launch_bounds__(256) void k_fc(char* __restrict__ ws,
                                            const signed char* __restrict__ q3g,
                                            int* __restrict__ i3out){
  __shared__ int part[3][16][64];   // waves 1..3 partials, transposed (conflict-free)
  int t=threadIdx.x, lane=t&63, wid=t>>6;
  int mt = blockIdx.x;              // 0..255
  const int col=lane&31, h=lane>>5;
  const signed char* A0 = q3g + (size_t)(mt*32 + col)*1568 + 16*h;
  const i32x4* wfp = (const i32x4*)WS_WFP(ws);
  i32x16 acc;
#pragma unroll
  for (int r=0;r<16;r++) acc[r]=0;
  for (int c=wid; c<49; c+=4){
    i32x4 a = *(const i32x4*)(A0 + c*32);
    i32x4 b = wfp[c*64 + lane];
    acc = __builtin_amdgcn_mfma_i32_32x32x32_i8(a, b, acc, 0,0,0);
  }
  if (wid>0){
#pragma unroll
    for (int r=0;r<16;r++) part[wid-1][r][lane] = acc[r];
  }
  __syncthreads();
  if (wid==0){
    int bias = (col<10) ? WS_BFL(ws)[col] : 0;
    int am=0;
#pragma unroll
    for (int r=0;r<16;r++){
      int v = acc[r] + part[0][r][lane] + part[1][r][lane] + part[2][r][lane] + bias;
      int row=(r&3)+8*(r>>2)+4*h;
      int img = mt*32+row;
      if (col<10){
        i3out[img*10+col] = v;
        am = max(am, v<0?-v:v);
      }
    }
    am = wave_max_i(am);
    if (lane==0) atomicMax(&WS_I(ws)[5], am);
  }
}

// ================= FALLBACK (verified R3 tier-A) =================
__global__ __launch_bounds__(256) void k_c1(const float* __restrict__ x, char* __restrict__ ws,
                                            short* __restrict__ i1p){
  constexpr int OFF_K0=0, OFF_A=960, OFF_I1=13760, OFF_B1=38848;
  __shared__ __align__(16) char arena[38912];
  signed char* k0b = (signed char*)(arena+OFF_K0);
  signed char* Abuf= (signed char*)(arena+OFF_A);
  short*       I1s = (short*)(arena+OFF_I1);
  int*         b1i = (int*)(arena+OFF_B1);

  const int tid=threadIdx.x, img=blockIdx.x;
  const int lane=tid&63, wid=tid>>6;
  const float s0 = WS_F(ws)[0];

  if (tid<16) b1i[tid]=WS_B1L(ws)[tid];
  for (int i=tid;i<240;i+=256) ((int*)k0b)[i]=0;
  for (int i=tid;i<3200;i+=256) ((int*)Abuf)[i]=0;
  __syncthreads();
  const float* xi = x + img*784;
  for (int i=tid;i<784;i+=256){
    int r=i/28, c=i-r*28;
    float v = clampf(rintf(xi[i]/s0), -128.f, 127.f);
    k0b[(r+1)*32 + (c+1)] = (signed char)v;
  }
  __syncthreads();
  for (int p=tid;p<784;p+=256){
    int oy=p/28, ox=p-oy*28;
    int base = oy*32+ox;
    int al = base & ~3, sh = (base&3)*8;
    unsigned l0a=*(const unsigned*)(k0b+al),    l1a=*(const unsigned*)(k0b+al+4);
    unsigned l0b=*(const unsigned*)(k0b+al+32), l1b=*(const unsigned*)(k0b+al+36);
    unsigned l0c=*(const unsigned*)(k0b+al+64), l1c=*(const unsigned*)(k0b+al+68);
    unsigned u0=(unsigned)(((((unsigned long long)l1a)<<32)|l0a)>>sh);
    unsigned u1=(unsigned)(((((unsigned long long)l1b)<<32)|l0b)>>sh);
    unsigned u2=(unsigned)(((((unsigned long long)l1c)<<32)|l0c)>>sh);
    i32x4 row;
    row[0]=(int)((u0&0xFFFFFFu)|(u1<<24));
    row[1]=(int)(((u1>>8)&0xFFFFu)|((u2&0xFFFFu)<<16));
    row[2]=(int)((u2>>16)&0xFFu);
    row[3]=0;
    *(i32x4*)(Abuf + p*16) = row;
  }
  __syncthreads();
  const i32x4 bfr = ((const i32x4*)WS_B1FR(ws))[lane];
  const int col=lane&31, h=lane>>5;
  const int bias=(col<16)? b1i[col] : 0;
  int amax=0, smax=INT_MIN;
  for (int mt=wid; mt<25; mt+=4){
    i32x4 a={0,0,0,0};
    if (h==0) a = *(const i32x4*)(Abuf + (mt*32+col)*16);
    i32x16 acc;
#pragma unroll
    for (int r=0;r<16;r++) acc[r]=bias;
    acc=__builtin_amdgcn_mfma_i32_32x32x32_i8(a,bfr,acc,0,0,0);
#pragma unroll
    for (int r=0;r<16;r++){
      int row=(r&3)+8*(r>>2)+4*h;
      int p=mt*32+row;
      if (p<784 && col<16){
        int v=acc[r];
        amax=max(amax,v<0?-v:v); smax=max(smax,v);
        I1s[p*16+col]=(short)v;
      }
    }
  }
  __syncthreads();
  for (int i=tid;i<3136;i+=256){
    int pp=i>>4, c=i&15, py=pp/14, px=pp-py*14;
    int p0=py*56+px*2;
    int m=max(max((int)I1s[p0*16+c],(int)I1s[(p0+1)*16+c]),
              max((int)I1s[(p0+28)*16+c],(int)I1s[(p0+29)*16+c]));
    i1p[(size_t)img*3136 + i]=(short)m;
  }
  reduce2_atomic(amax,smax,&WS_I(ws)[1],&WS_I(ws)[2]);
}

template<bool FIN>
__global__ __launch_bounds__(256) void k_c2(char* __restrict__ ws, const short* __restrict__ i1p,
                                            int* __restrict__ i3out){
  constexpr int OFF_Q2L=0, OFF_B2I=3136, OFF_Q2T=3264, OFF_N2=3520,
                OFF_Q3T=9792, OFF_BFS=10048, OFF_Q3F=10112, OFF_RED=16384;
  constexpr int ARENA = FIN ? 16544 : 3520;
  __shared__ __align__(16) char arena[ARENA];
  signed char* q2l=(signed char*)(arena+OFF_Q2L);
  int* b2li=(int*)(arena+OFF_B2I);
  signed char* q2t=(signed char*)(arena+OFF_Q2T);

  const int tid=threadIdx.x, img=blockIdx.x;
  const int lane=tid&63, wid=tid>>6;
  const float* F=WS_F(ws);
  const float sb1=F[3], sy1=F[4];

  q2t[tid]=WS_Q2TAB(ws)[tid];
  if (tid<32) b2li[tid]=WS_B2L(ws)[tid];
  if constexpr (FIN){
    ((signed char*)(arena+OFF_Q3T))[tid]=WS_Q3TAB(ws)[tid];
    if (tid<16) ((int*)(arena+OFF_BFS))[tid]=WS_BFL(ws)[tid];
  }
  __syncthreads();
  for (int i=tid;i<3136;i+=256){
    int m=(int)i1p[(size_t)img*3136+i];
    float k1=clampf(rintf((sb1*(float)m)/sy1),-128.f,127.f);
    q2l[i]=q2t[(int)k1+128];
  }
  __syncthreads();

  i32x4 bfr[5];
  {
    const i32x4* bg=(const i32x4*)WS_B2FR(ws);
#pragma unroll
    for (int c=0;c<5;c++) bfr[c]=bg[c*64+lane];
  }
  const int col=lane&31, h=lane>>5;
  const int bias=b2li[col];
  int amax2=0, smax2=INT_MIN;
  float sb2=0.f, sy2=0.f;
  signed char* n2buf=nullptr;
  if constexpr (FIN){ sb2=F[8]; sy2=F[9]; n2buf=(signed char*)(arena+OFF_N2); }

  for (int mt=wid; mt<7; mt+=4){
    const int p=mt*32+col;
    const bool pv=p<196;
    const int oy=p/14, ox=p-oy*14;
    i32x16 acc;
#pragma unroll
    for (int r=0;r<16;r++) acc[r]=bias;
#pragma unroll
    for (int c=0;c<5;c++){
      const int tap=2*c+h;
      i32x4 a={0,0,0,0};
      if (pv && tap<9){
        const int iy=oy+tap/3-1, ix=ox+tap-(tap/3)*3-1;
        if ((unsigned)iy<14u && (unsigned)ix<14u) a=*(const i32x4*)(q2l+(iy*14+ix)*16);
      }
      acc=__builtin_amdgcn_mfma_i32_32x32x32_i8(a,bfr[c],acc,0,0,0);
    }
#pragma unroll
    for (int r=0;r<16;r++){
      const int row=(r&3)+8*(r>>2)+4*h;
      const int pp=mt*32+row;
      if (pp<196){
        const int v=acc[r];
        if constexpr (!FIN){ amax2=max(amax2,v<0?-v:v); smax2=max(smax2,v); }
        else {
          n2buf[col*196+pp]=(signed char)clampf(rintf((sb2*(float)v)/sy2),-128.f,127.f);
        }
      }
    }
  }
  if constexpr (!FIN){
    reduce2_atomic(amax2,smax2,&WS_I(ws)[3],&WS_I(ws)[4]);
    return;
  } else {
    __syncthreads();
    signed char* q3t_s=(signed char*)(arena+OFF_Q3T);
    float* q3f=(float*)(arena+OFF_Q3F);
    for (int i=tid;i<1568;i+=256){
      int cch=i/49, s=i-cch*49, qy=s/7, qx=s-qy*7;
      int b=cch*196+qy*28+qx*2;
      int m=max(max((int)n2buf[b],(int)n2buf[b+1]),max((int)n2buf[b+14],(int)n2buf[b+15]));
      q3f[i]=(float)q3t_s[m+128];
    }
    __syncthreads();
    const float* mff=WS_MFF(ws);
    float a10[10];
#pragma unroll
    for (int o=0;o<10;o++) a10[o]=0.f;
    for (int k=tid;k<1568;k+=256){
      float qa=q3f[k];
#pragma unroll
      for (int o=0;o<10;o++) a10[o]=fmaf(qa,mff[o*1568+k],a10[o]);
    }
#pragma unroll
    for (int o=0;o<10;o++){
#pragma unroll
      for (int off=32;off;off>>=1) a10[o]+=__shfl_down(a10[o],off,64);
    }
    float* redf=(float*)(arena+OFF_RED);
    int* bfs=(int*)(arena+OFF_BFS);
    if (lane==0){
#pragma unroll
      for (int o=0;o<10;o++) redf[wid*10+o]=a10[o];
    }
    __syncthreads();
    if (tid<10){
      float s=redf[tid]+redf[10+tid]+redf[20+tid]+redf[30+tid];
      int I3v=(int)s+bfs[tid];
      i3out[img*10+tid]=I3v;
      redf[tid]=(float)(I3v<0?-I3v:I3v);
    }
    __syncthreads();
    if (tid==0){
      int m=0;
#pragma unroll
      for (int o=0;o<10;o++) m=max(m,(int)redf[o]);
      atomicMax(&WS_I(ws)[5],m);
    }
  }
}

__global__ void k_out(char* ws, float* __restrict__ out){
  float* F=WS_F(ws);
  float sb3=F[13], sy3=F[14];
  int i = blockIdx.x*blockDim.x + threadIdx.x;
  if (i < NB*10){
    int iv = ((const int*)out)[i];
    float y = sb3*(float)iv;
    float q = clampf(rintf(y/sy3), -128.f, 127.f);
    out[i] = q*sy3;
  }
}

extern "C" void kernel_launch(void* const* d_in, const int* in_sizes, int n_in,
                              void* d_out, int out_size, void* d_ws, size_t ws_size,
                              hipStream_t stream){
  const float* x  = (const float*)d_in[0];
  const float* w1 = (const float*)d_in[1];
  const float* b1 = (const float*)d_in[2];
  const float* w2 = (const float*)d_in[3];
  const float* b2 = (const float*)d_in[4];
  const float* wf = (const float*)d_in[5];
  const float* bf = (const float*)d_in[6];
  char* ws = (char*)d_ws;
  float* out = (float*)d_out;
  int* i3 = (int*)d_out;

  const size_t QX_SZ  = (size_t)NB*960;
  const size_t I1_SZ  = (size_t)NB*6272;
  const size_t Q3_SZ  = (size_t)NB*1568;
  const size_t needFull = (size_t)WS_BIG_OFF + QX_SZ + I1_SZ + Q3_SZ;

  k_init<<<dim3(1), dim3(64), 0, stream>>>(ws);
  k_absx<<<dim3(2048), dim3(256), 0, stream>>>(x, ws);
  k_wq<<<dim3(1), dim3(256), 0, stream>>>(w1, b1, w2, wf, ws);

  if (ws_size >= needFull){
    signed char* qx  = (signed char*)(ws + WS_BIG_OFF);
    short*       i1p = (short*)(ws + WS_BIG_OFF + QX_SZ);
    int*         p2g = (int*)i1p;
    signed char* q3g = (signed char*)(ws + WS_BIG_OFF + QX_SZ + I1_SZ);
    k_qx   <<<dim3(NB*240/256), dim3(256), 0, stream>>>(x, ws, qx);
    k_conv1<<<dim3(NB*196/256), dim3(256), 0, stream>>>(qx, ws, i1p);
    k_s1   <<<dim3(1), dim3(256), 0, stream>>>(b2, ws);
    k_conv2r<<<dim3(NB/4), dim3(256), 0, stream>>>(ws, i1p, p2g);
    k_s2   <<<dim3(1), dim3(256), 0, stream>>>(bf, ws);
    k_rq2  <<<dim3(NB*1568/1024), dim3(256), 0, stream>>>(ws, p2g, q3g);
    k_fc   <<<dim3(256), dim3(256), 0, stream>>>(ws, q3g, i3);
  } else {
    short* i1p = (short*)(ws + WS_BIG_OFF);
    k_c1<<<dim3(NB), dim3(256), 0, stream>>>(x, ws, i1p);
    k_s1<<<dim3(1), dim3(256), 0, stream>>>(b2, ws);
    k_c2<false><<<dim3(NB), dim3(256), 0, stream>>>(ws, i1p, i3);
    k_s2<<<dim3(1), dim3(256), 0, stream>>>(bf, ws);
    k_c2<true ><<<dim3(NB), dim3(256), 0, stream>>>(ws, i1p, i3);
  }
  k_s3<<<dim3(1), dim3(1), 0, stream>>>(ws);
  k_out<<<dim3((NB*10+255)/256), dim3(256), 0, stream>>>(ws, out);
}

// Round 6
// 201.169 us; speedup vs baseline: 7.1820x; 1.7605x over previous
//
#include <hip/hip_runtime.h>
#include <climits>

#define NB 8192
#define EPSQ 1e-8f

using i32x4  = __attribute__((ext_vector_type(4)))  int;
using i32x16 = __attribute__((ext_vector_type(16))) int;

// ---- ws layout (byte offsets) ----
// scalars F: 0 s0,1 sx1,2 sw1,3 sb1,4 sy1,5 sr1,6 sx2,7 sw2,8 sb2,9 sy2,10 sr2,11 sx3,12 swf,13 sb3,14 sy3
#define WS_F(ws)     ((float*)(ws))
#define WS_I(ws)     ((int*)((char*)(ws)+128))      // 0 maxabs_x bits,1 maxabsI1,2 maxI1,3 maxabsI2,4 maxI2,5 maxabsI3
#define WS_B1L(ws)   ((int*)((char*)(ws)+384))      // [16]
#define WS_B2L(ws)   ((int*)((char*)(ws)+448))      // [32]
#define WS_BFL(ws)   ((int*)((char*)(ws)+576))      // [16]
#define WS_M1F(ws)   ((float*)((char*)(ws)+640))    // [144]
#define WS_B1F(ws)   ((float*)((char*)(ws)+1280))   // [16] float bias levels (conv1)
#define WS_B2FR(ws)  ((char*)(ws)+2048)             // [5][64][16] conv2 i8 B-fragments
#define WS_Q2TAB(ws) ((signed char*)((char*)(ws)+7168))  // [256] k1 level -> q2 int8 level
#define WS_Q3TAB(ws) ((signed char*)((char*)(ws)+7424))  // [256] k2 level -> q3 int8 level
#define WS_B1FR(ws)  ((char*)(ws)+7680)             // [64][16] conv1 i8 B-fragments (fallback)
#define WS_MFF(ws)   ((float*)((char*)(ws)+20480))  // [10][1568] float fc levels (fallback)
#define WS_WFP(ws)   ((char*)(ws)+83200)            // [49][64][16] fc i8 B-fragments (50176 B)
// per-block reduction slots (no atomics in full path)
#define WS_RA1(ws)   ((int*)((char*)(ws)+139264))   // [6272] conv1 amax
#define WS_RS1(ws)   ((int*)((char*)(ws)+164352))   // [6272] conv1 smax
#define WS_RA2(ws)   ((int*)((char*)(ws)+189440))   // [2048] conv2 amax
#define WS_RS2(ws)   ((int*)((char*)(ws)+197632))   // [2048] conv2 smax
#define WS_RA3(ws)   ((int*)((char*)(ws)+205824))   // [256]  fc amax
#define WS_RAX(ws)   ((float*)((char*)(ws)+206848)) // [2048] absx per-block max
#define WS_BIG_OFF   217088

__device__ __forceinline__ float clampf(float v, float lo, float hi){ return fminf(fmaxf(v, lo), hi); }

__device__ __forceinline__ float wave_max_f(float v){
#pragma unroll
  for (int off=32; off; off>>=1) v = fmaxf(v, __shfl_down(v, off, 64));
  return v;
}
__device__ __forceinline__ int wave_max_i(int v){
#pragma unroll
  for (int off=32; off; off>>=1) v = max(v, __shfl_down(v, off, 64));
  return v;
}

// fallback-path block reduce + global atomics
__device__ __forceinline__ void reduce2_atomic(int amax, int smax, int* gA, int* gS){
  amax = wave_max_i(amax); smax = wave_max_i(smax);
  __shared__ int sA[4], sS[4];
  int w = threadIdx.x>>6, l = threadIdx.x&63;
  if (l==0){ sA[w]=amax; sS[w]=smax; }
  __syncthreads();
  if (threadIdx.x==0){
#pragma unroll
    for (int i=1;i<4;i++){ amax=max(amax,sA[i]); smax=max(smax,sS[i]); }
    atomicMax(gA, amax); atomicMax(gS, smax);
  }
}

// full-path block reduce + plain per-block store (no contention)
__device__ __forceinline__ void reduce2_store(int amax, int smax, int* pA, int* pS){
  amax = wave_max_i(amax); smax = wave_max_i(smax);
  __shared__ int sA[4], sS[4];
  int w = threadIdx.x>>6, l = threadIdx.x&63;
  if (l==0){ sA[w]=amax; sS[w]=smax; }
  __syncthreads();
  if (threadIdx.x==0){
#pragma unroll
    for (int i=1;i<4;i++){ amax=max(amax,sA[i]); smax=max(smax,sS[i]); }
    *pA = amax; *pS = smax;
  }
}

__global__ void k_init(char* ws){
  int* I = WS_I(ws);
  if (threadIdx.x==0){ I[0]=0; I[1]=0; I[2]=INT_MIN; I[3]=0; I[4]=INT_MIN; I[5]=0; }
}

__global__ void k_absx(const float* __restrict__ x, char* ws){
  const float4* x4 = (const float4*)x;
  const int n4 = NB*784/4;
  float m = 0.f;
  for (int i = blockIdx.x*blockDim.x + threadIdx.x; i < n4; i += gridDim.x*blockDim.x){
    float4 v = x4[i];
    m = fmaxf(m, fmaxf(fmaxf(fabsf(v.x),fabsf(v.y)), fmaxf(fabsf(v.z),fabsf(v.w))));
  }
  m = wave_max_f(m);
  __shared__ float sm[4];
  int w = threadIdx.x>>6;
  if ((threadIdx.x&63)==0) sm[w]=m;
  __syncthreads();
  if (threadIdx.x==0){
    m = fmaxf(fmaxf(sm[0],sm[1]), fmaxf(sm[2],sm[3]));
    WS_RAX(ws)[blockIdx.x] = m;     // per-block slot, no atomic
  }
}

__global__ void k_wq(const float* __restrict__ w1, const float* __restrict__ b1,
                     const float* __restrict__ w2, const float* __restrict__ wf,
                     char* ws){
  __shared__ float red[256];
  float* F = WS_F(ws);
  int t = threadIdx.x;
  auto bmaxabs = [&](const float* p, int n)->float{
    float m=0.f; for (int i=t;i<n;i+=256) m=fmaxf(m,fabsf(p[i]));
    red[t]=m; __syncthreads();
    for (int s=128;s;s>>=1){ if (t<s) red[t]=fmaxf(red[t],red[t+s]); __syncthreads(); }
    float r=red[0]; __syncthreads(); return r;
  };
  float mw1 = bmaxabs(w1,144);
  float mw2 = bmaxabs(w2,4608);
  float mwf = bmaxabs(wf,15680);
  // reduce per-block absx maxima
  float mxv=0.f;
  for (int i=t;i<2048;i+=256) mxv=fmaxf(mxv,WS_RAX(ws)[i]);
  red[t]=mxv; __syncthreads();
  for (int s=128;s;s>>=1){ if (t<s) red[t]=fmaxf(red[t],red[t+s]); __syncthreads(); }
  float mx=red[0]; __syncthreads();

  float s0  = fmaxf(mx/127.f, EPSQ);
  float sx1 = fmaxf((127.f*s0)/127.f, EPSQ);
  float sw1 = fmaxf(mw1/7.f, EPSQ);
  float sw2 = fmaxf(mw2/7.f, EPSQ);
  float swf = fmaxf(mwf/7.f, EPSQ);
  float sb1 = sx1*sw1;
  if (t==0){ F[0]=s0; F[1]=sx1; F[2]=sw1; F[3]=sb1; F[7]=sw2; F[12]=swf; }
  float* m1f = WS_M1F(ws);
  for (int i=t;i<144;i+=256) m1f[i] = clampf(rintf(w1[i]/sw1), -7.f, 7.f);
  if (t<16){
    int bl = (int)rintf(b1[t]/sb1);
    WS_B1L(ws)[t] = bl;
    WS_B1F(ws)[t] = (float)bl;
  }
  // conv2 B-fragments: chunk c, lane l -> col oc=l&31, k=(l>>5)*16+j; tap=2c+(l>>5), ch=j
  for (int i=t;i<5120;i+=256){
    int chunk=i>>10, r=i&1023, ln=r>>4, j=r&15;
    int tap=2*chunk+(ln>>5), oc=ln&31;
    signed char v=0;
    if (tap<9) v=(signed char)clampf(rintf(w2[oc*144 + j*9 + tap]/sw2), -7.f, 7.f);
    WS_B2FR(ws)[i]=v;
  }
  // conv1 B-fragments (fallback k_c1)
  for (int i=t;i<1024;i+=256){
    int ln=i>>4, j=i&15;
    int k=(ln>>5)*16+j, oc=ln&31;
    signed char v=0;
    if (k<9 && oc<16) v=(signed char)clampf(rintf(w1[oc*9+k]/sw1), -7.f, 7.f);
    WS_B1FR(ws)[i]=v;
  }
  float* mff = WS_MFF(ws);
  for (int i=t;i<15680;i+=256) mff[i] = clampf(rintf(wf[i]/swf), -7.f, 7.f);
  // fc B-fragments: chunk c, lane l: col oc=l&31, k=c*32+(l>>5)*16+j; feature f=ch*49+cell, k=cell*32+ch
  for (int i=t;i<50176;i+=256){
    int chunk=i>>10, r2=i&1023, ln=r2>>4, j=r2&15;
    int oc=ln&31, k=chunk*32+(ln>>5)*16+j;
    int cell=k>>5, ch=k&31;
    signed char v=0;
    if (oc<10) v=(signed char)clampf(rintf(wf[oc*1568 + ch*49 + cell]/swf), -7.f, 7.f);
    ((signed char*)WS_WFP(ws))[i]=v;
  }
}

template<bool FULLR>
__global__ void k_s1(const float* __restrict__ b2, char* ws){
  float* F=WS_F(ws); int* I=WS_I(ws);
  __shared__ int rA[256], rS[256];
  __shared__ float sh[4];
  int t=threadIdx.x;
  int amaxI, smaxI;
  if constexpr (FULLR){
    int a=0, s=INT_MIN;
    const int* ra=WS_RA1(ws); const int* rs=WS_RS1(ws);
    for (int i=t;i<6272;i+=256){ a=max(a,ra[i]); s=max(s,rs[i]); }
    rA[t]=a; rS[t]=s; __syncthreads();
    for (int st=128;st;st>>=1){ if (t<st){ rA[t]=max(rA[t],rA[t+st]); rS[t]=max(rS[t],rS[t+st]); } __syncthreads(); }
    amaxI=rA[0]; smaxI=rS[0];
  } else { amaxI=I[1]; smaxI=I[2]; }
  if (t==0){
    float sb1=F[3];
    float sy1 = fmaxf((sb1*(float)amaxI)/127.f, EPSQ);
    float mp  = sb1*(float)smaxI;
    float P1  = clampf(rintf(mp/sy1), 0.f, 127.f);
    float sr1 = fmaxf((sy1*P1)/15.f, EPSQ);
    float N1  = clampf(rintf((sy1*P1)/sr1), 0.f, 15.f);
    float sx2 = fmaxf((N1*sr1)/127.f, EPSQ);
    float sb2 = sx2*F[7];
    F[4]=sy1; F[5]=sr1; F[6]=sx2; F[8]=sb2;
    sh[0]=sy1; sh[1]=sr1; sh[2]=sx2; sh[3]=sb2;
  }
  __syncthreads();
  float sy1=sh[0], sr1=sh[1], sx2=sh[2], sb2=sh[3];
  int k = t-128;
  float n = (k>0) ? clampf(rintf((sy1*(float)k)/sr1), 0.f, 15.f) : 0.f;
  WS_Q2TAB(ws)[t] = (signed char)clampf(rintf((n*sr1)/sx2), -128.f, 127.f);
  if (t<32) WS_B2L(ws)[t] = (int)rintf(b2[t]/sb2);
}

template<bool FULLR>
__global__ void k_s2(const float* __restrict__ bf, char* ws){
  float* F=WS_F(ws); int* I=WS_I(ws);
  __shared__ int rA[256], rS[256];
  __shared__ float sh[4];
  int t=threadIdx.x;
  int amaxI, smaxI;
  if constexpr (FULLR){
    int a=0, s=INT_MIN;
    const int* ra=WS_RA2(ws); const int* rs=WS_RS2(ws);
    for (int i=t;i<2048;i+=256){ a=max(a,ra[i]); s=max(s,rs[i]); }
    rA[t]=a; rS[t]=s; __syncthreads();
    for (int st=128;st;st>>=1){ if (t<st){ rA[t]=max(rA[t],rA[t+st]); rS[t]=max(rS[t],rS[t+st]); } __syncthreads(); }
    amaxI=rA[0]; smaxI=rS[0];
  } else { amaxI=I[3]; smaxI=I[4]; }
  if (t==0){
    float sb2=F[8];
    float sy2 = fmaxf((sb2*(float)amaxI)/127.f, EPSQ);
    float mp  = sb2*(float)smaxI;
    float P2  = clampf(rintf(mp/sy2), 0.f, 127.f);
    float sr2 = fmaxf((sy2*P2)/15.f, EPSQ);
    float N2  = clampf(rintf((sy2*P2)/sr2), 0.f, 15.f);
    float sx3 = fmaxf((N2*sr2)/127.f, EPSQ);
    float sb3 = sx3*F[12];
    F[9]=sy2; F[10]=sr2; F[11]=sx3; F[13]=sb3;
    sh[0]=sy2; sh[1]=sr2; sh[2]=sx3; sh[3]=sb3;
  }
  __syncthreads();
  float sy2=sh[0], sr2=sh[1], sx3=sh[2], sb3=sh[3];
  int k = t-128;
  float n = (k>0) ? clampf(rintf((sy2*(float)k)/sr2), 0.f, 15.f) : 0.f;
  WS_Q3TAB(ws)[t] = (signed char)clampf(rintf((n*sr2)/sx3), -128.f, 127.f);
  if (t<16) WS_BFL(ws)[t] = (t<10) ? (int)rintf(bf[t]/sb3) : 0;
}

template<bool FULLR>
__global__ void k_s3(char* ws){
  float* F=WS_F(ws); int* I=WS_I(ws);
  __shared__ int rA[256];
  int t=threadIdx.x;
  int amaxI;
  if constexpr (FULLR){
    rA[t] = WS_RA3(ws)[t];
    __syncthreads();
    for (int st=128;st;st>>=1){ if (t<st) rA[t]=max(rA[t],rA[t+st]); __syncthreads(); }
    amaxI = rA[0];
  } else { amaxI = I[5]; }
  if (t==0) F[14] = fmaxf((F[13]*(float)amaxI)/127.f, EPSQ);
}

// ================= NEW PATH =================
// P2a: quantize x -> padded i8 [NB][30][32], zero borders. 1 thread = 1 u32 word.
__global__ void k_qx(const float* __restrict__ x, const char* __restrict__ ws,
                     signed char* __restrict__ qx){
  const float s0 = ((const float*)ws)[0];
  int id = blockIdx.x*256 + threadIdx.x;          // < NB*240
  int img = id/240, w = id - img*240;
  int r = w>>3, c4 = (w&7)<<2;
  const float* xi = x + img*784;
  unsigned out = 0;
#pragma unroll
  for (int j=0;j<4;j++){
    int c = c4+j;
    bool valid = (r>=1) && (r<=28) && (c>=1) && (c<=28);
    int q = 0;
    if (valid){
      float xv = xi[(r-1)*28 + (c-1)];
      q = (int)clampf(rintf(xv/s0), -128.f, 127.f);
    }
    out |= ((unsigned)(unsigned char)(signed char)q) << (8*j);
  }
  ((unsigned*)qx)[id] = out;
}

// P2b: conv1 + pool1 + per-block (amax,smax) store. 1 thread = 1 (img, pooled-cell).
__global__ __launch_bounds__(256) void k_conv1(const signed char* __restrict__ qx,
                                               char* __restrict__ ws,
                                               short* __restrict__ i1p){
  const int t = threadIdx.x;
  const int id = blockIdx.x*256 + t;
  const int img = id/196, cell = id - img*196;
  const int py = cell/14, px = cell - py*14;
  const signed char* qb = qx + img*960 + (2*py)*32;
  const int pc0 = 2*px;
  const int al = pc0 & ~3, sh = (pc0&3)*8;
  float in[4][4];
#pragma unroll
  for (int rr=0; rr<4; rr++){
    unsigned lo = *(const unsigned*)(qb + rr*32 + al);
    unsigned hi = *(const unsigned*)(qb + rr*32 + al + 4);
    unsigned wrd = (unsigned)(((((unsigned long long)hi)<<32)|lo) >> sh);
#pragma unroll
    for (int cc=0; cc<4; cc++)
      in[rr][cc] = (float)(signed char)((wrd >> (8*cc)) & 0xFFu);
  }
  const float* __restrict__ m1f = WS_M1F(ws);   // uniform -> s_load
  const float* __restrict__ b1f = WS_B1F(ws);
  int amax=0, smax=INT_MIN;
  short outv[16];
#pragma unroll
  for (int oc=0; oc<16; oc++){
    float b = b1f[oc];
    float a00=b, a01=b, a10=b, a11=b;
#pragma unroll
    for (int dy=0; dy<3; dy++){
#pragma unroll
      for (int dx=0; dx<3; dx++){
        float wt = m1f[oc*9+dy*3+dx];
        a00 = fmaf(in[dy  ][dx  ], wt, a00);
        a01 = fmaf(in[dy  ][dx+1], wt, a01);
        a10 = fmaf(in[dy+1][dx  ], wt, a10);
        a11 = fmaf(in[dy+1][dx+1], wt, a11);
      }
    }
    int v00=(int)a00, v01=(int)a01, v10=(int)a10, v11=(int)a11;
    int mx = max(max(v00,v01), max(v10,v11));
    int ax = max(max(v00<0?-v00:v00, v01<0?-v01:v01), max(v10<0?-v10:v10, v11<0?-v11:v11));
    amax = max(amax, ax);
    smax = max(smax, mx);
    outv[oc] = (short)mx;
  }
  int4* dst = (int4*)(i1p + (size_t)id*16);
  dst[0] = *(const int4*)&outv[0];
  dst[1] = *(const int4*)&outv[8];
  reduce2_store(amax, smax, &WS_RA1(ws)[blockIdx.x], &WS_RS1(ws)[blockIdx.x]);
}

// P3: conv2 MFMA (wave = image) + per-block (amax,smax) + pool2 -> pooled-I2 int32 in-place.
__global__ __launch_bounds__(256) void k_conv2r(char* __restrict__ ws,
                                                short* __restrict__ i1p,
                                                int* __restrict__ p2g){
  constexpr int WSLICE = 4096 + 6272;
  __shared__ __align__(16) char arena[4*WSLICE];
  const int t=threadIdx.x, lane=t&63, wid=t>>6;
  const int img = blockIdx.x*4 + wid;
  char* wbase = arena + wid*WSLICE;
  signed char* q2p = (signed char*)wbase;            // [16][16][16ch] padded, zero borders
  int* poolw = (int*)(wbase + 4096);                 // [49][32]
  const float* F = WS_F(ws);
  const float sb1=F[3], sy1=F[4];
  const signed char* q2t = WS_Q2TAB(ws);

#pragma unroll
  for (int k=0;k<8;k++) ((unsigned long long*)q2p)[lane + 64*k] = 0ULL;
#pragma unroll
  for (int k=0;k<24;k++) poolw[lane + 64*k] = INT_MIN;
  if (lane<32) poolw[1536+lane] = INT_MIN;

  const unsigned* src = (const unsigned*)(i1p + (size_t)img*3136);
  for (int k=0;k<25;k++){
    int idx = lane + 64*k;
    if (idx >= 1568) break;
    unsigned wv = src[idx];
    int e0 = idx*2;
    int cellc = e0 >> 4, ch = e0 & 15;
    int pyc = cellc/14, pxc = cellc - pyc*14;
    int m0 = (int)(short)(wv & 0xFFFFu);
    int m1 = (int)(short)(wv >> 16);
    float k10 = clampf(rintf((sb1*(float)m0)/sy1), -128.f, 127.f);
    float k11 = clampf(rintf((sb1*(float)m1)/sy1), -128.f, 127.f);
    int b0 = (int)(unsigned char)q2t[(int)k10+128];
    int b1 = (int)(unsigned char)q2t[(int)k11+128];
    *(unsigned short*)(q2p + ((pyc+1)*16 + (pxc+1))*16 + ch) = (unsigned short)(b0 | (b1<<8));
  }

  i32x4 bfr[5];
  const i32x4* bg = (const i32x4*)WS_B2FR(ws);
#pragma unroll
  for (int c=0;c<5;c++) bfr[c] = bg[c*64+lane];
  const int col = lane&31, h = lane>>5;
  const int bias = WS_B2L(ws)[col];
  int amax2=0, smax2=INT_MIN;
  const int TOFF[9] = {0,1,2,16,17,18,32,33,34};

#pragma unroll
  for (int mt=0; mt<7; mt++){
    int p = mt*32 + col;
    bool pv = p < 196;
    int oy = p/14, ox = p - oy*14;
    int E0 = oy*16 + ox;
    i32x16 acc;
#pragma unroll
    for (int r=0;r<16;r++) acc[r] = bias;
#pragma unroll
    for (int c=0;c<5;c++){
      int toff = h ? ((2*c+1<9)? TOFF[2*c+1] : -1) : TOFF[2*c];
      bool ok = pv && (toff>=0);
      int entry = ok ? (E0 + toff) : 0;
      i32x4 a = *(const i32x4*)(q2p + entry*16);
      acc = __builtin_amdgcn_mfma_i32_32x32x32_i8(a, bfr[c], acc, 0,0,0);
    }
#pragma unroll
    for (int r=0;r<16;r++){
      int row = (r&3) + 8*(r>>2) + 4*h;
      int pp = mt*32 + row;
      if (pp < 196){
        int v = acc[r];
        amax2 = max(amax2, v<0?-v:v);
        smax2 = max(smax2, v);
        int qy = pp/14, qx2 = pp - qy*14;
        int cc = (qy>>1)*7 + (qx2>>1);
        atomicMax(&poolw[cc*32 + col], v);   // LDS atomic, no contention issue
      }
    }
  }
  reduce2_store(amax2, smax2, &WS_RA2(ws)[blockIdx.x], &WS_RS2(ws)[blockIdx.x]);
  int* dst = p2g + (size_t)img*1568;
#pragma unroll
  for (int k=0;k<24;k++){ int idx = lane+64*k; dst[idx] = poolw[idx]; }
  if (lane<32) dst[1536+lane] = poolw[1536+lane];
}

// P4: pooled-I2 -> q3 int8 levels (pure stream)
__global__ void k_rq2(const char* __restrict__ ws, const int* __restrict__ p2g,
                      signed char* __restrict__ q3g){
  const float* F = (const float*)ws;
  const float sb2 = F[8], sy2 = F[9];
  const signed char* q3t = WS_Q3TAB(ws);
  int id = blockIdx.x*256 + threadIdx.x;
  i32x4 m4 = ((const i32x4*)p2g)[id];
  unsigned out=0;
#pragma unroll
  for (int j=0;j<4;j++){
    float k2 = clampf(rintf((sb2*(float)m4[j])/sy2), -128.f, 127.f);
    out |= ((unsigned)(unsigned char)q3t[(int)k2+128]) << (8*j);
  }
  ((unsigned*)q3g)[id] = out;
}

// P5: fc as i8 MFMA GEMM, 256 blocks, K split across 4 waves, LDS combine.
__global__ __launch_bounds__(256) void k_fc(char* __restrict__ ws,
                                            const signed char* __restrict__ q3g,
                                            int* __restrict__ i3out){
  __shared__ int part[3][16][64];
  int t=threadIdx.x, lane=t&63, wid=t>>6;
  int mt = blockIdx.x;              // 0..255
  const int col=lane&31, h=lane>>5;
  const signed char* A0 = q3g + (size_t)(mt*32 + col)*1568 + 16*h;
  const i32x4* wfp = (const i32x4*)WS_WFP(ws);
  i32x16 acc;
#pragma unroll
  for (int r=0;r<16;r++) acc[r]=0;
  for (int c=wid; c<49; c+=4){
    i32x4 a = *(const i32x4*)(A0 + c*32);
    i32x4 b = wfp[c*64 + lane];
    acc = __builtin_amdgcn_mfma_i32_32x32x32_i8(a, b, acc, 0,0,0);
  }
  if (wid>0){
#pragma unroll
    for (int r=0;r<16;r++) part[wid-1][r][lane] = acc[r];
  }
  __syncthreads();
  if (wid==0){
    int bias = (col<10) ? WS_BFL(ws)[col] : 0;
    int am=0;
#pragma unroll
    for (int r=0;r<16;r++){
      int v = acc[r] + part[0][r][lane] + part[1][r][lane] + part[2][r][lane] + bias;
      int row=(r&3)+8*(r>>2)+4*h;
      int img = mt*32+row;
      if (col<10){
        i3out[img*10+col] = v;
        am = max(am, v<0?-v:v);
      }
    }
    am = wave_max_i(am);
    if (lane==0) WS_RA3(ws)[blockIdx.x] = am;
  }
}

// ================= FALLBACK (verified R3 tier-A) =================
__global__ __launch_bounds__(256) void k_c1(const float* __restrict__ x, char* __restrict__ ws,
                                            short* __restrict__ i1p){
  constexpr int OFF_K0=0, OFF_A=960, OFF_I1=13760, OFF_B1=38848;
  __shared__ __align__(16) char arena[38912];
  signed char* k0b = (signed char*)(arena+OFF_K0);
  signed char* Abuf= (signed char*)(arena+OFF_A);
  short*       I1s = (short*)(arena+OFF_I1);
  int*         b1i = (int*)(arena+OFF_B1);

  const int tid=threadIdx.x, img=blockIdx.x;
  const int lane=tid&63, wid=tid>>6;
  const float s0 = WS_F(ws)[0];

  if (tid<16) b1i[tid]=WS_B1L(ws)[tid];
  for (int i=tid;i<240;i+=256) ((int*)k0b)[i]=0;
  for (int i=tid;i<3200;i+=256) ((int*)Abuf)[i]=0;
  __syncthreads();
  const float* xi = x + img*784;
  for (int i=tid;i<784;i+=256){
    int r=i/28, c=i-r*28;
    float v = clampf(rintf(xi[i]/s0), -128.f, 127.f);
    k0b[(r+1)*32 + (c+1)] = (signed char)v;
  }
  __syncthreads();
  for (int p=tid;p<784;p+=256){
    int oy=p/28, ox=p-oy*28;
    int base = oy*32+ox;
    int al = base & ~3, sh = (base&3)*8;
    unsigned l0a=*(const unsigned*)(k0b+al),    l1a=*(const unsigned*)(k0b+al+4);
    unsigned l0b=*(const unsigned*)(k0b+al+32), l1b=*(const unsigned*)(k0b+al+36);
    unsigned l0c=*(const unsigned*)(k0b+al+64), l1c=*(const unsigned*)(k0b+al+68);
    unsigned u0=(unsigned)(((((unsigned long long)l1a)<<32)|l0a)>>sh);
    unsigned u1=(unsigned)(((((unsigned long long)l1b)<<32)|l0b)>>sh);
    unsigned u2=(unsigned)(((((unsigned long long)l1c)<<32)|l0c)>>sh);
    i32x4 row;
    row[0]=(int)((u0&0xFFFFFFu)|(u1<<24));
    row[1]=(int)(((u1>>8)&0xFFFFu)|((u2&0xFFFFu)<<16));
    row[2]=(int)((u2>>16)&0xFFu);
    row[3]=0;
    *(i32x4*)(Abuf + p*16) = row;
  }
  __syncthreads();
  const i32x4 bfr = ((const i32x4*)WS_B1FR(ws))[lane];
  const int col=lane&31, h=lane>>5;
  const int bias=(col<16)? b1i[col] : 0;
  int amax=0, smax=INT_MIN;
  for (int mt=wid; mt<25; mt+=4){
    i32x4 a={0,0,0,0};
    if (h==0) a = *(const i32x4*)(Abuf + (mt*32+col)*16);
    i32x16 acc;
#pragma unroll
    for (int r=0;r<16;r++) acc[r]=bias;
    acc=__builtin_amdgcn_mfma_i32_32x32x32_i8(a,bfr,acc,0,0,0);
#pragma unroll
    for (int r=0;r<16;r++){
      int row=(r&3)+8*(r>>2)+4*h;
      int p=mt*32+row;
      if (p<784 && col<16){
        int v=acc[r];
        amax=max(amax,v<0?-v:v); smax=max(smax,v);
        I1s[p*16+col]=(short)v;
      }
    }
  }
  __syncthreads();
  for (int i=tid;i<3136;i+=256){
    int pp=i>>4, c=i&15, py=pp/14, px=pp-py*14;
    int p0=py*56+px*2;
    int m=max(max((int)I1s[p0*16+c],(int)I1s[(p0+1)*16+c]),
              max((int)I1s[(p0+28)*16+c],(int)I1s[(p0+29)*16+c]));
    i1p[(size_t)img*3136 + i]=(short)m;
  }
  reduce2_atomic(amax,smax,&WS_I(ws)[1],&WS_I(ws)[2]);
}

template<bool FIN>
__global__ __launch_bounds__(256) void k_c2(char* __restrict__ ws, const short* __restrict__ i1p,
                                            int* __restrict__ i3out){
  constexpr int OFF_Q2L=0, OFF_B2I=3136, OFF_Q2T=3264, OFF_N2=3520,
                OFF_Q3T=9792, OFF_BFS=10048, OFF_Q3F=10112, OFF_RED=16384;
  constexpr int ARENA = FIN ? 16544 : 3520;
  __shared__ __align__(16) char arena[ARENA];
  signed char* q2l=(signed char*)(arena+OFF_Q2L);
  int* b2li=(int*)(arena+OFF_B2I);
  signed char* q2t=(signed char*)(arena+OFF_Q2T);

  const int tid=threadIdx.x, img=blockIdx.x;
  const int lane=tid&63, wid=tid>>6;
  const float* F=WS_F(ws);
  const float sb1=F[3], sy1=F[4];

  q2t[tid]=WS_Q2TAB(ws)[tid];
  if (tid<32) b2li[tid]=WS_B2L(ws)[tid];
  if constexpr (FIN){
    ((signed char*)(arena+OFF_Q3T))[tid]=WS_Q3TAB(ws)[tid];
    if (tid<16) ((int*)(arena+OFF_BFS))[tid]=WS_BFL(ws)[tid];
  }
  __syncthreads();
  for (int i=tid;i<3136;i+=256){
    int m=(int)i1p[(size_t)img*3136+i];
    float k1=clampf(rintf((sb1*(float)m)/sy1),-128.f,127.f);
    q2l[i]=q2t[(int)k1+128];
  }
  __syncthreads();

  i32x4 bfr[5];
  {
    const i32x4* bg=(const i32x4*)WS_B2FR(ws);
#pragma unroll
    for (int c=0;c<5;c++) bfr[c]=bg[c*64+lane];
  }
  const int col=lane&31, h=lane>>5;
  const int bias=b2li[col];
  int amax2=0, smax2=INT_MIN;
  float sb2=0.f, sy2=0.f;
  signed char* n2buf=nullptr;
  if constexpr (FIN){ sb2=F[8]; sy2=F[9]; n2buf=(signed char*)(arena+OFF_N2); }

  for (int mt=wid; mt<7; mt+=4){
    const int p=mt*32+col;
    const bool pv=p<196;
    const int oy=p/14, ox=p-oy*14;
    i32x16 acc;
#pragma unroll
    for (int r=0;r<16;r++) acc[r]=bias;
#pragma unroll
    for (int c=0;c<5;c++){
      const int tap=2*c+h;
      i32x4 a={0,0,0,0};
      if (pv && tap<9){
        const int iy=oy+tap/3-1, ix=ox+tap-(tap/3)*3-1;
        if ((unsigned)iy<14u && (unsigned)ix<14u) a=*(const i32x4*)(q2l+(iy*14+ix)*16);
      }
      acc=__builtin_amdgcn_mfma_i32_32x32x32_i8(a,bfr[c],acc,0,0,0);
    }
#pragma unroll
    for (int r=0;r<16;r++){
      const int row=(r&3)+8*(r>>2)+4*h;
      const int pp=mt*32+row;
      if (pp<196){
        const int v=acc[r];
        if constexpr (!FIN){ amax2=max(amax2,v<0?-v:v); smax2=max(smax2,v); }
        else {
          n2buf[col*196+pp]=(signed char)clampf(rintf((sb2*(float)v)/sy2),-128.f,127.f);
        }
      }
    }
  }
  if constexpr (!FIN){
    reduce2_atomic(amax2,smax2,&WS_I(ws)[3],&WS_I(ws)[4]);
    return;
  } else {
    __syncthreads();
    signed char* q3t_s=(signed char*)(arena+OFF_Q3T);
    float* q3f=(float*)(arena+OFF_Q3F);
    for (int i=tid;i<1568;i+=256){
      int cch=i/49, s=i-cch*49, qy=s/7, qx=s-qy*7;
      int b=cch*196+qy*28+qx*2;
      int m=max(max((int)n2buf[b],(int)n2buf[b+1]),max((int)n2buf[b+14],(int)n2buf[b+15]));
      q3f[i]=(float)q3t_s[m+128];
    }
    __syncthreads();
    const float* mff=WS_MFF(ws);
    float a10[10];
#pragma unroll
    for (int o=0;o<10;o++) a10[o]=0.f;
    for (int k=tid;k<1568;k+=256){
      float qa=q3f[k];
#pragma unroll
      for (int o=0;o<10;o++) a10[o]=fmaf(qa,mff[o*1568+k],a10[o]);
    }
#pragma unroll
    for (int o=0;o<10;o++){
#pragma unroll
      for (int off=32;off;off>>=1) a10[o]+=__shfl_down(a10[o],off,64);
    }
    float* redf=(float*)(arena+OFF_RED);
    int* bfs=(int*)(arena+OFF_BFS);
    if (lane==0){
#pragma unroll
      for (int o=0;o<10;o++) redf[wid*10+o]=a10[o];
    }
    __syncthreads();
    if (tid<10){
      float s=redf[tid]+redf[10+tid]+redf[20+tid]+redf[30+tid];
      int I3v=(int)s+bfs[tid];
      i3out[img*10+tid]=I3v;
      redf[tid]=(float)(I3v<0?-I3v:I3v);
    }
    __syncthreads();
    if (tid==0){
      int m=0;
#pragma unroll
      for (int o=0;o<10;o++) m=max(m,(int)redf[o]);
      atomicMax(&WS_I(ws)[5],m);
    }
  }
}

__global__ void k_out(char* ws, float* __restrict__ out){
  float* F=WS_F(ws);
  float sb3=F[13], sy3=F[14];
  int i = blockIdx.x*blockDim.x + threadIdx.x;
  if (i < NB*10){
    int iv = ((const int*)out)[i];
    float y = sb3*(float)iv;
    float q = clampf(rintf(y/sy3), -128.f, 127.f);
    out[i] = q*sy3;
  }
}

extern "C" void kernel_launch(void* const* d_in, const int* in_sizes, int n_in,
                              void* d_out, int out_size, void* d_ws, size_t ws_size,
                              hipStream_t stream){
  const float* x  = (const float*)d_in[0];
  const float* w1 = (const float*)d_in[1];
  const float* b1 = (const float*)d_in[2];
  const float* w2 = (const float*)d_in[3];
  const float* b2 = (const float*)d_in[4];
  const float* wf = (const float*)d_in[5];
  const float* bf = (const float*)d_in[6];
  char* ws = (char*)d_ws;
  float* out = (float*)d_out;
  int* i3 = (int*)d_out;

  const size_t QX_SZ  = (size_t)NB*960;
  const size_t I1_SZ  = (size_t)NB*6272;
  const size_t Q3_SZ  = (size_t)NB*1568;
  const size_t needFull = (size_t)WS_BIG_OFF + QX_SZ + I1_SZ + Q3_SZ;

  k_init<<<dim3(1), dim3(64), 0, stream>>>(ws);
  k_absx<<<dim3(2048), dim3(256), 0, stream>>>(x, ws);
  k_wq<<<dim3(1), dim3(256), 0, stream>>>(w1, b1, w2, wf, ws);

  if (ws_size >= needFull){
    signed char* qx  = (signed char*)(ws + WS_BIG_OFF);
    short*       i1p = (short*)(ws + WS_BIG_OFF + QX_SZ);
    int*         p2g = (int*)i1p;
    signed char* q3g = (signed char*)(ws + WS_BIG_OFF + QX_SZ + I1_SZ);
    k_qx   <<<dim3(NB*240/256), dim3(256), 0, stream>>>(x, ws, qx);
    k_conv1<<<dim3(NB*196/256), dim3(256), 0, stream>>>(qx, ws, i1p);
    k_s1<true><<<dim3(1), dim3(256), 0, stream>>>(b2, ws);
    k_conv2r<<<dim3(NB/4), dim3(256), 0, stream>>>(ws, i1p, p2g);
    k_s2<true><<<dim3(1), dim3(256), 0, stream>>>(bf, ws);
    k_rq2  <<<dim3(NB*1568/1024), dim3(256), 0, stream>>>(ws, p2g, q3g);
    k_fc   <<<dim3(256), dim3(256), 0, stream>>>(ws, q3g, i3);
    k_s3<true><<<dim3(1), dim3(256), 0, stream>>>(ws);
  } else {
    short* i1p = (short*)(ws + WS_BIG_OFF);
    k_c1<<<dim3(NB), dim3(256), 0, stream>>>(x, ws, i1p);
    k_s1<false><<<dim3(1), dim3(256), 0, stream>>>(b2, ws);
    k_c2<false><<<dim3(NB), dim3(256), 0, stream>>>(ws, i1p, i3);
    k_s2<false><<<dim3(1), dim3(256), 0, stream>>>(bf, ws);
    k_c2<true ><<<dim3(NB), dim3(256), 0, stream>>>(ws, i1p, i3);
    k_s3<false><<<dim3(1), dim3(256), 0, stream>>>(ws);
  }
  k_out<<<dim3((NB*10+255)/256), dim3(256), 0, stream>>>(ws, out);
}

// Round 7
// 148.658 us; speedup vs baseline: 9.7190x; 1.3532x over previous
//
#include <hip/hip_runtime.h>
#include <climits>

#define NB 8192
#define EPSQ 1e-8f

using i32x4  = __attribute__((ext_vector_type(4)))  int;
using i32x16 = __attribute__((ext_vector_type(16))) int;

// ---- ws layout (byte offsets) ----
// scalars F: 0 s0,1 sx1,2 sw1,3 sb1,4 sy1,5 sr1,6 sx2,7 sw2,8 sb2,9 sy2,10 sr2,11 sx3,12 swf,13 sb3,14 sy3
#define WS_F(ws)     ((float*)(ws))
#define WS_I(ws)     ((int*)((char*)(ws)+128))      // fallback atomics
#define WS_B1L(ws)   ((int*)((char*)(ws)+384))      // [16]
#define WS_B2L(ws)   ((int*)((char*)(ws)+448))      // [32]
#define WS_BFL(ws)   ((int*)((char*)(ws)+576))      // [16]
#define WS_M1F(ws)   ((float*)((char*)(ws)+640))    // [144]
#define WS_B1F(ws)   ((float*)((char*)(ws)+1280))   // [16] float bias levels (conv1)
#define WS_B2FR(ws)  ((char*)(ws)+2048)             // [5][64][16] conv2 i8 B-fragments
#define WS_Q2TAB(ws) ((signed char*)((char*)(ws)+7168))  // [256]
#define WS_Q3TAB(ws) ((signed char*)((char*)(ws)+7424))  // [256]
#define WS_B1FR(ws)  ((char*)(ws)+7680)             // [64][16] conv1 i8 B-fragments (fallback)
#define WS_MFF(ws)   ((float*)((char*)(ws)+20480))  // [10][1568] float fc levels (fallback)
#define WS_WFP(ws)   ((char*)(ws)+83200)            // [49][64][16] fc i8 B-fragments
// per-block reduction slots (no atomics in full path)
#define WS_RA1(ws)   ((int*)((char*)(ws)+139264))   // [6272] conv1 amax
#define WS_RS1(ws)   ((int*)((char*)(ws)+164352))   // [6272] conv1 smax
#define WS_RA2(ws)   ((int*)((char*)(ws)+189440))   // [2048] conv2 amax
#define WS_RS2(ws)   ((int*)((char*)(ws)+197632))   // [2048] conv2 smax
#define WS_RA3(ws)   ((int*)((char*)(ws)+205824))   // [256]  fc amax
#define WS_RAX(ws)   ((float*)((char*)(ws)+206848)) // [2048] absx per-block max
#define WS_WMX(ws)   ((float*)((char*)(ws)+215040)) // [81] weight maxabs partials
#define WS_BIG_OFF   217088

__device__ __forceinline__ float clampf(float v, float lo, float hi){ return fminf(fmaxf(v, lo), hi); }

__device__ __forceinline__ float wave_max_f(float v){
#pragma unroll
  for (int off=32; off; off>>=1) v = fmaxf(v, __shfl_down(v, off, 64));
  return v;
}
__device__ __forceinline__ int wave_max_i(int v){
#pragma unroll
  for (int off=32; off; off>>=1) v = max(v, __shfl_down(v, off, 64));
  return v;
}

__device__ __forceinline__ void reduce2_atomic(int amax, int smax, int* gA, int* gS){
  amax = wave_max_i(amax); smax = wave_max_i(smax);
  __shared__ int sA[4], sS[4];
  int w = threadIdx.x>>6, l = threadIdx.x&63;
  if (l==0){ sA[w]=amax; sS[w]=smax; }
  __syncthreads();
  if (threadIdx.x==0){
#pragma unroll
    for (int i=1;i<4;i++){ amax=max(amax,sA[i]); smax=max(smax,sS[i]); }
    atomicMax(gA, amax); atomicMax(gS, smax);
  }
}

__device__ __forceinline__ void reduce2_store(int amax, int smax, int* pA, int* pS){
  amax = wave_max_i(amax); smax = wave_max_i(smax);
  __shared__ int sA[4], sS[4];
  int w = threadIdx.x>>6, l = threadIdx.x&63;
  if (l==0){ sA[w]=amax; sS[w]=smax; }
  __syncthreads();
  if (threadIdx.x==0){
#pragma unroll
    for (int i=1;i<4;i++){ amax=max(amax,sA[i]); smax=max(smax,sS[i]); }
    *pA = amax; *pS = smax;
  }
}

__global__ void k_init(char* ws){
  int* I = WS_I(ws);
  if (threadIdx.x==0){ I[0]=0; I[1]=0; I[2]=INT_MIN; I[3]=0; I[4]=INT_MIN; I[5]=0; }
}

__global__ void k_absx(const float* __restrict__ x, char* ws){
  const float4* x4 = (const float4*)x;
  const int n4 = NB*784/4;
  float m = 0.f;
  for (int i = blockIdx.x*blockDim.x + threadIdx.x; i < n4; i += gridDim.x*blockDim.x){
    float4 v = x4[i];
    m = fmaxf(m, fmaxf(fmaxf(fabsf(v.x),fabsf(v.y)), fmaxf(fabsf(v.z),fabsf(v.w))));
  }
  m = wave_max_f(m);
  __shared__ float sm[4];
  int w = threadIdx.x>>6;
  if ((threadIdx.x&63)==0) sm[w]=m;
  __syncthreads();
  if (threadIdx.x==0){
    m = fmaxf(fmaxf(sm[0],sm[1]), fmaxf(sm[2],sm[3]));
    WS_RAX(ws)[blockIdx.x] = m;
  }
}

// full path: per-chunk weight maxabs partials. blocks: 0 -> w1(144); 1..18 -> w2; 19..80 -> wf
__global__ void k_wmax(const float* __restrict__ w1, const float* __restrict__ w2,
                       const float* __restrict__ wf, char* ws){
  __shared__ float red[256];
  int b = blockIdx.x, t = threadIdx.x;
  float m = 0.f;
  if (b==0){ if (t<144) m = fabsf(w1[t]); }
  else if (b<19){ m = fabsf(w2[(b-1)*256 + t]); }
  else { int i=(b-19)*256+t; if (i<15680) m = fabsf(wf[i]); }
  red[t]=m; __syncthreads();
  for (int s=128;s;s>>=1){ if (t<s) red[t]=fmaxf(red[t],red[t+s]); __syncthreads(); }
  if (t==0) WS_WMX(ws)[b]=red[0];
}

// full path: reduce partials -> all scale scalars + conv1 weight/bias levels
__global__ void k_scales(const float* __restrict__ w1, const float* __restrict__ b1, char* ws){
  __shared__ float red[256];
  float* F = WS_F(ws);
  int t = threadIdx.x;
  // weight maxima from 81 partials
  float vw1 = WS_WMX(ws)[0];
  float m2=0.f, mf=0.f;
  if (t<18) m2 = WS_WMX(ws)[1+t];
  if (t<62) mf = WS_WMX(ws)[19+t];
  red[t]=m2; __syncthreads();
  for (int s=128;s;s>>=1){ if (t<s) red[t]=fmaxf(red[t],red[t+s]); __syncthreads(); }
  float mw2=red[0]; __syncthreads();
  red[t]=mf; __syncthreads();
  for (int s=128;s;s>>=1){ if (t<s) red[t]=fmaxf(red[t],red[t+s]); __syncthreads(); }
  float mwf=red[0]; __syncthreads();
  // absx from 2048 partials
  float mxv=0.f;
  for (int i=t;i<2048;i+=256) mxv=fmaxf(mxv,WS_RAX(ws)[i]);
  red[t]=mxv; __syncthreads();
  for (int s=128;s;s>>=1){ if (t<s) red[t]=fmaxf(red[t],red[t+s]); __syncthreads(); }
  float mx=red[0]; __syncthreads();

  float s0  = fmaxf(mx/127.f, EPSQ);
  float sx1 = fmaxf((127.f*s0)/127.f, EPSQ);
  float sw1 = fmaxf(vw1/7.f, EPSQ);
  float sw2 = fmaxf(mw2/7.f, EPSQ);
  float swf = fmaxf(mwf/7.f, EPSQ);
  float sb1 = sx1*sw1;
  if (t==0){ F[0]=s0; F[1]=sx1; F[2]=sw1; F[3]=sb1; F[7]=sw2; F[12]=swf; }
  if (t<144) WS_M1F(ws)[t] = clampf(rintf(w1[t]/sw1), -7.f, 7.f);
  if (t<16){
    int bl = (int)rintf(b1[t]/sb1);
    WS_B1L(ws)[t] = bl;
    WS_B1F(ws)[t] = (float)bl;
  }
}

// full path: all fragment packing, one element/thread (282 blocks)
__global__ void k_pack(const float* __restrict__ w1, const float* __restrict__ w2,
                       const float* __restrict__ wf, char* ws){
  const float* F = WS_F(ws);
  int id = blockIdx.x*256 + threadIdx.x;
  if (id < 5120){
    // conv2 B-fragments: chunk c, lane l -> col oc=l&31, k=(l>>5)*16+j; tap=2c+(l>>5), ch=j
    float sw2 = F[7];
    int chunk=id>>10, r=id&1023, ln=r>>4, j=r&15;
    int tap=2*chunk+(ln>>5), oc=ln&31;
    signed char v=0;
    if (tap<9) v=(signed char)clampf(rintf(w2[oc*144 + j*9 + tap]/sw2), -7.f, 7.f);
    WS_B2FR(ws)[id]=v;
  } else if (id < 6144){
    // conv1 B-fragments (fallback)
    float sw1 = F[2];
    int i=id-5120;
    int ln=i>>4, j=i&15;
    int k=(ln>>5)*16+j, oc=ln&31;
    signed char v=0;
    if (k<9 && oc<16) v=(signed char)clampf(rintf(w1[oc*9+k]/sw1), -7.f, 7.f);
    WS_B1FR(ws)[i]=v;
  } else if (id < 56320){
    // fc B-fragments: chunk c, lane l: col oc=l&31, k=c*32+(l>>5)*16+j; f=ch*49+cell, k=cell*32+ch
    float swf = F[12];
    int i=id-6144;
    int chunk=i>>10, r2=i&1023, ln=r2>>4, j=r2&15;
    int oc=ln&31, k=chunk*32+(ln>>5)*16+j;
    int cell=k>>5, ch=k&31;
    signed char v=0;
    if (oc<10) v=(signed char)clampf(rintf(wf[oc*1568 + ch*49 + cell]/swf), -7.f, 7.f);
    ((signed char*)WS_WFP(ws))[i]=v;
  } else if (id < 72000){
    float swf = F[12];
    int i=id-56320;
    WS_MFF(ws)[i] = clampf(rintf(wf[i]/swf), -7.f, 7.f);
  }
}

// fallback: verified monolithic scale+pack kernel
__global__ void k_wq(const float* __restrict__ w1, const float* __restrict__ b1,
                     const float* __restrict__ w2, const float* __restrict__ wf,
                     char* ws){
  __shared__ float red[256];
  float* F = WS_F(ws);
  int t = threadIdx.x;
  auto bmaxabs = [&](const float* p, int n)->float{
    float m=0.f; for (int i=t;i<n;i+=256) m=fmaxf(m,fabsf(p[i]));
    red[t]=m; __syncthreads();
    for (int s=128;s;s>>=1){ if (t<s) red[t]=fmaxf(red[t],red[t+s]); __syncthreads(); }
    float r=red[0]; __syncthreads(); return r;
  };
  float mw1 = bmaxabs(w1,144);
  float mw2 = bmaxabs(w2,4608);
  float mwf = bmaxabs(wf,15680);
  float mxv=0.f;
  for (int i=t;i<2048;i+=256) mxv=fmaxf(mxv,WS_RAX(ws)[i]);
  red[t]=mxv; __syncthreads();
  for (int s=128;s;s>>=1){ if (t<s) red[t]=fmaxf(red[t],red[t+s]); __syncthreads(); }
  float mx=red[0]; __syncthreads();

  float s0  = fmaxf(mx/127.f, EPSQ);
  float sx1 = fmaxf((127.f*s0)/127.f, EPSQ);
  float sw1 = fmaxf(mw1/7.f, EPSQ);
  float sw2 = fmaxf(mw2/7.f, EPSQ);
  float swf = fmaxf(mwf/7.f, EPSQ);
  float sb1 = sx1*sw1;
  if (t==0){ F[0]=s0; F[1]=sx1; F[2]=sw1; F[3]=sb1; F[7]=sw2; F[12]=swf; }
  float* m1f = WS_M1F(ws);
  for (int i=t;i<144;i+=256) m1f[i] = clampf(rintf(w1[i]/sw1), -7.f, 7.f);
  if (t<16){
    int bl = (int)rintf(b1[t]/sb1);
    WS_B1L(ws)[t] = bl;
    WS_B1F(ws)[t] = (float)bl;
  }
  for (int i=t;i<5120;i+=256){
    int chunk=i>>10, r=i&1023, ln=r>>4, j=r&15;
    int tap=2*chunk+(ln>>5), oc=ln&31;
    signed char v=0;
    if (tap<9) v=(signed char)clampf(rintf(w2[oc*144 + j*9 + tap]/sw2), -7.f, 7.f);
    WS_B2FR(ws)[i]=v;
  }
  for (int i=t;i<1024;i+=256){
    int ln=i>>4, j=i&15;
    int k=(ln>>5)*16+j, oc=ln&31;
    signed char v=0;
    if (k<9 && oc<16) v=(signed char)clampf(rintf(w1[oc*9+k]/sw1), -7.f, 7.f);
    WS_B1FR(ws)[i]=v;
  }
  float* mff = WS_MFF(ws);
  for (int i=t;i<15680;i+=256) mff[i] = clampf(rintf(wf[i]/swf), -7.f, 7.f);
  for (int i=t;i<50176;i+=256){
    int chunk=i>>10, r2=i&1023, ln=r2>>4, j=r2&15;
    int oc=ln&31, k=chunk*32+(ln>>5)*16+j;
    int cell=k>>5, ch=k&31;
    signed char v=0;
    if (oc<10) v=(signed char)clampf(rintf(wf[oc*1568 + ch*49 + cell]/swf), -7.f, 7.f);
    ((signed char*)WS_WFP(ws))[i]=v;
  }
}

template<bool FULLR>
__global__ void k_s1(const float* __restrict__ b2, char* ws){
  float* F=WS_F(ws); int* I=WS_I(ws);
  __shared__ int rA[256], rS[256];
  __shared__ float sh[4];
  int t=threadIdx.x;
  int amaxI, smaxI;
  if constexpr (FULLR){
    int a=0, s=INT_MIN;
    const int* ra=WS_RA1(ws); const int* rs=WS_RS1(ws);
    for (int i=t;i<6272;i+=256){ a=max(a,ra[i]); s=max(s,rs[i]); }
    rA[t]=a; rS[t]=s; __syncthreads();
    for (int st=128;st;st>>=1){ if (t<st){ rA[t]=max(rA[t],rA[t+st]); rS[t]=max(rS[t],rS[t+st]); } __syncthreads(); }
    amaxI=rA[0]; smaxI=rS[0];
  } else { amaxI=I[1]; smaxI=I[2]; }
  if (t==0){
    float sb1=F[3];
    float sy1 = fmaxf((sb1*(float)amaxI)/127.f, EPSQ);
    float mp  = sb1*(float)smaxI;
    float P1  = clampf(rintf(mp/sy1), 0.f, 127.f);
    float sr1 = fmaxf((sy1*P1)/15.f, EPSQ);
    float N1  = clampf(rintf((sy1*P1)/sr1), 0.f, 15.f);
    float sx2 = fmaxf((N1*sr1)/127.f, EPSQ);
    float sb2 = sx2*F[7];
    F[4]=sy1; F[5]=sr1; F[6]=sx2; F[8]=sb2;
    sh[0]=sy1; sh[1]=sr1; sh[2]=sx2; sh[3]=sb2;
  }
  __syncthreads();
  float sy1=sh[0], sr1=sh[1], sx2=sh[2], sb2=sh[3];
  int k = t-128;
  float n = (k>0) ? clampf(rintf((sy1*(float)k)/sr1), 0.f, 15.f) : 0.f;
  WS_Q2TAB(ws)[t] = (signed char)clampf(rintf((n*sr1)/sx2), -128.f, 127.f);
  if (t<32) WS_B2L(ws)[t] = (int)rintf(b2[t]/sb2);
}

template<bool FULLR>
__global__ void k_s2(const float* __restrict__ bf, char* ws){
  float* F=WS_F(ws); int* I=WS_I(ws);
  __shared__ int rA[256], rS[256];
  __shared__ float sh[4];
  int t=threadIdx.x;
  int amaxI, smaxI;
  if constexpr (FULLR){
    int a=0, s=INT_MIN;
    const int* ra=WS_RA2(ws); const int* rs=WS_RS2(ws);
    for (int i=t;i<2048;i+=256){ a=max(a,ra[i]); s=max(s,rs[i]); }
    rA[t]=a; rS[t]=s; __syncthreads();
    for (int st=128;st;st>>=1){ if (t<st){ rA[t]=max(rA[t],rA[t+st]); rS[t]=max(rS[t],rS[t+st]); } __syncthreads(); }
    amaxI=rA[0]; smaxI=rS[0];
  } else { amaxI=I[3]; smaxI=I[4]; }
  if (t==0){
    float sb2=F[8];
    float sy2 = fmaxf((sb2*(float)amaxI)/127.f, EPSQ);
    float mp  = sb2*(float)smaxI;
    float P2  = clampf(rintf(mp/sy2), 0.f, 127.f);
    float sr2 = fmaxf((sy2*P2)/15.f, EPSQ);
    float N2  = clampf(rintf((sy2*P2)/sr2), 0.f, 15.f);
    float sx3 = fmaxf((N2*sr2)/127.f, EPSQ);
    float sb3 = sx3*F[12];
    F[9]=sy2; F[10]=sr2; F[11]=sx3; F[13]=sb3;
    sh[0]=sy2; sh[1]=sr2; sh[2]=sx3; sh[3]=sb3;
  }
  __syncthreads();
  float sy2=sh[0], sr2=sh[1], sx3=sh[2], sb3=sh[3];
  int k = t-128;
  float n = (k>0) ? clampf(rintf((sy2*(float)k)/sr2), 0.f, 15.f) : 0.f;
  WS_Q3TAB(ws)[t] = (signed char)clampf(rintf((n*sr2)/sx3), -128.f, 127.f);
  if (t<16) WS_BFL(ws)[t] = (t<10) ? (int)rintf(bf[t]/sb3) : 0;
}

template<bool FULLR>
__global__ void k_s3(char* ws){
  float* F=WS_F(ws); int* I=WS_I(ws);
  __shared__ int rA[256];
  int t=threadIdx.x;
  int amaxI;
  if constexpr (FULLR){
    rA[t] = WS_RA3(ws)[t];
    __syncthreads();
    for (int st=128;st;st>>=1){ if (t<st) rA[t]=max(rA[t],rA[t+st]); __syncthreads(); }
    amaxI = rA[0];
  } else { amaxI = I[5]; }
  if (t==0) F[14] = fmaxf((F[13]*(float)amaxI)/127.f, EPSQ);
}

// ================= FULL PATH compute =================
__global__ void k_qx(const float* __restrict__ x, const char* __restrict__ ws,
                     signed char* __restrict__ qx){
  const float s0 = ((const float*)ws)[0];
  int id = blockIdx.x*256 + threadIdx.x;          // < NB*240
  int img = id/240, w = id - img*240;
  int r = w>>3, c4 = (w&7)<<2;
  const float* xi = x + img*784;
  unsigned out = 0;
#pragma unroll
  for (int j=0;j<4;j++){
    int c = c4+j;
    bool valid = (r>=1) && (r<=28) && (c>=1) && (c<=28);
    int q = 0;
    if (valid){
      float xv = xi[(r-1)*28 + (c-1)];
      q = (int)clampf(rintf(xv/s0), -128.f, 127.f);
    }
    out |= ((unsigned)(unsigned char)(signed char)q) << (8*j);
  }
  ((unsigned*)qx)[id] = out;
}

__global__ __launch_bounds__(256) void k_conv1(const signed char* __restrict__ qx,
                                               char* __restrict__ ws,
                                               short* __restrict__ i1p){
  const int t = threadIdx.x;
  const int id = blockIdx.x*256 + t;
  const int img = id/196, cell = id - img*196;
  const int py = cell/14, px = cell - py*14;
  const signed char* qb = qx + img*960 + (2*py)*32;
  const int pc0 = 2*px;
  const int al = pc0 & ~3, sh = (pc0&3)*8;
  float in[4][4];
#pragma unroll
  for (int rr=0; rr<4; rr++){
    unsigned lo = *(const unsigned*)(qb + rr*32 + al);
    unsigned hi = *(const unsigned*)(qb + rr*32 + al + 4);
    unsigned wrd = (unsigned)(((((unsigned long long)hi)<<32)|lo) >> sh);
#pragma unroll
    for (int cc=0; cc<4; cc++)
      in[rr][cc] = (float)(signed char)((wrd >> (8*cc)) & 0xFFu);
  }
  const float* __restrict__ m1f = WS_M1F(ws);   // uniform -> s_load
  const float* __restrict__ b1f = WS_B1F(ws);
  int amax=0, smax=INT_MIN;
  short outv[16];
#pragma unroll
  for (int oc=0; oc<16; oc++){
    float b = b1f[oc];
    float a00=b, a01=b, a10=b, a11=b;
#pragma unroll
    for (int dy=0; dy<3; dy++){
#pragma unroll
      for (int dx=0; dx<3; dx++){
        float wt = m1f[oc*9+dy*3+dx];
        a00 = fmaf(in[dy  ][dx  ], wt, a00);
        a01 = fmaf(in[dy  ][dx+1], wt, a01);
        a10 = fmaf(in[dy+1][dx  ], wt, a10);
        a11 = fmaf(in[dy+1][dx+1], wt, a11);
      }
    }
    int v00=(int)a00, v01=(int)a01, v10=(int)a10, v11=(int)a11;
    int mx = max(max(v00,v01), max(v10,v11));
    int ax = max(max(v00<0?-v00:v00, v01<0?-v01:v01), max(v10<0?-v10:v10, v11<0?-v11:v11));
    amax = max(amax, ax);
    smax = max(smax, mx);
    outv[oc] = (short)mx;
  }
  int4* dst = (int4*)(i1p + (size_t)id*16);
  dst[0] = *(const int4*)&outv[0];
  dst[1] = *(const int4*)&outv[8];
  reduce2_store(amax, smax, &WS_RA1(ws)[blockIdx.x], &WS_RS1(ws)[blockIdx.x]);
}

__global__ __launch_bounds__(256) void k_conv2r(char* __restrict__ ws,
                                                short* __restrict__ i1p,
                                                int* __restrict__ p2g){
  constexpr int WSLICE = 4096 + 6272;
  __shared__ __align__(16) char arena[4*WSLICE];
  const int t=threadIdx.x, lane=t&63, wid=t>>6;
  const int img = blockIdx.x*4 + wid;
  char* wbase = arena + wid*WSLICE;
  signed char* q2p = (signed char*)wbase;            // [16][16][16ch] padded
  int* poolw = (int*)(wbase + 4096);                 // [49][32]
  const float* F = WS_F(ws);
  const float sb1=F[3], sy1=F[4];
  const signed char* q2t = WS_Q2TAB(ws);

#pragma unroll
  for (int k=0;k<8;k++) ((unsigned long long*)q2p)[lane + 64*k] = 0ULL;
#pragma unroll
  for (int k=0;k<24;k++) poolw[lane + 64*k] = INT_MIN;
  if (lane<32) poolw[1536+lane] = INT_MIN;

  const unsigned* src = (const unsigned*)(i1p + (size_t)img*3136);
  for (int k=0;k<25;k++){
    int idx = lane + 64*k;
    if (idx >= 1568) break;
    unsigned wv = src[idx];
    int e0 = idx*2;
    int cellc = e0 >> 4, ch = e0 & 15;
    int pyc = cellc/14, pxc = cellc - pyc*14;
    int m0 = (int)(short)(wv & 0xFFFFu);
    int m1 = (int)(short)(wv >> 16);
    float k10 = clampf(rintf((sb1*(float)m0)/sy1), -128.f, 127.f);
    float k11 = clampf(rintf((sb1*(float)m1)/sy1), -128.f, 127.f);
    int b0 = (int)(unsigned char)q2t[(int)k10+128];
    int b1 = (int)(unsigned char)q2t[(int)k11+128];
    *(unsigned short*)(q2p + ((pyc+1)*16 + (pxc+1))*16 + ch) = (unsigned short)(b0 | (b1<<8));
  }

  i32x4 bfr[5];
  const i32x4* bg = (const i32x4*)WS_B2FR(ws);
#pragma unroll
  for (int c=0;c<5;c++) bfr[c] = bg[c*64+lane];
  const int col = lane&31, h = lane>>5;
  const int bias = WS_B2L(ws)[col];
  int amax2=0, smax2=INT_MIN;
  const int TOFF[9] = {0,1,2,16,17,18,32,33,34};

#pragma unroll
  for (int mt=0; mt<7; mt++){
    int p = mt*32 + col;
    bool pv = p < 196;
    int oy = p/14, ox = p - oy*14;
    int E0 = oy*16 + ox;
    i32x16 acc;
#pragma unroll
    for (int r=0;r<16;r++) acc[r] = bias;
#pragma unroll
    for (int c=0;c<5;c++){
      int toff = h ? ((2*c+1<9)? TOFF[2*c+1] : -1) : TOFF[2*c];
      bool ok = pv && (toff>=0);
      int entry = ok ? (E0 + toff) : 0;
      i32x4 a = *(const i32x4*)(q2p + entry*16);
      acc = __builtin_amdgcn_mfma_i32_32x32x32_i8(a, bfr[c], acc, 0,0,0);
    }
#pragma unroll
    for (int r=0;r<16;r++){
      int row = (r&3) + 8*(r>>2) + 4*h;
      int pp = mt*32 + row;
      if (pp < 196){
        int v = acc[r];
        amax2 = max(amax2, v<0?-v:v);
        smax2 = max(smax2, v);
        int qy = pp/14, qx2 = pp - qy*14;
        int cc = (qy>>1)*7 + (qx2>>1);
        atomicMax(&poolw[cc*32 + col], v);
      }
    }
  }
  reduce2_store(amax2, smax2, &WS_RA2(ws)[blockIdx.x], &WS_RS2(ws)[blockIdx.x]);
  int* dst = p2g + (size_t)img*1568;
#pragma unroll
  for (int k=0;k<24;k++){ int idx = lane+64*k; dst[idx] = poolw[idx]; }
  if (lane<32) dst[1536+lane] = poolw[1536+lane];
}

__global__ void k_rq2(const char* __restrict__ ws, const int* __restrict__ p2g,
                      signed char* __restrict__ q3g){
  const float* F = (const float*)ws;
  const float sb2 = F[8], sy2 = F[9];
  const signed char* q3t = WS_Q3TAB(ws);
  int id = blockIdx.x*256 + threadIdx.x;
  i32x4 m4 = ((const i32x4*)p2g)[id];
  unsigned out=0;
#pragma unroll
  for (int j=0;j<4;j++){
    float k2 = clampf(rintf((sb2*(float)m4[j])/sy2), -128.f, 127.f);
    out |= ((unsigned)(unsigned char)q3t[(int)k2+128]) << (8*j);
  }
  ((unsigned*)q3g)[id] = out;
}

__global__ __launch_bounds__(256) void k_fc(char* __restrict__ ws,
                                            const signed char* __restrict__ q3g,
                                            int* __restrict__ i3out){
  __shared__ int part[3][16][64];
  int t=threadIdx.x, lane=t&63, wid=t>>6;
  int mt = blockIdx.x;              // 0..255
  const int col=lane&31, h=lane>>5;
  const signed char* A0 = q3g + (size_t)(mt*32 + col)*1568 + 16*h;
  const i32x4* wfp = (const i32x4*)WS_WFP(ws);
  i32x16 acc;
#pragma unroll
  for (int r=0;r<16;r++) acc[r]=0;
  for (int c=wid; c<49; c+=4){
    i32x4 a = *(const i32x4*)(A0 + c*32);
    i32x4 b = wfp[c*64 + lane];
    acc = __builtin_amdgcn_mfma_i32_32x32x32_i8(a, b, acc, 0,0,0);
  }
  if (wid>0){
#pragma unroll
    for (int r=0;r<16;r++) part[wid-1][r][lane] = acc[r];
  }
  __syncthreads();
  if (wid==0){
    int bias = (col<10) ? WS_BFL(ws)[col] : 0;
    int am=0;
#pragma unroll
    for (int r=0;r<16;r++){
      int v = acc[r] + part[0][r][lane] + part[1][r][lane] + part[2][r][lane] + bias;
      int row=(r&3)+8*(r>>2)+4*h;
      int img = mt*32+row;
      if (col<10){
        i3out[img*10+col] = v;
        am = max(am, v<0?-v:v);
      }
    }
    am = wave_max_i(am);
    if (lane==0) WS_RA3(ws)[blockIdx.x] = am;
  }
}

// ================= FALLBACK (verified) =================
__global__ __launch_bounds__(256) void k_c1(const float* __restrict__ x, char* __restrict__ ws,
                                            short* __restrict__ i1p){
  constexpr int OFF_K0=0, OFF_A=960, OFF_I1=13760, OFF_B1=38848;
  __shared__ __align__(16) char arena[38912];
  signed char* k0b = (signed char*)(arena+OFF_K0);
  signed char* Abuf= (signed char*)(arena+OFF_A);
  short*       I1s = (short*)(arena+OFF_I1);
  int*         b1i = (int*)(arena+OFF_B1);

  const int tid=threadIdx.x, img=blockIdx.x;
  const int lane=tid&63, wid=tid>>6;
  const float s0 = WS_F(ws)[0];

  if (tid<16) b1i[tid]=WS_B1L(ws)[tid];
  for (int i=tid;i<240;i+=256) ((int*)k0b)[i]=0;
  for (int i=tid;i<3200;i+=256) ((int*)Abuf)[i]=0;
  __syncthreads();
  const float* xi = x + img*784;
  for (int i=tid;i<784;i+=256){
    int r=i/28, c=i-r*28;
    float v = clampf(rintf(xi[i]/s0), -128.f, 127.f);
    k0b[(r+1)*32 + (c+1)] = (signed char)v;
  }
  __syncthreads();
  for (int p=tid;p<784;p+=256){
    int oy=p/28, ox=p-oy*28;
    int base = oy*32+ox;
    int al = base & ~3, sh = (base&3)*8;
    unsigned l0a=*(const unsigned*)(k0b+al),    l1a=*(const unsigned*)(k0b+al+4);
    unsigned l0b=*(const unsigned*)(k0b+al+32), l1b=*(const unsigned*)(k0b+al+36);
    unsigned l0c=*(const unsigned*)(k0b+al+64), l1c=*(const unsigned*)(k0b+al+68);
    unsigned u0=(unsigned)(((((unsigned long long)l1a)<<32)|l0a)>>sh);
    unsigned u1=(unsigned)(((((unsigned long long)l1b)<<32)|l0b)>>sh);
    unsigned u2=(unsigned)(((((unsigned long long)l1c)<<32)|l0c)>>sh);
    i32x4 row;
    row[0]=(int)((u0&0xFFFFFFu)|(u1<<24));
    row[1]=(int)(((u1>>8)&0xFFFFu)|((u2&0xFFFFu)<<16));
    row[2]=(int)((u2>>16)&0xFFu);
    row[3]=0;
    *(i32x4*)(Abuf + p*16) = row;
  }
  __syncthreads();
  const i32x4 bfr = ((const i32x4*)WS_B1FR(ws))[lane];
  const int col=lane&31, h=lane>>5;
  const int bias=(col<16)? b1i[col] : 0;
  int amax=0, smax=INT_MIN;
  for (int mt=wid; mt<25; mt+=4){
    i32x4 a={0,0,0,0};
    if (h==0) a = *(const i32x4*)(Abuf + (mt*32+col)*16);
    i32x16 acc;
#pragma unroll
    for (int r=0;r<16;r++) acc[r]=bias;
    acc=__builtin_amdgcn_mfma_i32_32x32x32_i8(a,bfr,acc,0,0,0);
#pragma unroll
    for (int r=0;r<16;r++){
      int row=(r&3)+8*(r>>2)+4*h;
      int p=mt*32+row;
      if (p<784 && col<16){
        int v=acc[r];
        amax=max(amax,v<0?-v:v); smax=max(smax,v);
        I1s[p*16+col]=(short)v;
      }
    }
  }
  __syncthreads();
  for (int i=tid;i<3136;i+=256){
    int pp=i>>4, c=i&15, py=pp/14, px=pp-py*14;
    int p0=py*56+px*2;
    int m=max(max((int)I1s[p0*16+c],(int)I1s[(p0+1)*16+c]),
              max((int)I1s[(p0+28)*16+c],(int)I1s[(p0+29)*16+c]));
    i1p[(size_t)img*3136 + i]=(short)m;
  }
  reduce2_atomic(amax,smax,&WS_I(ws)[1],&WS_I(ws)[2]);
}

template<bool FIN>
__global__ __launch_bounds__(256) void k_c2(char* __restrict__ ws, const short* __restrict__ i1p,
                                            int* __restrict__ i3out){
  constexpr int OFF_Q2L=0, OFF_B2I=3136, OFF_Q2T=3264, OFF_N2=3520,
                OFF_Q3T=9792, OFF_BFS=10048, OFF_Q3F=10112, OFF_RED=16384;
  constexpr int ARENA = FIN ? 16544 : 3520;
  __shared__ __align__(16) char arena[ARENA];
  signed char* q2l=(signed char*)(arena+OFF_Q2L);
  int* b2li=(int*)(arena+OFF_B2I);
  signed char* q2t=(signed char*)(arena+OFF_Q2T);

  const int tid=threadIdx.x, img=blockIdx.x;
  const int lane=tid&63, wid=tid>>6;
  const float* F=WS_F(ws);
  const float sb1=F[3], sy1=F[4];

  q2t[tid]=WS_Q2TAB(ws)[tid];
  if (tid<32) b2li[tid]=WS_B2L(ws)[tid];
  if constexpr (FIN){
    ((signed char*)(arena+OFF_Q3T))[tid]=WS_Q3TAB(ws)[tid];
    if (tid<16) ((int*)(arena+OFF_BFS))[tid]=WS_BFL(ws)[tid];
  }
  __syncthreads();
  for (int i=tid;i<3136;i+=256){
    int m=(int)i1p[(size_t)img*3136+i];
    float k1=clampf(rintf((sb1*(float)m)/sy1),-128.f,127.f);
    q2l[i]=q2t[(int)k1+128];
  }
  __syncthreads();

  i32x4 bfr[5];
  {
    const i32x4* bg=(const i32x4*)WS_B2FR(ws);
#pragma unroll
    for (int c=0;c<5;c++) bfr[c]=bg[c*64+lane];
  }
  const int col=lane&31, h=lane>>5;
  const int bias=b2li[col];
  int amax2=0, smax2=INT_MIN;
  float sb2=0.f, sy2=0.f;
  signed char* n2buf=nullptr;
  if constexpr (FIN){ sb2=F[8]; sy2=F[9]; n2buf=(signed char*)(arena+OFF_N2); }

  for (int mt=wid; mt<7; mt+=4){
    const int p=mt*32+col;
    const bool pv=p<196;
    const int oy=p/14, ox=p-oy*14;
    i32x16 acc;
#pragma unroll
    for (int r=0;r<16;r++) acc[r]=bias;
#pragma unroll
    for (int c=0;c<5;c++){
      const int tap=2*c+h;
      i32x4 a={0,0,0,0};
      if (pv && tap<9){
        const int iy=oy+tap/3-1, ix=ox+tap-(tap/3)*3-1;
        if ((unsigned)iy<14u && (unsigned)ix<14u) a=*(const i32x4*)(q2l+(iy*14+ix)*16);
      }
      acc=__builtin_amdgcn_mfma_i32_32x32x32_i8(a,bfr[c],acc,0,0,0);
    }
#pragma unroll
    for (int r=0;r<16;r++){
      const int row=(r&3)+8*(r>>2)+4*h;
      const int pp=mt*32+row;
      if (pp<196){
        const int v=acc[r];
        if constexpr (!FIN){ amax2=max(amax2,v<0?-v:v); smax2=max(smax2,v); }
        else {
          n2buf[col*196+pp]=(signed char)clampf(rintf((sb2*(float)v)/sy2),-128.f,127.f);
        }
      }
    }
  }
  if constexpr (!FIN){
    reduce2_atomic(amax2,smax2,&WS_I(ws)[3],&WS_I(ws)[4]);
    return;
  } else {
    __syncthreads();
    signed char* q3t_s=(signed char*)(arena+OFF_Q3T);
    float* q3f=(float*)(arena+OFF_Q3F);
    for (int i=tid;i<1568;i+=256){
      int cch=i/49, s=i-cch*49, qy=s/7, qx=s-qy*7;
      int b=cch*196+qy*28+qx*2;
      int m=max(max((int)n2buf[b],(int)n2buf[b+1]),max((int)n2buf[b+14],(int)n2buf[b+15]));
      q3f[i]=(float)q3t_s[m+128];
    }
    __syncthreads();
    const float* mff=WS_MFF(ws);
    float a10[10];
#pragma unroll
    for (int o=0;o<10;o++) a10[o]=0.f;
    for (int k=tid;k<1568;k+=256){
      float qa=q3f[k];
#pragma unroll
      for (int o=0;o<10;o++) a10[o]=fmaf(qa,mff[o*1568+k],a10[o]);
    }
#pragma unroll
    for (int o=0;o<10;o++){
#pragma unroll
      for (int off=32;off;off>>=1) a10[o]+=__shfl_down(a10[o],off,64);
    }
    float* redf=(float*)(arena+OFF_RED);
    int* bfs=(int*)(arena+OFF_BFS);
    if (lane==0){
#pragma unroll
      for (int o=0;o<10;o++) redf[wid*10+o]=a10[o];
    }
    __syncthreads();
    if (tid<10){
      float s=redf[tid]+redf[10+tid]+redf[20+tid]+redf[30+tid];
      int I3v=(int)s+bfs[tid];
      i3out[img*10+tid]=I3v;
      redf[tid]=(float)(I3v<0?-I3v:I3v);
    }
    __syncthreads();
    if (tid==0){
      int m=0;
#pragma unroll
      for (int o=0;o<10;o++) m=max(m,(int)redf[o]);
      atomicMax(&WS_I(ws)[5],m);
    }
  }
}

__global__ void k_out(char* ws, float* __restrict__ out){
  float* F=WS_F(ws);
  float sb3=F[13], sy3=F[14];
  int i = blockIdx.x*blockDim.x + threadIdx.x;
  if (i < NB*10){
    int iv = ((const int*)out)[i];
    float y = sb3*(float)iv;
    float q = clampf(rintf(y/sy3), -128.f, 127.f);
    out[i] = q*sy3;
  }
}

extern "C" void kernel_launch(void* const* d_in, const int* in_sizes, int n_in,
                              void* d_out, int out_size, void* d_ws, size_t ws_size,
                              hipStream_t stream){
  const float* x  = (const float*)d_in[0];
  const float* w1 = (const float*)d_in[1];
  const float* b1 = (const float*)d_in[2];
  const float* w2 = (const float*)d_in[3];
  const float* b2 = (const float*)d_in[4];
  const float* wf = (const float*)d_in[5];
  const float* bf = (const float*)d_in[6];
  char* ws = (char*)d_ws;
  float* out = (float*)d_out;
  int* i3 = (int*)d_out;

  const size_t QX_SZ  = (size_t)NB*960;
  const size_t I1_SZ  = (size_t)NB*6272;
  const size_t Q3_SZ  = (size_t)NB*1568;
  const size_t needFull = (size_t)WS_BIG_OFF + QX_SZ + I1_SZ + Q3_SZ;

  if (ws_size >= needFull){
    signed char* qx  = (signed char*)(ws + WS_BIG_OFF);
    short*       i1p = (short*)(ws + WS_BIG_OFF + QX_SZ);
    int*         p2g = (int*)i1p;
    signed char* q3g = (signed char*)(ws + WS_BIG_OFF + QX_SZ + I1_SZ);
    k_absx  <<<dim3(2048), dim3(256), 0, stream>>>(x, ws);
    k_wmax  <<<dim3(81), dim3(256), 0, stream>>>(w1, w2, wf, ws);
    k_scales<<<dim3(1), dim3(256), 0, stream>>>(w1, b1, ws);
    k_qx    <<<dim3(NB*240/256), dim3(256), 0, stream>>>(x, ws, qx);
    k_pack  <<<dim3(282), dim3(256), 0, stream>>>(w1, w2, wf, ws);
    k_conv1 <<<dim3(NB*196/256), dim3(256), 0, stream>>>(qx, ws, i1p);
    k_s1<true><<<dim3(1), dim3(256), 0, stream>>>(b2, ws);
    k_conv2r<<<dim3(NB/4), dim3(256), 0, stream>>>(ws, i1p, p2g);
    k_s2<true><<<dim3(1), dim3(256), 0, stream>>>(bf, ws);
    k_rq2   <<<dim3(NB*1568/1024), dim3(256), 0, stream>>>(ws, p2g, q3g);
    k_fc    <<<dim3(256), dim3(256), 0, stream>>>(ws, q3g, i3);
    k_s3<true><<<dim3(1), dim3(256), 0, stream>>>(ws);
  } else {
    short* i1p = (short*)(ws + WS_BIG_OFF);
    k_init<<<dim3(1), dim3(64), 0, stream>>>(ws);
    k_absx<<<dim3(2048), dim3(256), 0, stream>>>(x, ws);
    k_wq  <<<dim3(1), dim3(256), 0, stream>>>(w1, b1, w2, wf, ws);
    k_c1<<<dim3(NB), dim3(256), 0, stream>>>(x, ws, i1p);
    k_s1<false><<<dim3(1), dim3(256), 0, stream>>>(b2, ws);
    k_c2<false><<<dim3(NB), dim3(256), 0, stream>>>(ws, i1p, i3);
    k_s2<false><<<dim3(1), dim3(256), 0, stream>>>(bf, ws);
    k_c2<true ><<<dim3(NB), dim3(256), 0, stream>>>(ws, i1p, i3);
    k_s3<false><<<dim3(1), dim3(256), 0, stream>>>(ws);
  }
  k_out<<<dim3((NB*10+255)/256), dim3(256), 0, stream>>>(ws, out);
}

// Round 8
// 137.795 us; speedup vs baseline: 10.4852x; 1.0788x over previous
//
#include <hip/hip_runtime.h>
#include <climits>

#define NB 8192
#define EPSQ 1e-8f

using i32x4  = __attribute__((ext_vector_type(4)))  int;
using i32x16 = __attribute__((ext_vector_type(16))) int;

// ---- ws layout (byte offsets) ----
// scalars F: 0 s0,1 sx1,2 sw1,3 sb1,4 sy1,5 sr1,6 sx2,7 sw2,8 sb2,9 sy2,10 sr2,11 sx3,12 swf,13 sb3,14 sy3
#define WS_F(ws)     ((float*)(ws))
#define WS_I(ws)     ((int*)((char*)(ws)+128))      // fallback atomics
#define WS_B1L(ws)   ((int*)((char*)(ws)+384))      // [16]
#define WS_B2L(ws)   ((int*)((char*)(ws)+448))      // [32]
#define WS_BFL(ws)   ((int*)((char*)(ws)+576))      // [16]
#define WS_M1F(ws)   ((float*)((char*)(ws)+640))    // [144]
#define WS_B1F(ws)   ((float*)((char*)(ws)+1280))   // [16] float bias levels (conv1)
#define WS_B2FR(ws)  ((char*)(ws)+2048)             // [5][64][16] conv2 i8 B-fragments
#define WS_Q2TAB(ws) ((signed char*)((char*)(ws)+7168))  // [256]
#define WS_Q3TAB(ws) ((signed char*)((char*)(ws)+7424))  // [256]
#define WS_B1FR(ws)  ((char*)(ws)+7680)             // [64][16] conv1 i8 B-fragments (fallback)
#define WS_MFF(ws)   ((float*)((char*)(ws)+20480))  // [10][1568] float fc levels (fallback)
#define WS_WFP(ws)   ((char*)(ws)+83200)            // [49][64][16] fc i8 B-fragments
// per-block reduction slots (no atomics in full path)
#define WS_RA1(ws)   ((int*)((char*)(ws)+139264))   // [6272] conv1 amax
#define WS_RS1(ws)   ((int*)((char*)(ws)+164352))   // [6272] conv1 smax
#define WS_RA2(ws)   ((int*)((char*)(ws)+189440))   // [2048] conv2 amax
#define WS_RS2(ws)   ((int*)((char*)(ws)+197632))   // [2048] conv2 smax
#define WS_RA3(ws)   ((int*)((char*)(ws)+205824))   // [256]  fc amax
#define WS_RAX(ws)   ((float*)((char*)(ws)+206848)) // [2048] absx per-block max
#define WS_WMX(ws)   ((float*)((char*)(ws)+215040)) // [81] weight maxabs partials
#define WS_BIG_OFF   217088

__device__ __forceinline__ float clampf(float v, float lo, float hi){ return fminf(fmaxf(v, lo), hi); }

__device__ __forceinline__ float wave_max_f(float v){
#pragma unroll
  for (int off=32; off; off>>=1) v = fmaxf(v, __shfl_down(v, off, 64));
  return v;
}
__device__ __forceinline__ int wave_max_i(int v){
#pragma unroll
  for (int off=32; off; off>>=1) v = max(v, __shfl_down(v, off, 64));
  return v;
}

__device__ __forceinline__ void reduce2_atomic(int amax, int smax, int* gA, int* gS){
  amax = wave_max_i(amax); smax = wave_max_i(smax);
  __shared__ int sA[4], sS[4];
  int w = threadIdx.x>>6, l = threadIdx.x&63;
  if (l==0){ sA[w]=amax; sS[w]=smax; }
  __syncthreads();
  if (threadIdx.x==0){
#pragma unroll
    for (int i=1;i<4;i++){ amax=max(amax,sA[i]); smax=max(smax,sS[i]); }
    atomicMax(gA, amax); atomicMax(gS, smax);
  }
}

__device__ __forceinline__ void reduce2_store(int amax, int smax, int* pA, int* pS){
  amax = wave_max_i(amax); smax = wave_max_i(smax);
  __shared__ int sA[4], sS[4];
  int w = threadIdx.x>>6, l = threadIdx.x&63;
  if (l==0){ sA[w]=amax; sS[w]=smax; }
  __syncthreads();
  if (threadIdx.x==0){
#pragma unroll
    for (int i=1;i<4;i++){ amax=max(amax,sA[i]); smax=max(smax,sS[i]); }
    *pA = amax; *pS = smax;
  }
}

__global__ void k_init(char* ws){
  int* I = WS_I(ws);
  if (threadIdx.x==0){ I[0]=0; I[1]=0; I[2]=INT_MIN; I[3]=0; I[4]=INT_MIN; I[5]=0; }
}

__global__ void k_absx(const float* __restrict__ x, char* ws){
  const float4* x4 = (const float4*)x;
  const int n4 = NB*784/4;
  float m = 0.f;
  for (int i = blockIdx.x*blockDim.x + threadIdx.x; i < n4; i += gridDim.x*blockDim.x){
    float4 v = x4[i];
    m = fmaxf(m, fmaxf(fmaxf(fabsf(v.x),fabsf(v.y)), fmaxf(fabsf(v.z),fabsf(v.w))));
  }
  m = wave_max_f(m);
  __shared__ float sm[4];
  int w = threadIdx.x>>6;
  if ((threadIdx.x&63)==0) sm[w]=m;
  __syncthreads();
  if (threadIdx.x==0){
    m = fmaxf(fmaxf(sm[0],sm[1]), fmaxf(sm[2],sm[3]));
    WS_RAX(ws)[blockIdx.x] = m;
  }
}

// full path: per-chunk weight maxabs partials. blocks: 0 -> w1(144); 1..18 -> w2; 19..80 -> wf
__global__ void k_wmax(const float* __restrict__ w1, const float* __restrict__ w2,
                       const float* __restrict__ wf, char* ws){
  __shared__ float red[256];
  int b = blockIdx.x, t = threadIdx.x;
  float m = 0.f;
  if (b==0){ if (t<144) m = fabsf(w1[t]); }
  else if (b<19){ m = fabsf(w2[(b-1)*256 + t]); }
  else { int i=(b-19)*256+t; if (i<15680) m = fabsf(wf[i]); }
  red[t]=m; __syncthreads();
  for (int s=128;s;s>>=1){ if (t<s) red[t]=fmaxf(red[t],red[t+s]); __syncthreads(); }
  if (t==0) WS_WMX(ws)[b]=red[0];
}

// full path: reduce partials -> all scale scalars + conv1 weight/bias levels
__global__ void k_scales(const float* __restrict__ w1, const float* __restrict__ b1, char* ws){
  __shared__ float red[256];
  float* F = WS_F(ws);
  int t = threadIdx.x;
  float vw1 = WS_WMX(ws)[0];
  float m2=0.f, mf=0.f;
  if (t<18) m2 = WS_WMX(ws)[1+t];
  if (t<62) mf = WS_WMX(ws)[19+t];
  red[t]=m2; __syncthreads();
  for (int s=128;s;s>>=1){ if (t<s) red[t]=fmaxf(red[t],red[t+s]); __syncthreads(); }
  float mw2=red[0]; __syncthreads();
  red[t]=mf; __syncthreads();
  for (int s=128;s;s>>=1){ if (t<s) red[t]=fmaxf(red[t],red[t+s]); __syncthreads(); }
  float mwf=red[0]; __syncthreads();
  float mxv=0.f;
  for (int i=t;i<2048;i+=256) mxv=fmaxf(mxv,WS_RAX(ws)[i]);
  red[t]=mxv; __syncthreads();
  for (int s=128;s;s>>=1){ if (t<s) red[t]=fmaxf(red[t],red[t+s]); __syncthreads(); }
  float mx=red[0]; __syncthreads();

  float s0  = fmaxf(mx/127.f, EPSQ);
  float sx1 = fmaxf((127.f*s0)/127.f, EPSQ);
  float sw1 = fmaxf(vw1/7.f, EPSQ);
  float sw2 = fmaxf(mw2/7.f, EPSQ);
  float swf = fmaxf(mwf/7.f, EPSQ);
  float sb1 = sx1*sw1;
  if (t==0){ F[0]=s0; F[1]=sx1; F[2]=sw1; F[3]=sb1; F[7]=sw2; F[12]=swf; }
  if (t<144) WS_M1F(ws)[t] = clampf(rintf(w1[t]/sw1), -7.f, 7.f);
  if (t<16){
    int bl = (int)rintf(b1[t]/sb1);
    WS_B1L(ws)[t] = bl;
    WS_B1F(ws)[t] = (float)bl;
  }
}

// full path: all fragment packing, one element/thread (282 blocks)
__global__ void k_pack(const float* __restrict__ w1, const float* __restrict__ w2,
                       const float* __restrict__ wf, char* ws){
  const float* F = WS_F(ws);
  int id = blockIdx.x*256 + threadIdx.x;
  if (id < 5120){
    float sw2 = F[7];
    int chunk=id>>10, r=id&1023, ln=r>>4, j=r&15;
    int tap=2*chunk+(ln>>5), oc=ln&31;
    signed char v=0;
    if (tap<9) v=(signed char)clampf(rintf(w2[oc*144 + j*9 + tap]/sw2), -7.f, 7.f);
    WS_B2FR(ws)[id]=v;
  } else if (id < 6144){
    float sw1 = F[2];
    int i=id-5120;
    int ln=i>>4, j=i&15;
    int k=(ln>>5)*16+j, oc=ln&31;
    signed char v=0;
    if (k<9 && oc<16) v=(signed char)clampf(rintf(w1[oc*9+k]/sw1), -7.f, 7.f);
    WS_B1FR(ws)[i]=v;
  } else if (id < 56320){
    float swf = F[12];
    int i=id-6144;
    int chunk=i>>10, r2=i&1023, ln=r2>>4, j=r2&15;
    int oc=ln&31, k=chunk*32+(ln>>5)*16+j;
    int cell=k>>5, ch=k&31;
    signed char v=0;
    if (oc<10) v=(signed char)clampf(rintf(wf[oc*1568 + ch*49 + cell]/swf), -7.f, 7.f);
    ((signed char*)WS_WFP(ws))[i]=v;
  } else if (id < 72000){
    float swf = F[12];
    int i=id-56320;
    WS_MFF(ws)[i] = clampf(rintf(wf[i]/swf), -7.f, 7.f);
  }
}

// fallback: verified monolithic scale+pack kernel
__global__ void k_wq(const float* __restrict__ w1, const float* __restrict__ b1,
                     const float* __restrict__ w2, const float* __restrict__ wf,
                     char* ws){
  __shared__ float red[256];
  float* F = WS_F(ws);
  int t = threadIdx.x;
  auto bmaxabs = [&](const float* p, int n)->float{
    float m=0.f; for (int i=t;i<n;i+=256) m=fmaxf(m,fabsf(p[i]));
    red[t]=m; __syncthreads();
    for (int s=128;s;s>>=1){ if (t<s) red[t]=fmaxf(red[t],red[t+s]); __syncthreads(); }
    float r=red[0]; __syncthreads(); return r;
  };
  float mw1 = bmaxabs(w1,144);
  float mw2 = bmaxabs(w2,4608);
  float mwf = bmaxabs(wf,15680);
  float mxv=0.f;
  for (int i=t;i<2048;i+=256) mxv=fmaxf(mxv,WS_RAX(ws)[i]);
  red[t]=mxv; __syncthreads();
  for (int s=128;s;s>>=1){ if (t<s) red[t]=fmaxf(red[t],red[t+s]); __syncthreads(); }
  float mx=red[0]; __syncthreads();

  float s0  = fmaxf(mx/127.f, EPSQ);
  float sx1 = fmaxf((127.f*s0)/127.f, EPSQ);
  float sw1 = fmaxf(mw1/7.f, EPSQ);
  float sw2 = fmaxf(mw2/7.f, EPSQ);
  float swf = fmaxf(mwf/7.f, EPSQ);
  float sb1 = sx1*sw1;
  if (t==0){ F[0]=s0; F[1]=sx1; F[2]=sw1; F[3]=sb1; F[7]=sw2; F[12]=swf; }
  float* m1f = WS_M1F(ws);
  for (int i=t;i<144;i+=256) m1f[i] = clampf(rintf(w1[i]/sw1), -7.f, 7.f);
  if (t<16){
    int bl = (int)rintf(b1[t]/sb1);
    WS_B1L(ws)[t] = bl;
    WS_B1F(ws)[t] = (float)bl;
  }
  for (int i=t;i<5120;i+=256){
    int chunk=i>>10, r=i&1023, ln=r>>4, j=r&15;
    int tap=2*chunk+(ln>>5), oc=ln&31;
    signed char v=0;
    if (tap<9) v=(signed char)clampf(rintf(w2[oc*144 + j*9 + tap]/sw2), -7.f, 7.f);
    WS_B2FR(ws)[i]=v;
  }
  for (int i=t;i<1024;i+=256){
    int ln=i>>4, j=i&15;
    int k=(ln>>5)*16+j, oc=ln&31;
    signed char v=0;
    if (k<9 && oc<16) v=(signed char)clampf(rintf(w1[oc*9+k]/sw1), -7.f, 7.f);
    WS_B1FR(ws)[i]=v;
  }
  float* mff = WS_MFF(ws);
  for (int i=t;i<15680;i+=256) mff[i] = clampf(rintf(wf[i]/swf), -7.f, 7.f);
  for (int i=t;i<50176;i+=256){
    int chunk=i>>10, r2=i&1023, ln=r2>>4, j=r2&15;
    int oc=ln&31, k=chunk*32+(ln>>5)*16+j;
    int cell=k>>5, ch=k&31;
    signed char v=0;
    if (oc<10) v=(signed char)clampf(rintf(wf[oc*1568 + ch*49 + cell]/swf), -7.f, 7.f);
    ((signed char*)WS_WFP(ws))[i]=v;
  }
}

template<bool FULLR>
__global__ void k_s1(const float* __restrict__ b2, char* ws){
  float* F=WS_F(ws); int* I=WS_I(ws);
  __shared__ int rA[256], rS[256];
  __shared__ float sh[4];
  int t=threadIdx.x;
  int amaxI, smaxI;
  if constexpr (FULLR){
    int a=0, s=INT_MIN;
    const int* ra=WS_RA1(ws); const int* rs=WS_RS1(ws);
    for (int i=t;i<6272;i+=256){ a=max(a,ra[i]); s=max(s,rs[i]); }
    rA[t]=a; rS[t]=s; __syncthreads();
    for (int st=128;st;st>>=1){ if (t<st){ rA[t]=max(rA[t],rA[t+st]); rS[t]=max(rS[t],rS[t+st]); } __syncthreads(); }
    amaxI=rA[0]; smaxI=rS[0];
  } else { amaxI=I[1]; smaxI=I[2]; }
  if (t==0){
    float sb1=F[3];
    float sy1 = fmaxf((sb1*(float)amaxI)/127.f, EPSQ);
    float mp  = sb1*(float)smaxI;
    float P1  = clampf(rintf(mp/sy1), 0.f, 127.f);
    float sr1 = fmaxf((sy1*P1)/15.f, EPSQ);
    float N1  = clampf(rintf((sy1*P1)/sr1), 0.f, 15.f);
    float sx2 = fmaxf((N1*sr1)/127.f, EPSQ);
    float sb2 = sx2*F[7];
    F[4]=sy1; F[5]=sr1; F[6]=sx2; F[8]=sb2;
    sh[0]=sy1; sh[1]=sr1; sh[2]=sx2; sh[3]=sb2;
  }
  __syncthreads();
  float sy1=sh[0], sr1=sh[1], sx2=sh[2], sb2=sh[3];
  int k = t-128;
  float n = (k>0) ? clampf(rintf((sy1*(float)k)/sr1), 0.f, 15.f) : 0.f;
  WS_Q2TAB(ws)[t] = (signed char)clampf(rintf((n*sr1)/sx2), -128.f, 127.f);
  if (t<32) WS_B2L(ws)[t] = (int)rintf(b2[t]/sb2);
}

template<bool FULLR>
__global__ void k_s2(const float* __restrict__ bf, char* ws){
  float* F=WS_F(ws); int* I=WS_I(ws);
  __shared__ int rA[256], rS[256];
  __shared__ float sh[4];
  int t=threadIdx.x;
  int amaxI, smaxI;
  if constexpr (FULLR){
    int a=0, s=INT_MIN;
    const int* ra=WS_RA2(ws); const int* rs=WS_RS2(ws);
    for (int i=t;i<2048;i+=256){ a=max(a,ra[i]); s=max(s,rs[i]); }
    rA[t]=a; rS[t]=s; __syncthreads();
    for (int st=128;st;st>>=1){ if (t<st){ rA[t]=max(rA[t],rA[t+st]); rS[t]=max(rS[t],rS[t+st]); } __syncthreads(); }
    amaxI=rA[0]; smaxI=rS[0];
  } else { amaxI=I[3]; smaxI=I[4]; }
  if (t==0){
    float sb2=F[8];
    float sy2 = fmaxf((sb2*(float)amaxI)/127.f, EPSQ);
    float mp  = sb2*(float)smaxI;
    float P2  = clampf(rintf(mp/sy2), 0.f, 127.f);
    float sr2 = fmaxf((sy2*P2)/15.f, EPSQ);
    float N2  = clampf(rintf((sy2*P2)/sr2), 0.f, 15.f);
    float sx3 = fmaxf((N2*sr2)/127.f, EPSQ);
    float sb3 = sx3*F[12];
    F[9]=sy2; F[10]=sr2; F[11]=sx3; F[13]=sb3;
    sh[0]=sy2; sh[1]=sr2; sh[2]=sx3; sh[3]=sb3;
  }
  __syncthreads();
  float sy2=sh[0], sr2=sh[1], sx3=sh[2], sb3=sh[3];
  int k = t-128;
  float n = (k>0) ? clampf(rintf((sy2*(float)k)/sr2), 0.f, 15.f) : 0.f;
  WS_Q3TAB(ws)[t] = (signed char)clampf(rintf((n*sr2)/sx3), -128.f, 127.f);
  if (t<16) WS_BFL(ws)[t] = (t<10) ? (int)rintf(bf[t]/sb3) : 0;
}

template<bool FULLR>
__global__ void k_s3(char* ws){
  float* F=WS_F(ws); int* I=WS_I(ws);
  __shared__ int rA[256];
  int t=threadIdx.x;
  int amaxI;
  if constexpr (FULLR){
    rA[t] = WS_RA3(ws)[t];
    __syncthreads();
    for (int st=128;st;st>>=1){ if (t<st) rA[t]=max(rA[t],rA[t+st]); __syncthreads(); }
    amaxI = rA[0];
  } else { amaxI = I[5]; }
  if (t==0) F[14] = fmaxf((F[13]*(float)amaxI)/127.f, EPSQ);
}

// ================= FULL PATH compute =================
__global__ void k_qx(const float* __restrict__ x, const char* __restrict__ ws,
                     signed char* __restrict__ qx){
  const float s0 = ((const float*)ws)[0];
  int id = blockIdx.x*256 + threadIdx.x;          // < NB*240
  int img = id/240, w = id - img*240;
  int r = w>>3, c4 = (w&7)<<2;
  const float* xi = x + img*784;
  unsigned out = 0;
#pragma unroll
  for (int j=0;j<4;j++){
    int c = c4+j;
    bool valid = (r>=1) && (r<=28) && (c>=1) && (c<=28);
    int q = 0;
    if (valid){
      float xv = xi[(r-1)*28 + (c-1)];
      q = (int)clampf(rintf(xv/s0), -128.f, 127.f);
    }
    out |= ((unsigned)(unsigned char)(signed char)q) << (8*j);
  }
  ((unsigned*)qx)[id] = out;
}

__global__ __launch_bounds__(256) void k_conv1(const signed char* __restrict__ qx,
                                               char* __restrict__ ws,
                                               short* __restrict__ i1p){
  const int t = threadIdx.x;
  const int id = blockIdx.x*256 + t;
  const int img = id/196, cell = id - img*196;
  const int py = cell/14, px = cell - py*14;
  const signed char* qb = qx + img*960 + (2*py)*32;
  const int pc0 = 2*px;
  const int al = pc0 & ~3, sh = (pc0&3)*8;
  float in[4][4];
#pragma unroll
  for (int rr=0; rr<4; rr++){
    unsigned lo = *(const unsigned*)(qb + rr*32 + al);
    unsigned hi = *(const unsigned*)(qb + rr*32 + al + 4);
    unsigned wrd = (unsigned)(((((unsigned long long)hi)<<32)|lo) >> sh);
#pragma unroll
    for (int cc=0; cc<4; cc++)
      in[rr][cc] = (float)(signed char)((wrd >> (8*cc)) & 0xFFu);
  }
  const float* __restrict__ m1f = WS_M1F(ws);   // uniform -> s_load
  const float* __restrict__ b1f = WS_B1F(ws);
  int amax=0, smax=INT_MIN;
  short outv[16];
#pragma unroll
  for (int oc=0; oc<16; oc++){
    float b = b1f[oc];
    float a00=b, a01=b, a10=b, a11=b;
#pragma unroll
    for (int dy=0; dy<3; dy++){
#pragma unroll
      for (int dx=0; dx<3; dx++){
        float wt = m1f[oc*9+dy*3+dx];
        a00 = fmaf(in[dy  ][dx  ], wt, a00);
        a01 = fmaf(in[dy  ][dx+1], wt, a01);
        a10 = fmaf(in[dy+1][dx  ], wt, a10);
        a11 = fmaf(in[dy+1][dx+1], wt, a11);
      }
    }
    int v00=(int)a00, v01=(int)a01, v10=(int)a10, v11=(int)a11;
    int mx = max(max(v00,v01), max(v10,v11));
    int ax = max(max(v00<0?-v00:v00, v01<0?-v01:v01), max(v10<0?-v10:v10, v11<0?-v11:v11));
    amax = max(amax, ax);
    smax = max(smax, mx);
    outv[oc] = (short)mx;
  }
  int4* dst = (int4*)(i1p + (size_t)id*16);
  dst[0] = *(const int4*)&outv[0];
  dst[1] = *(const int4*)&outv[8];
  reduce2_store(amax, smax, &WS_RA1(ws)[blockIdx.x], &WS_RS1(ws)[blockIdx.x]);
}

// P3: conv2 MFMA, pool-cell-grouped M-row permutation.
// M-row m (0..223): group g=m>>2 = pool cell (g<49), sub=m&3 = (dy,dx) within 2x2.
// C layout gives each lane 4 consecutive-row groups (g = mt*8+2i+h) -> pool2 is a
// register max over acc[4i..4i+3]. No LDS pool, no atomics, no div in epilogue.
__global__ __launch_bounds__(256) void k_conv2r(char* __restrict__ ws,
                                                short* __restrict__ i1p,
                                                int* __restrict__ p2g){
  __shared__ __align__(16) signed char q2p4[4][4096];   // per-wave padded [16][16][16ch]
  const int t=threadIdx.x, lane=t&63, wid=t>>6;
  const int img = blockIdx.x*4 + wid;
  signed char* q2p = q2p4[wid];
  const float* F = WS_F(ws);
  const float sb1=F[3], sy1=F[4];
  const signed char* q2t = WS_Q2TAB(ws);

#pragma unroll
  for (int k=0;k<8;k++) ((unsigned long long*)q2p)[lane + 64*k] = 0ULL;

  const unsigned* src = (const unsigned*)(i1p + (size_t)img*3136);
  for (int k=0;k<25;k++){
    int idx = lane + 64*k;
    if (idx >= 1568) break;
    unsigned wv = src[idx];
    int e0 = idx*2;
    int cellc = e0 >> 4, ch = e0 & 15;
    int pyc = cellc/14, pxc = cellc - pyc*14;
    int m0 = (int)(short)(wv & 0xFFFFu);
    int m1 = (int)(short)(wv >> 16);
    float k10 = clampf(rintf((sb1*(float)m0)/sy1), -128.f, 127.f);
    float k11 = clampf(rintf((sb1*(float)m1)/sy1), -128.f, 127.f);
    int b0 = (int)(unsigned char)q2t[(int)k10+128];
    int b1 = (int)(unsigned char)q2t[(int)k11+128];
    *(unsigned short*)(q2p + ((pyc+1)*16 + (pxc+1))*16 + ch) = (unsigned short)(b0 | (b1<<8));
  }

  i32x4 bfr[5];
  const i32x4* bg = (const i32x4*)WS_B2FR(ws);
#pragma unroll
  for (int c=0;c<5;c++) bfr[c] = bg[c*64+lane];
  const int col = lane&31, h = lane>>5;
  const int bias = WS_B2L(ws)[col];
  int amax2=0, smax2=INT_MIN;
  const int TOFF[9] = {0,1,2,16,17,18,32,33,34};
  int* dstb = p2g + (size_t)img*1568;

#pragma unroll
  for (int mt=0; mt<7; mt++){
    // A-row position for this lane: m = mt*32+col -> cell g, sub -> padded-tile entry base
    int m = mt*32 + col;
    int g = m>>2, sub = m&3;
    bool gv = g < 49;
    int py = (g*37)>>8;            // g/7, exact for g<56
    int px = g - py*7;
    int oy = 2*py + (sub>>1), ox = 2*px + (sub&1);
    int E0 = oy*16 + ox;
    i32x16 acc;
#pragma unroll
    for (int r=0;r<16;r++) acc[r] = bias;
#pragma unroll
    for (int c=0;c<5;c++){
      const int t0 = TOFF[2*c];
      const int t1 = (2*c+1<9) ? TOFF[2*c+1] : -1;
      int toff = h ? t1 : t0;
      int entry = (gv && toff>=0) ? (E0 + toff) : 0;   // entry 0 = zero border
      i32x4 a = *(const i32x4*)(q2p + entry*16);
      acc = __builtin_amdgcn_mfma_i32_32x32x32_i8(a, bfr[c], acc, 0,0,0);
    }
    // epilogue: per consecutive-4 group = one pool cell, all in registers
#pragma unroll
    for (int i=0;i<4;i++){
      int gg = mt*8 + 2*i + h;
      if (gg < 49){
        int v0=acc[4*i], v1=acc[4*i+1], v2=acc[4*i+2], v3=acc[4*i+3];
        int a0=v0<0?-v0:v0, a1=v1<0?-v1:v1, a2=v2<0?-v2:v2, a3=v3<0?-v3:v3;
        amax2 = max(amax2, max(max(a0,a1),max(a2,a3)));
        int mx = max(max(v0,v1),max(v2,v3));
        smax2 = max(smax2, mx);
        dstb[gg*32 + col] = mx;
      }
    }
  }
  reduce2_store(amax2, smax2, &WS_RA2(ws)[blockIdx.x], &WS_RS2(ws)[blockIdx.x]);
}

__global__ void k_rq2(const char* __restrict__ ws, const int* __restrict__ p2g,
                      signed char* __restrict__ q3g){
  const float* F = (const float*)ws;
  const float sb2 = F[8], sy2 = F[9];
  const signed char* q3t = WS_Q3TAB(ws);
  int id = blockIdx.x*256 + threadIdx.x;
  i32x4 m4 = ((const i32x4*)p2g)[id];
  unsigned out=0;
#pragma unroll
  for (int j=0;j<4;j++){
    float k2 = clampf(rintf((sb2*(float)m4[j])/sy2), -128.f, 127.f);
    out |= ((unsigned)(unsigned char)q3t[(int)k2+128]) << (8*j);
  }
  ((unsigned*)q3g)[id] = out;
}

__global__ __launch_bounds__(256) void k_fc(char* __restrict__ ws,
                                            const signed char* __restrict__ q3g,
                                            int* __restrict__ i3out){
  __shared__ int part[3][16][64];
  int t=threadIdx.x, lane=t&63, wid=t>>6;
  int mt = blockIdx.x;              // 0..255
  const int col=lane&31, h=lane>>5;
  const signed char* A0 = q3g + (size_t)(mt*32 + col)*1568 + 16*h;
  const i32x4* wfp = (const i32x4*)WS_WFP(ws);
  i32x16 acc;
#pragma unroll
  for (int r=0;r<16;r++) acc[r]=0;
  for (int c=wid; c<49; c+=4){
    i32x4 a = *(const i32x4*)(A0 + c*32);
    i32x4 b = wfp[c*64 + lane];
    acc = __builtin_amdgcn_mfma_i32_32x32x32_i8(a, b, acc, 0,0,0);
  }
  if (wid>0){
#pragma unroll
    for (int r=0;r<16;r++) part[wid-1][r][lane] = acc[r];
  }
  __syncthreads();
  if (wid==0){
    int bias = (col<10) ? WS_BFL(ws)[col] : 0;
    int am=0;
#pragma unroll
    for (int r=0;r<16;r++){
      int v = acc[r] + part[0][r][lane] + part[1][r][lane] + part[2][r][lane] + bias;
      int row=(r&3)+8*(r>>2)+4*h;
      int img = mt*32+row;
      if (col<10){
        i3out[img*10+col] = v;
        am = max(am, v<0?-v:v);
      }
    }
    am = wave_max_i(am);
    if (lane==0) WS_RA3(ws)[blockIdx.x] = am;
  }
}

// ================= FALLBACK (verified) =================
__global__ __launch_bounds__(256) void k_c1(const float* __restrict__ x, char* __restrict__ ws,
                                            short* __restrict__ i1p){
  constexpr int OFF_K0=0, OFF_A=960, OFF_I1=13760, OFF_B1=38848;
  __shared__ __align__(16) char arena[38912];
  signed char* k0b = (signed char*)(arena+OFF_K0);
  signed char* Abuf= (signed char*)(arena+OFF_A);
  short*       I1s = (short*)(arena+OFF_I1);
  int*         b1i = (int*)(arena+OFF_B1);

  const int tid=threadIdx.x, img=blockIdx.x;
  const int lane=tid&63, wid=tid>>6;
  const float s0 = WS_F(ws)[0];

  if (tid<16) b1i[tid]=WS_B1L(ws)[tid];
  for (int i=tid;i<240;i+=256) ((int*)k0b)[i]=0;
  for (int i=tid;i<3200;i+=256) ((int*)Abuf)[i]=0;
  __syncthreads();
  const float* xi = x + img*784;
  for (int i=tid;i<784;i+=256){
    int r=i/28, c=i-r*28;
    float v = clampf(rintf(xi[i]/s0), -128.f, 127.f);
    k0b[(r+1)*32 + (c+1)] = (signed char)v;
  }
  __syncthreads();
  for (int p=tid;p<784;p+=256){
    int oy=p/28, ox=p-oy*28;
    int base = oy*32+ox;
    int al = base & ~3, sh = (base&3)*8;
    unsigned l0a=*(const unsigned*)(k0b+al),    l1a=*(const unsigned*)(k0b+al+4);
    unsigned l0b=*(const unsigned*)(k0b+al+32), l1b=*(const unsigned*)(k0b+al+36);
    unsigned l0c=*(const unsigned*)(k0b+al+64), l1c=*(const unsigned*)(k0b+al+68);
    unsigned u0=(unsigned)(((((unsigned long long)l1a)<<32)|l0a)>>sh);
    unsigned u1=(unsigned)(((((unsigned long long)l1b)<<32)|l0b)>>sh);
    unsigned u2=(unsigned)(((((unsigned long long)l1c)<<32)|l0c)>>sh);
    i32x4 row;
    row[0]=(int)((u0&0xFFFFFFu)|(u1<<24));
    row[1]=(int)(((u1>>8)&0xFFFFu)|((u2&0xFFFFu)<<16));
    row[2]=(int)((u2>>16)&0xFFu);
    row[3]=0;
    *(i32x4*)(Abuf + p*16) = row;
  }
  __syncthreads();
  const i32x4 bfr = ((const i32x4*)WS_B1FR(ws))[lane];
  const int col=lane&31, h=lane>>5;
  const int bias=(col<16)? b1i[col] : 0;
  int amax=0, smax=INT_MIN;
  for (int mt=wid; mt<25; mt+=4){
    i32x4 a={0,0,0,0};
    if (h==0) a = *(const i32x4*)(Abuf + (mt*32+col)*16);
    i32x16 acc;
#pragma unroll
    for (int r=0;r<16;r++) acc[r]=bias;
    acc=__builtin_amdgcn_mfma_i32_32x32x32_i8(a,bfr,acc,0,0,0);
#pragma unroll
    for (int r=0;r<16;r++){
      int row=(r&3)+8*(r>>2)+4*h;
      int p=mt*32+row;
      if (p<784 && col<16){
        int v=acc[r];
        amax=max(amax,v<0?-v:v); smax=max(smax,v);
        I1s[p*16+col]=(short)v;
      }
    }
  }
  __syncthreads();
  for (int i=tid;i<3136;i+=256){
    int pp=i>>4, c=i&15, py=pp/14, px=pp-py*14;
    int p0=py*56+px*2;
    int m=max(max((int)I1s[p0*16+c],(int)I1s[(p0+1)*16+c]),
              max((int)I1s[(p0+28)*16+c],(int)I1s[(p0+29)*16+c]));
    i1p[(size_t)img*3136 + i]=(short)m;
  }
  reduce2_atomic(amax,smax,&WS_I(ws)[1],&WS_I(ws)[2]);
}

template<bool FIN>
__global__ __launch_bounds__(256) void k_c2(char* __restrict__ ws, const short* __restrict__ i1p,
                                            int* __restrict__ i3out){
  constexpr int OFF_Q2L=0, OFF_B2I=3136, OFF_Q2T=3264, OFF_N2=3520,
                OFF_Q3T=9792, OFF_BFS=10048, OFF_Q3F=10112, OFF_RED=16384;
  constexpr int ARENA = FIN ? 16544 : 3520;
  __shared__ __align__(16) char arena[ARENA];
  signed char* q2l=(signed char*)(arena+OFF_Q2L);
  int* b2li=(int*)(arena+OFF_B2I);
  signed char* q2t=(signed char*)(arena+OFF_Q2T);

  const int tid=threadIdx.x, img=blockIdx.x;
  const int lane=tid&63, wid=tid>>6;
  const float* F=WS_F(ws);
  const float sb1=F[3], sy1=F[4];

  q2t[tid]=WS_Q2TAB(ws)[tid];
  if (tid<32) b2li[tid]=WS_B2L(ws)[tid];
  if constexpr (FIN){
    ((signed char*)(arena+OFF_Q3T))[tid]=WS_Q3TAB(ws)[tid];
    if (tid<16) ((int*)(arena+OFF_BFS))[tid]=WS_BFL(ws)[tid];
  }
  __syncthreads();
  for (int i=tid;i<3136;i+=256){
    int m=(int)i1p[(size_t)img*3136+i];
    float k1=clampf(rintf((sb1*(float)m)/sy1),-128.f,127.f);
    q2l[i]=q2t[(int)k1+128];
  }
  __syncthreads();

  i32x4 bfr[5];
  {
    const i32x4* bg=(const i32x4*)WS_B2FR(ws);
#pragma unroll
    for (int c=0;c<5;c++) bfr[c]=bg[c*64+lane];
  }
  const int col=lane&31, h=lane>>5;
  const int bias=b2li[col];
  int amax2=0, smax2=INT_MIN;
  float sb2=0.f, sy2=0.f;
  signed char* n2buf=nullptr;
  if constexpr (FIN){ sb2=F[8]; sy2=F[9]; n2buf=(signed char*)(arena+OFF_N2); }

  for (int mt=wid; mt<7; mt+=4){
    const int p=mt*32+col;
    const bool pv=p<196;
    const int oy=p/14, ox=p-oy*14;
    i32x16 acc;
#pragma unroll
    for (int r=0;r<16;r++) acc[r]=bias;
#pragma unroll
    for (int c=0;c<5;c++){
      const int tap=2*c+h;
      i32x4 a={0,0,0,0};
      if (pv && tap<9){
        const int iy=oy+tap/3-1, ix=ox+tap-(tap/3)*3-1;
        if ((unsigned)iy<14u && (unsigned)ix<14u) a=*(const i32x4*)(q2l+(iy*14+ix)*16);
      }
      acc=__builtin_amdgcn_mfma_i32_32x32x32_i8(a,bfr[c],acc,0,0,0);
    }
#pragma unroll
    for (int r=0;r<16;r++){
      const int row=(r&3)+8*(r>>2)+4*h;
      const int pp=mt*32+row;
      if (pp<196){
        const int v=acc[r];
        if constexpr (!FIN){ amax2=max(amax2,v<0?-v:v); smax2=max(smax2,v); }
        else {
          n2buf[col*196+pp]=(signed char)clampf(rintf((sb2*(float)v)/sy2),-128.f,127.f);
        }
      }
    }
  }
  if constexpr (!FIN){
    reduce2_atomic(amax2,smax2,&WS_I(ws)[3],&WS_I(ws)[4]);
    return;
  } else {
    __syncthreads();
    signed char* q3t_s=(signed char*)(arena+OFF_Q3T);
    float* q3f=(float*)(arena+OFF_Q3F);
    for (int i=tid;i<1568;i+=256){
      int cch=i/49, s=i-cch*49, qy=s/7, qx=s-qy*7;
      int b=cch*196+qy*28+qx*2;
      int m=max(max((int)n2buf[b],(int)n2buf[b+1]),max((int)n2buf[b+14],(int)n2buf[b+15]));
      q3f[i]=(float)q3t_s[m+128];
    }
    __syncthreads();
    const float* mff=WS_MFF(ws);
    float a10[10];
#pragma unroll
    for (int o=0;o<10;o++) a10[o]=0.f;
    for (int k=tid;k<1568;k+=256){
      float qa=q3f[k];
#pragma unroll
      for (int o=0;o<10;o++) a10[o]=fmaf(qa,mff[o*1568+k],a10[o]);
    }
#pragma unroll
    for (int o=0;o<10;o++){
#pragma unroll
      for (int off=32;off;off>>=1) a10[o]+=__shfl_down(a10[o],off,64);
    }
    float* redf=(float*)(arena+OFF_RED);
    int* bfs=(int*)(arena+OFF_BFS);
    if (lane==0){
#pragma unroll
      for (int o=0;o<10;o++) redf[wid*10+o]=a10[o];
    }
    __syncthreads();
    if (tid<10){
      float s=redf[tid]+redf[10+tid]+redf[20+tid]+redf[30+tid];
      int I3v=(int)s+bfs[tid];
      i3out[img*10+tid]=I3v;
      redf[tid]=(float)(I3v<0?-I3v:I3v);
    }
    __syncthreads();
    if (tid==0){
      int m=0;
#pragma unroll
      for (int o=0;o<10;o++) m=max(m,(int)redf[o]);
      atomicMax(&WS_I(ws)[5],m);
    }
  }
}

__global__ void k_out(char* ws, float* __restrict__ out){
  float* F=WS_F(ws);
  float sb3=F[13], sy3=F[14];
  int i = blockIdx.x*blockDim.x + threadIdx.x;
  if (i < NB*10){
    int iv = ((const int*)out)[i];
    float y = sb3*(float)iv;
    float q = clampf(rintf(y/sy3), -128.f, 127.f);
    out[i] = q*sy3;
  }
}

extern "C" void kernel_launch(void* const* d_in, const int* in_sizes, int n_in,
                              void* d_out, int out_size, void* d_ws, size_t ws_size,
                              hipStream_t stream){
  const float* x  = (const float*)d_in[0];
  const float* w1 = (const float*)d_in[1];
  const float* b1 = (const float*)d_in[2];
  const float* w2 = (const float*)d_in[3];
  const float* b2 = (const float*)d_in[4];
  const float* wf = (const float*)d_in[5];
  const float* bf = (const float*)d_in[6];
  char* ws = (char*)d_ws;
  float* out = (float*)d_out;
  int* i3 = (int*)d_out;

  const size_t QX_SZ  = (size_t)NB*960;
  const size_t I1_SZ  = (size_t)NB*6272;
  const size_t Q3_SZ  = (size_t)NB*1568;
  const size_t needFull = (size_t)WS_BIG_OFF + QX_SZ + I1_SZ + Q3_SZ;

  if (ws_size >= needFull){
    signed char* qx  = (signed char*)(ws + WS_BIG_OFF);
    short*       i1p = (short*)(ws + WS_BIG_OFF + QX_SZ);
    int*         p2g = (int*)i1p;
    signed char* q3g = (signed char*)(ws + WS_BIG_OFF + QX_SZ + I1_SZ);
    k_absx  <<<dim3(2048), dim3(256), 0, stream>>>(x, ws);
    k_wmax  <<<dim3(81), dim3(256), 0, stream>>>(w1, w2, wf, ws);
    k_scales<<<dim3(1), dim3(256), 0, stream>>>(w1, b1, ws);
    k_qx    <<<dim3(NB*240/256), dim3(256), 0, stream>>>(x, ws, qx);
    k_pack  <<<dim3(282), dim3(256), 0, stream>>>(w1, w2, wf, ws);
    k_conv1 <<<dim3(NB*196/256), dim3(256), 0, stream>>>(qx, ws, i1p);
    k_s1<true><<<dim3(1), dim3(256), 0, stream>>>(b2, ws);
    k_conv2r<<<dim3(NB/4), dim3(256), 0, stream>>>(ws, i1p, p2g);
    k_s2<true><<<dim3(1), dim3(256), 0, stream>>>(bf, ws);
    k_rq2   <<<dim3(NB*1568/1024), dim3(256), 0, stream>>>(ws, p2g, q3g);
    k_fc    <<<dim3(256), dim3(256), 0, stream>>>(ws, q3g, i3);
    k_s3<true><<<dim3(1), dim3(256), 0, stream>>>(ws);
  } else {
    short* i1p = (short*)(ws + WS_BIG_OFF);
    k_init<<<dim3(1), dim3(64), 0, stream>>>(ws);
    k_absx<<<dim3(2048), dim3(256), 0, stream>>>(x, ws);
    k_wq  <<<dim3(1), dim3(256), 0, stream>>>(w1, b1, w2, wf, ws);
    k_c1<<<dim3(NB), dim3(256), 0, stream>>>(x, ws, i1p);
    k_s1<false><<<dim3(1), dim3(256), 0, stream>>>(b2, ws);
    k_c2<false><<<dim3(NB), dim3(256), 0, stream>>>(ws, i1p, i3);
    k_s2<false><<<dim3(1), dim3(256), 0, stream>>>(bf, ws);
    k_c2<true ><<<dim3(NB), dim3(256), 0, stream>>>(ws, i1p, i3);
    k_s3<false><<<dim3(1), dim3(256), 0, stream>>>(ws);
  }
  k_out<<<dim3((NB*10+255)/256), dim3(256), 0, stream>>>(ws, out);
}